// Round 13
// baseline (460.789 us; speedup 1.0000x reference)
//
#include <hip/hip_runtime.h>
#include <cstdint>
#include <cstddef>

#define N1v 262144
#define E1v 1048576
#define N2v 9472
#define E2v 262144
#define BBv 64
#define RRv 148
#define HIDv 1000
#define BRv (BBv * RRv)
#define NSEG 9472
#define EPB 1024
#define NBK1 512
#define SH1 9
#define BINS1 512
#define CAP1 2560
#define NBK2 74
#define SH2 7
#define BINS2 128
#define CAP2 4096

__host__ __device__ constexpr int cdiv(int a, int b) { return (a + b - 1) / b; }

typedef __attribute__((ext_vector_type(8))) short bf16x8;
typedef __attribute__((ext_vector_type(4))) float f32x4;
typedef unsigned short ushort_t;
typedef unsigned long long u64;

__device__ inline short f2bf(float f) {
    union { float f; unsigned u; } v; v.f = f;
    unsigned r = v.u + 0x7fff + ((v.u >> 16) & 1);   // RNE
    return (short)(r >> 16);
}
__device__ inline float bf2f(unsigned hs) {
    union { unsigned u; float f; } v; v.u = hs << 16; return v.f;
}
__device__ inline unsigned relu_pk(unsigned u) {
    unsigned r = u;
    if (r & 0x8000u) r &= 0xFFFF0000u;
    if (r & 0x80000000u) r &= 0x0000FFFFu;
    return r;
}

// ---------------- pass A: coarse bucket histogram (both branches) ----------------
__global__ __launch_bounds__(256) void k_binA(const int* __restrict__ dst1, int* __restrict__ bc1,
                                              const int* __restrict__ dst2, int* __restrict__ bc2) {
    int bid = blockIdx.x;
    const int* dst; int* bc; int nbk, sh; int e0;
    if (bid < E1v / EPB) { dst = dst1; bc = bc1; nbk = NBK1; sh = SH1; e0 = bid * EPB; }
    else { dst = dst2; bc = bc2; nbk = NBK2; sh = SH2; e0 = (bid - E1v / EPB) * EPB; }
    __shared__ int h[NBK1];
    int tid = threadIdx.x;
    for (int t = tid; t < nbk; t += 256) h[t] = 0;
    __syncthreads();
    for (int t = tid; t < EPB; t += 256) atomicAdd(&h[dst[e0 + t] >> sh], 1);
    __syncthreads();
    for (int t = tid; t < nbk; t += 256) if (h[t]) atomicAdd(&bc[t], h[t]);
}

// ---------------- scan bucket totals -> bases + cursors ----------------
__global__ __launch_bounds__(256) void k_scanAB(const int* __restrict__ bc1, int* __restrict__ bb1, int* __restrict__ cur1,
                                                const int* __restrict__ bc2, int* __restrict__ bb2, int* __restrict__ cur2) {
    __shared__ int tmp[256];
    int t = threadIdx.x;
    // branch 1: 512 buckets, 2 per thread
    int v0 = bc1[t * 2], v1 = bc1[t * 2 + 1];
    int ts = v0 + v1;
    tmp[t] = ts; __syncthreads();
    int val = ts;
    for (int off = 1; off < 256; off <<= 1) { int o = (t >= off) ? tmp[t - off] : 0; __syncthreads(); val += o; tmp[t] = val; __syncthreads(); }
    int excl = val - ts;
    bb1[t * 2] = excl;     cur1[t * 2] = excl;
    bb1[t * 2 + 1] = excl + v0; cur1[t * 2 + 1] = excl + v0;
    if (t == 255) bb1[NBK1] = val;
    __syncthreads();
    int v2 = (t < NBK2) ? bc2[t] : 0;
    tmp[t] = v2; __syncthreads();
    int val2 = v2;
    for (int off = 1; off < 256; off <<= 1) { int o = (t >= off) ? tmp[t - off] : 0; __syncthreads(); val2 += o; tmp[t] = val2; __syncthreads(); }
    if (t < NBK2) { int e2 = val2 - v2; bb2[t] = e2; cur2[t] = e2; }
    if (t == NBK2 - 1) bb2[NBK2] = val2;
}

// ---------------- pass B: bucket-grouped record scatter (ew | src<<sh | dstlow) ----------------
__global__ __launch_bounds__(256) void k_binB(const int* __restrict__ src1, const int* __restrict__ dst1,
                                              const float* __restrict__ ew1, int* __restrict__ cur1, u64* __restrict__ rb1,
                                              const int* __restrict__ src2, const int* __restrict__ dst2,
                                              const float* __restrict__ ew2, int* __restrict__ cur2, u64* __restrict__ rb2) {
    int bid = blockIdx.x;
    const int* src; const int* dst; const float* ew; int* cur; u64* rb; int nbk, sh; int e0;
    if (bid < E1v / EPB) { src = src1; dst = dst1; ew = ew1; cur = cur1; rb = rb1; nbk = NBK1; sh = SH1; e0 = bid * EPB; }
    else { src = src2; dst = dst2; ew = ew2; cur = cur2; rb = rb2; nbk = NBK2; sh = SH2; e0 = (bid - E1v / EPB) * EPB; }
    __shared__ int h[NBK1], basg[NBK1];
    int tid = threadIdx.x;
    for (int t = tid; t < nbk; t += 256) h[t] = 0;
    __syncthreads();
    for (int t = tid; t < EPB; t += 256) atomicAdd(&h[dst[e0 + t] >> sh], 1);
    __syncthreads();
    for (int t = tid; t < nbk; t += 256) {
        int c = h[t];
        basg[t] = c ? atomicAdd(&cur[t], c) : 0;
        h[t] = 0;
    }
    __syncthreads();
    unsigned lowmask = (1u << sh) - 1u;
    for (int t = tid; t < EPB; t += 256) {
        int d = dst[e0 + t];
        int b = d >> sh;
        int r = atomicAdd(&h[b], 1);
        unsigned lo = ((unsigned)src[e0 + t] << sh) | ((unsigned)d & lowmask);
        rb[(size_t)basg[b] + r] = ((u64)(unsigned)__float_as_int(ew[e0 + t]) << 32) | lo;
    }
}

// ---------------- pass C: per-bucket CSR build (offs + dinv + (src,ew) records) ----------------
template<int BINS, int CAP, int SH>
__global__ __launch_bounds__(256) void k_csrC(const u64* __restrict__ rb, const int* __restrict__ bb,
                                              float* __restrict__ dinv, int* __restrict__ offs,
                                              int2* __restrict__ snC) {
    int b = blockIdx.x;
    int beg = bb[b], end = bb[b + 1], cnt = end - beg;
    __shared__ int hist[BINS];
    __shared__ float degs[BINS];
    __shared__ int scn[BINS];
    __shared__ int tmp[256];
    extern __shared__ int2 outb[];
    int tid = threadIdx.x;
    for (int i = tid; i < BINS; i += 256) { hist[i] = 0; degs[i] = 0.f; }
    __syncthreads();
    for (int j = beg + tid; j < end; j += 256) {
        u64 rec = rb[j];
        int bin = (int)((unsigned)rec & (BINS - 1));
        float w = __int_as_float((int)(rec >> 32));
        atomicAdd(&hist[bin], 1);
        atomicAdd(&degs[bin], w);
    }
    __syncthreads();
    constexpr int PER = (BINS + 255) / 256;
    int lv[PER];
    int tsum = 0;
    int base_i = tid * PER;
#pragma unroll
    for (int k = 0; k < PER; ++k) { int idx = base_i + k; lv[k] = (idx < BINS) ? hist[idx] : 0; tsum += lv[k]; }
    tmp[tid] = tsum; __syncthreads();
    int val = tsum;
    for (int off = 1; off < 256; off <<= 1) { int o = (tid >= off) ? tmp[tid - off] : 0; __syncthreads(); val += o; tmp[tid] = val; __syncthreads(); }
    int run = val - tsum;
#pragma unroll
    for (int k = 0; k < PER; ++k) { int idx = base_i + k; if (idx < BINS) { scn[idx] = run; run += lv[k]; } }
    __syncthreads();
    for (int i = tid; i < BINS; i += 256) {
        offs[b * BINS + i] = beg + scn[i];
        dinv[b * BINS + i] = rsqrtf(degs[i] + 1.0f);
    }
    __syncthreads();
    bool staged = (cnt <= CAP);
    for (int j = beg + tid; j < end; j += 256) {
        u64 rec = rb[j];
        unsigned lo = (unsigned)rec;
        int bin = (int)(lo & (BINS - 1));
        int s = (int)(lo >> SH);
        int wbits = (int)(rec >> 32);
        int r = atomicAdd(&scn[bin], 1);
        int2 o2 = make_int2(s, wbits);
        if (staged) outb[r] = o2;
        else snC[(size_t)beg + r] = o2;
    }
    __syncthreads();
    if (staged) {
        for (int j = tid; j < cnt; j += 256) snC[(size_t)beg + j] = outb[j];
    }
}

// ---------------- block-local pool CSR ----------------
__global__ __launch_bounds__(256) void k_pool_csr(const int* __restrict__ roi, int* __restrict__ offs_p,
                                                  int* __restrict__ nodeC) {
    int b = blockIdx.x;
    __shared__ int rl[4096];
    __shared__ int hist[RRv];
    __shared__ int curs[RRv];
    int tid = threadIdx.x;
    for (int t = tid; t < RRv; t += 256) hist[t] = 0;
    __syncthreads();
    int base = b * 4096;
    for (int t = tid; t < 4096; t += 256) {
        int r = roi[base + t];
        rl[t] = r;
        atomicAdd(&hist[r], 1);
    }
    __syncthreads();
    if (tid < RRv) {
        int s = 0;
        for (int k = 0; k < tid; ++k) s += hist[k];
        curs[tid] = s;
        offs_p[b * RRv + tid] = base + s;
    }
    __syncthreads();
    for (int t = tid; t < 4096; t += 256) {
        int r = rl[t];
        int j = atomicAdd(&curs[r], 1);
        nodeC[base + j] = base + t;
    }
}

// ---------------- branch-1 pool gather: 2 segs x 4 slots x 8 lanes, uint4 loads ----------------
__global__ __launch_bounds__(256) void k_pool_gather(const int* __restrict__ nodeC, const int* __restrict__ offs,
                                                     const ushort_t* __restrict__ Ab, float* __restrict__ pooled) {
    int tid = threadIdx.x;
    int lane = tid & 63;
    int nh = lane >> 5;
    int slot = (lane >> 3) & 3;
    int f8 = lane & 7;
    int gw = blockIdx.x * 4 + (tid >> 6);
    int tw = gridDim.x * 4;
    for (int ss = gw * 2; ss < NSEG; ss += tw * 2) {
        int s = ss + nh;
        int beg = offs[s];
        int end = (s + 1 < NSEG) ? offs[s + 1] : N1v;
        float a0 = 0.f, a1 = 0.f, a2 = 0.f, a3 = 0.f, a4 = 0.f, a5 = 0.f, a6 = 0.f, a7 = 0.f;
        for (int j = beg + slot; j < end; j += 4) {
            int node = nodeC[j];
            uint4 v = *(const uint4*)(Ab + (size_t)node * 64 + f8 * 8);
            a0 += fmaxf(bf2f(v.x & 0xffffu), 0.f);
            a1 += fmaxf(bf2f(v.x >> 16), 0.f);
            a2 += fmaxf(bf2f(v.y & 0xffffu), 0.f);
            a3 += fmaxf(bf2f(v.y >> 16), 0.f);
            a4 += fmaxf(bf2f(v.z & 0xffffu), 0.f);
            a5 += fmaxf(bf2f(v.z >> 16), 0.f);
            a6 += fmaxf(bf2f(v.w & 0xffffu), 0.f);
            a7 += fmaxf(bf2f(v.w >> 16), 0.f);
        }
        a0 += __shfl_xor(a0, 8);  a1 += __shfl_xor(a1, 8);  a2 += __shfl_xor(a2, 8);  a3 += __shfl_xor(a3, 8);
        a4 += __shfl_xor(a4, 8);  a5 += __shfl_xor(a5, 8);  a6 += __shfl_xor(a6, 8);  a7 += __shfl_xor(a7, 8);
        a0 += __shfl_xor(a0, 16); a1 += __shfl_xor(a1, 16); a2 += __shfl_xor(a2, 16); a3 += __shfl_xor(a3, 16);
        a4 += __shfl_xor(a4, 16); a5 += __shfl_xor(a5, 16); a6 += __shfl_xor(a6, 16); a7 += __shfl_xor(a7, 16);
        if (slot == 0) {
            float inv = 1.f / (float)max(end - beg, 1);
            float4 r0, r1;
            r0.x = a0 * inv; r0.y = a1 * inv; r0.z = a2 * inv; r0.w = a3 * inv;
            r1.x = a4 * inv; r1.y = a5 * inv; r1.z = a6 * inv; r1.w = a7 * inv;
            *(float4*)(pooled + (size_t)s * 64 + f8 * 8) = r0;
            *(float4*)(pooled + (size_t)s * 64 + f8 * 8 + 4) = r1;
        }
    }
}

// ---------------- edge gather v3: 2 nodes x 4 edge-slots x 8 lanes, bf16 P in, bf16 A out ----------------
__global__ __launch_bounds__(256) void k_edge_gather3(const int2* __restrict__ snC,
                                                      const int* __restrict__ offs, const ushort_t* __restrict__ Pb,
                                                      const float* __restrict__ dinv, const float* __restrict__ bias,
                                                      ushort_t* __restrict__ A, int N, int E) {
    int tid = threadIdx.x;
    int lane = tid & 63;
    int nh = lane >> 5;
    int slot = (lane >> 3) & 3;
    int f8 = lane & 7;
    float4 bv0 = *(const float4*)(bias + f8 * 8);
    float4 bv1 = *(const float4*)(bias + f8 * 8 + 4);
    int gw = blockIdx.x * 4 + (tid >> 6);
    int tw = gridDim.x * 4;
    for (int ii = gw * 2; ii < N; ii += tw * 2) {
        int i = ii + nh;
        int beg = offs[i];
        int end = (i + 1 < N) ? offs[i + 1] : E;
        float di = dinv[i];
        float a0 = 0.f, a1 = 0.f, a2 = 0.f, a3 = 0.f, a4 = 0.f, a5 = 0.f, a6 = 0.f, a7 = 0.f;
        for (int j = beg + slot; j < end; j += 4) {
            int2 e = snC[j];
            int s = e.x;
            float nv = dinv[s] * __int_as_float(e.y) * di;
            uint4 w = *(const uint4*)(Pb + (size_t)s * 64 + f8 * 8);
            a0 = fmaf(nv, bf2f(w.x & 0xffffu), a0);
            a1 = fmaf(nv, bf2f(w.x >> 16), a1);
            a2 = fmaf(nv, bf2f(w.y & 0xffffu), a2);
            a3 = fmaf(nv, bf2f(w.y >> 16), a3);
            a4 = fmaf(nv, bf2f(w.z & 0xffffu), a4);
            a5 = fmaf(nv, bf2f(w.z >> 16), a5);
            a6 = fmaf(nv, bf2f(w.w & 0xffffu), a6);
            a7 = fmaf(nv, bf2f(w.w >> 16), a7);
        }
        a0 += __shfl_xor(a0, 8);  a1 += __shfl_xor(a1, 8);  a2 += __shfl_xor(a2, 8);  a3 += __shfl_xor(a3, 8);
        a4 += __shfl_xor(a4, 8);  a5 += __shfl_xor(a5, 8);  a6 += __shfl_xor(a6, 8);  a7 += __shfl_xor(a7, 8);
        a0 += __shfl_xor(a0, 16); a1 += __shfl_xor(a1, 16); a2 += __shfl_xor(a2, 16); a3 += __shfl_xor(a3, 16);
        a4 += __shfl_xor(a4, 16); a5 += __shfl_xor(a5, 16); a6 += __shfl_xor(a6, 16); a7 += __shfl_xor(a7, 16);
        if (slot == 0) {
            uint4 w = *(const uint4*)(Pb + (size_t)i * 64 + f8 * 8);
            float s2 = di * di;
            float r0 = fmaf(s2, bf2f(w.x & 0xffffu), a0) + bv0.x;
            float r1 = fmaf(s2, bf2f(w.x >> 16),    a1) + bv0.y;
            float r2 = fmaf(s2, bf2f(w.y & 0xffffu), a2) + bv0.z;
            float r3 = fmaf(s2, bf2f(w.y >> 16),    a3) + bv0.w;
            float r4 = fmaf(s2, bf2f(w.z & 0xffffu), a4) + bv1.x;
            float r5 = fmaf(s2, bf2f(w.z >> 16),    a5) + bv1.y;
            float r6 = fmaf(s2, bf2f(w.w & 0xffffu), a6) + bv1.z;
            float r7 = fmaf(s2, bf2f(w.w >> 16),    a7) + bv1.w;
            uint4 ov;
            ov.x = (unsigned)(ushort_t)f2bf(r0) | ((unsigned)(ushort_t)f2bf(r1) << 16);
            ov.y = (unsigned)(ushort_t)f2bf(r2) | ((unsigned)(ushort_t)f2bf(r3) << 16);
            ov.z = (unsigned)(ushort_t)f2bf(r4) | ((unsigned)(ushort_t)f2bf(r5) << 16);
            ov.w = (unsigned)(ushort_t)f2bf(r6) | ((unsigned)(ushort_t)f2bf(r7) << 16);
            *(uint4*)(A + (size_t)i * 64 + f8 * 8) = ov;
        }
    }
}

// ---------------- MFMA bf16 GEMM ----------------
template<bool RIN, bool IBF16>
__global__ __launch_bounds__(256) void k_gemm_mfma(const void* __restrict__ Xv, const float* __restrict__ Wmat,
                                                   ushort_t* __restrict__ Y, int N) {
    int tid = threadIdx.x;
    int lane = tid & 63;
    int wv = tid >> 6;
    int l15 = lane & 15;
    int lg = lane >> 4;
    bf16x8 bfrag[2][4];
    for (int kh = 0; kh < 2; ++kh)
        for (int ct = 0; ct < 4; ++ct) {
            bf16x8 b;
#pragma unroll
            for (int i = 0; i < 8; ++i)
                b[i] = f2bf(Wmat[(size_t)(kh * 32 + lg * 8 + i) * 64 + ct * 16 + l15]);
            bfrag[kh][ct] = b;
        }
    int gw = blockIdx.x * 4 + wv;
    int tw = gridDim.x * 4;
    int ntiles = N >> 4;
    for (int t = gw; t < ntiles; t += tw) {
        int row0 = t << 4;
        bf16x8 af0, af1;
        if (IBF16) {
            const ushort_t* xp = (const ushort_t*)Xv + (size_t)(row0 + l15) * 64 + lg * 8;
            uint4 c0 = *(const uint4*)(xp);
            uint4 c1 = *(const uint4*)(xp + 32);
            if (RIN) {
                c0.x = relu_pk(c0.x); c0.y = relu_pk(c0.y); c0.z = relu_pk(c0.z); c0.w = relu_pk(c0.w);
                c1.x = relu_pk(c1.x); c1.y = relu_pk(c1.y); c1.z = relu_pk(c1.z); c1.w = relu_pk(c1.w);
            }
            af0 = *reinterpret_cast<bf16x8*>(&c0);
            af1 = *reinterpret_cast<bf16x8*>(&c1);
        } else {
            const float* xp = (const float*)Xv + (size_t)(row0 + l15) * 64 + lg * 8;
            float4 a0 = *(const float4*)(xp);
            float4 a1 = *(const float4*)(xp + 4);
            float4 a2 = *(const float4*)(xp + 32);
            float4 a3 = *(const float4*)(xp + 36);
            if (RIN) {
                a0.x = fmaxf(a0.x, 0.f); a0.y = fmaxf(a0.y, 0.f); a0.z = fmaxf(a0.z, 0.f); a0.w = fmaxf(a0.w, 0.f);
                a1.x = fmaxf(a1.x, 0.f); a1.y = fmaxf(a1.y, 0.f); a1.z = fmaxf(a1.z, 0.f); a1.w = fmaxf(a1.w, 0.f);
                a2.x = fmaxf(a2.x, 0.f); a2.y = fmaxf(a2.y, 0.f); a2.z = fmaxf(a2.z, 0.f); a2.w = fmaxf(a2.w, 0.f);
                a3.x = fmaxf(a3.x, 0.f); a3.y = fmaxf(a3.y, 0.f); a3.z = fmaxf(a3.z, 0.f); a3.w = fmaxf(a3.w, 0.f);
            }
            af0[0] = f2bf(a0.x); af0[1] = f2bf(a0.y); af0[2] = f2bf(a0.z); af0[3] = f2bf(a0.w);
            af0[4] = f2bf(a1.x); af0[5] = f2bf(a1.y); af0[6] = f2bf(a1.z); af0[7] = f2bf(a1.w);
            af1[0] = f2bf(a2.x); af1[1] = f2bf(a2.y); af1[2] = f2bf(a2.z); af1[3] = f2bf(a2.w);
            af1[4] = f2bf(a3.x); af1[5] = f2bf(a3.y); af1[6] = f2bf(a3.z); af1[7] = f2bf(a3.w);
        }
        f32x4 acc0 = {0.f, 0.f, 0.f, 0.f}, acc1 = acc0, acc2 = acc0, acc3 = acc0;
        acc0 = __builtin_amdgcn_mfma_f32_16x16x32_bf16(af0, bfrag[0][0], acc0, 0, 0, 0);
        acc1 = __builtin_amdgcn_mfma_f32_16x16x32_bf16(af0, bfrag[0][1], acc1, 0, 0, 0);
        acc2 = __builtin_amdgcn_mfma_f32_16x16x32_bf16(af0, bfrag[0][2], acc2, 0, 0, 0);
        acc3 = __builtin_amdgcn_mfma_f32_16x16x32_bf16(af0, bfrag[0][3], acc3, 0, 0, 0);
        acc0 = __builtin_amdgcn_mfma_f32_16x16x32_bf16(af1, bfrag[1][0], acc0, 0, 0, 0);
        acc1 = __builtin_amdgcn_mfma_f32_16x16x32_bf16(af1, bfrag[1][1], acc1, 0, 0, 0);
        acc2 = __builtin_amdgcn_mfma_f32_16x16x32_bf16(af1, bfrag[1][2], acc2, 0, 0, 0);
        acc3 = __builtin_amdgcn_mfma_f32_16x16x32_bf16(af1, bfrag[1][3], acc3, 0, 0, 0);
        ushort_t* yp = Y + (size_t)(row0 + lg * 4) * 64 + l15;
#pragma unroll
        for (int r = 0; r < 4; ++r) {
            yp[(size_t)r * 64 + 0]  = (ushort_t)f2bf(acc0[r]);
            yp[(size_t)r * 64 + 16] = (ushort_t)f2bf(acc1[r]);
            yp[(size_t)r * 64 + 32] = (ushort_t)f2bf(acc2[r]);
            yp[(size_t)r * 64 + 48] = (ushort_t)f2bf(acc3[r]);
        }
    }
}

// ---------------- row-per-wave GEMM ----------------
template<int MB, bool RIN, bool ROUT, bool OBF16>
__global__ __launch_bounds__(256) void k_gemm_rowwave(const float* __restrict__ X, const float* __restrict__ W,
                                                      const float* __restrict__ bias, void* __restrict__ Yv,
                                                      int N, int K) {
    extern __shared__ float Wl[];
    const int M = MB * 64;
    for (int idx = threadIdx.x; idx < K * M; idx += 256) Wl[idx] = W[idx];
    __syncthreads();
    int lane = threadIdx.x & 63;
    int gw = blockIdx.x * 4 + (threadIdx.x >> 6);
    int tw = gridDim.x * 4;
    const int K4 = K >> 2;
    for (int row = gw; row < N; row += tw) {
        float acc[MB];
#pragma unroll
        for (int cb = 0; cb < MB; ++cb) acc[cb] = 0.f;
        const float4* xr = (const float4*)(X + (size_t)row * K);
        for (int k4 = 0; k4 < K4; ++k4) {
            float4 xv = xr[k4];
            if (RIN) {
                xv.x = fmaxf(xv.x, 0.f); xv.y = fmaxf(xv.y, 0.f);
                xv.z = fmaxf(xv.z, 0.f); xv.w = fmaxf(xv.w, 0.f);
            }
            const float* wp = Wl + (k4 * 4) * M + lane;
#pragma unroll
            for (int cb = 0; cb < MB; ++cb) acc[cb] = fmaf(xv.x, wp[cb * 64], acc[cb]);
            wp += M;
#pragma unroll
            for (int cb = 0; cb < MB; ++cb) acc[cb] = fmaf(xv.y, wp[cb * 64], acc[cb]);
            wp += M;
#pragma unroll
            for (int cb = 0; cb < MB; ++cb) acc[cb] = fmaf(xv.z, wp[cb * 64], acc[cb]);
            wp += M;
#pragma unroll
            for (int cb = 0; cb < MB; ++cb) acc[cb] = fmaf(xv.w, wp[cb * 64], acc[cb]);
        }
#pragma unroll
        for (int cb = 0; cb < MB; ++cb) {
            float y = acc[cb];
            int col = cb * 64 + lane;
            if (bias) y += bias[col];
            if (ROUT) y = fmaxf(y, 0.f);
            if (OBF16) ((ushort_t*)Yv)[(size_t)row * M + col] = (ushort_t)f2bf(y);
            else ((float*)Yv)[(size_t)row * M + col] = y;
        }
    }
}

// ---------------- fused double transpose (in_proj 192x64, out_proj 64x64) ----------------
__global__ __launch_bounds__(256) void k_transpose2(const float* __restrict__ Win, float* __restrict__ WinT,
                                                    const float* __restrict__ Wout, float* __restrict__ WoutT) {
    int i = blockIdx.x * 256 + threadIdx.x;
    if (i < 192 * 64) {
        int r = i >> 6, c = i & 63;
        WinT[c * 192 + r] = Win[i];
    } else if (i < 192 * 64 + 64 * 64) {
        int j = i - 192 * 64;
        int r = j >> 6, c = j & 63;
        WoutT[c * 64 + r] = Wout[j];
    }
}

// ---------------- branch-2 pool (identity, bf16 in) + comb ----------------
__global__ __launch_bounds__(256) void k_pool_fin2b(const ushort_t* __restrict__ h2Ab, const float* __restrict__ pooled,
                                                    float* __restrict__ pooledroi, float* __restrict__ comb,
                                                    int n4) {
    int i = blockIdx.x * 256 + threadIdx.x;
    if (i < n4) {
        uint2 v = *(const uint2*)(h2Ab + (size_t)i * 4);
        float4 p = ((const float4*)pooled)[i];
        float4 r;
        r.x = fmaxf(bf2f(v.x & 0xffffu), 0.f);
        r.y = fmaxf(bf2f(v.x >> 16), 0.f);
        r.z = fmaxf(bf2f(v.y & 0xffffu), 0.f);
        r.w = fmaxf(bf2f(v.y >> 16), 0.f);
        ((float4*)pooledroi)[i] = r;
        float4 c;
        c.x = r.x + p.x; c.y = r.y + p.y; c.z = r.z + p.z; c.w = r.w + p.w;
        ((float4*)comb)[i] = c;
    }
}

// ---------------- attention ----------------
__global__ __launch_bounds__(256) void k_attn(const float* __restrict__ qkv, float* __restrict__ aw,
                                              float* __restrict__ o) {
    int qc = blockIdx.x & 3;
    int bh = blockIdx.x >> 2;
    int b = bh >> 2, h = bh & 3;
    __shared__ float qs[37][16];
    __shared__ float kT[16][152];
    __shared__ float vs[148][16];
    __shared__ float ps[4][152];
    int tid = threadIdx.x;
    const float* base = qkv + (size_t)b * 148 * 192 + h * 16;
    for (int idx = tid; idx < 148 * 16; idx += 256) {
        int i = idx >> 4, d = idx & 15;
        const float* p = base + (size_t)i * 192 + d;
        kT[d][i] = p[64];
        vs[i][d] = p[128];
    }
    int q0 = qc * 37;
    for (int idx = tid; idx < 37 * 16; idx += 256) {
        int i = idx >> 4, d = idx & 15;
        qs[i][d] = base[(size_t)(q0 + i) * 192 + d] * 0.25f;
    }
    __syncthreads();
    int wv = tid >> 6, lane = tid & 63;
    float* aw_bh = aw + (size_t)bh * 148 * 148;
    for (int ii = wv; ii < 37; ii += 4) {
        int i = q0 + ii;
        float s0 = 0.f, s1 = 0.f, s2 = 0.f;
#pragma unroll
        for (int d = 0; d < 16; ++d) {
            float q = qs[ii][d];
            s0 = fmaf(q, kT[d][lane], s0);
            s1 = fmaf(q, kT[d][lane + 64], s1);
            if (lane < 20) s2 = fmaf(q, kT[d][lane + 128], s2);
        }
        float m = fmaxf(s0, s1);
        if (lane < 20) m = fmaxf(m, s2);
#pragma unroll
        for (int off = 1; off < 64; off <<= 1) m = fmaxf(m, __shfl_xor(m, off));
        float e0 = __expf(s0 - m), e1 = __expf(s1 - m);
        float e2 = (lane < 20) ? __expf(s2 - m) : 0.f;
        float sum = e0 + e1 + e2;
#pragma unroll
        for (int off = 1; off < 64; off <<= 1) sum += __shfl_xor(sum, off);
        float inv = 1.f / sum;
        float p0 = e0 * inv, p1 = e1 * inv, p2 = e2 * inv;
        float* awr = aw_bh + (size_t)i * 148;
        awr[lane] = p0;
        awr[lane + 64] = p1;
        if (lane < 20) awr[lane + 128] = p2;
        ps[wv][lane] = p0;
        ps[wv][lane + 64] = p1;
        if (lane < 20) ps[wv][lane + 128] = p2;
        int d = lane & 15, jj = lane >> 4;
        float acc = 0.f;
        for (int t = jj; t < 148; t += 4) acc = fmaf(ps[wv][t], vs[t][d], acc);
        acc += __shfl_xor(acc, 16);
        acc += __shfl_xor(acc, 32);
        if (lane < 16) o[((size_t)b * 148 + i) * 64 + h * 16 + d] = acc;
    }
}

// ---------------- fused GEMM + bias + residual + LayerNorm (K=M=64) ----------------
__global__ __launch_bounds__(256) void k_ln_gemm(const float* __restrict__ X, const float* __restrict__ Wt,
                                                 const float* __restrict__ bias, const float* __restrict__ resid,
                                                 const float* __restrict__ g, const float* __restrict__ bb,
                                                 float* __restrict__ Y, int N) {
    __shared__ float Wl[4096];
    for (int idx = threadIdx.x; idx < 4096; idx += 256) Wl[idx] = Wt[idx];
    __syncthreads();
    int lane = threadIdx.x & 63;
    int gw = blockIdx.x * 4 + (threadIdx.x >> 6);
    int tw = gridDim.x * 4;
    for (int row = gw; row < N; row += tw) {
        const float4* xr = (const float4*)(X + (size_t)row * 64);
        float acc = 0.f;
        for (int k4 = 0; k4 < 16; ++k4) {
            float4 xv = xr[k4];
            const float* wp = Wl + (k4 * 4) * 64 + lane;
            acc = fmaf(xv.x, wp[0], acc);
            acc = fmaf(xv.y, wp[64], acc);
            acc = fmaf(xv.z, wp[128], acc);
            acc = fmaf(xv.w, wp[192], acc);
        }
        float y = acc + bias[lane] + resid[(size_t)row * 64 + lane];
        float s = y;
#pragma unroll
        for (int off = 1; off < 64; off <<= 1) s += __shfl_xor(s, off);
        float mu = s * (1.f / 64.f);
        float dcen = y - mu;
        float v = dcen * dcen;
#pragma unroll
        for (int off = 1; off < 64; off <<= 1) v += __shfl_xor(v, off);
        float var = v * (1.f / 64.f);
        Y[(size_t)row * 64 + lane] = dcen * rsqrtf(var + 1e-5f) * g[lane] + bb[lane];
    }
}

// ---------------- classifier stage A ----------------
__global__ __launch_bounds__(256) void k_cls_part(const float* __restrict__ T, const float* __restrict__ Wc1,
                                                  float* __restrict__ Zp) {
    int ks = blockIdx.x >> 2;
    int mt = blockIdx.x & 3;
    int k0 = ks * 74;
    int m0 = mt * 256;
    __shared__ float Tl[64][74];
    int tid = threadIdx.x;
    for (int idx = tid; idx < 64 * 74; idx += 256) {
        int b = idx / 74, kk = idx - b * 74;
        Tl[b][kk] = T[(size_t)b * 9472 + k0 + kk];
    }
    __syncthreads();
    int lane = tid & 63, bq = tid >> 6;
    int mbase = m0 + lane * 4;
    size_t moff = (mbase + 3 < 1000) ? (size_t)mbase : 0;
    float4 acc[16];
#pragma unroll
    for (int j = 0; j < 16; ++j) acc[j] = make_float4(0.f, 0.f, 0.f, 0.f);
#pragma unroll 2
    for (int kk = 0; kk < 74; ++kk) {
        float4 w = *(const float4*)(Wc1 + (size_t)(k0 + kk) * 1000 + moff);
#pragma unroll
        for (int j = 0; j < 16; ++j) {
            float t = Tl[bq * 16 + j][kk];
            acc[j].x = fmaf(t, w.x, acc[j].x);
            acc[j].y = fmaf(t, w.y, acc[j].y);
            acc[j].z = fmaf(t, w.z, acc[j].z);
            acc[j].w = fmaf(t, w.w, acc[j].w);
        }
    }
    float* zp = Zp + (size_t)ks * 64 * 1024;
#pragma unroll
    for (int j = 0; j < 16; ++j) {
        int b = bq * 16 + j;
        *(float4*)(zp + (size_t)b * 1024 + mbase) = acc[j];
    }
}

// ---------------- classifier stage B ----------------
__global__ __launch_bounds__(256) void k_cls_reduce(const float* __restrict__ Zp, const float* __restrict__ bc1,
                                                    const float* __restrict__ bn_g, const float* __restrict__ bn_b,
                                                    float* __restrict__ zb) {
    int flat = blockIdx.x * 256 + threadIdx.x;
    int b = flat >> 10, m = flat & 1023;
    if (m >= 1000) return;
    float s = 0.f;
    for (int ks = 0; ks < 128; ++ks)
        s += Zp[((size_t)ks * 64 + b) * 1024 + m];
    float rs = rsqrtf(1.0f + 1e-5f);
    float z = bn_g[m] * (s + bc1[m]) * rs + bn_b[m];
    zb[flat] = z >= 0.f ? z : 0.01f * z;
}

// ---------------- classifier finish ----------------
__global__ __launch_bounds__(256) void k_cls_final(const float* __restrict__ zb,
                                                   const float* __restrict__ Wc2, const float* __restrict__ bc2,
                                                   float* __restrict__ out) {
    int b = blockIdx.x;
    int tid = threadIdx.x;
    float a0 = 0.f, a1 = 0.f;
    for (int m = tid; m < 1000; m += 256) {
        float z = zb[b * 1024 + m];
        a0 = fmaf(z, Wc2[m * 2], a0);
        a1 = fmaf(z, Wc2[m * 2 + 1], a1);
    }
#pragma unroll
    for (int off = 1; off < 64; off <<= 1) {
        a0 += __shfl_xor(a0, off);
        a1 += __shfl_xor(a1, off);
    }
    __shared__ float r0[4], r1[4];
    if ((tid & 63) == 0) { r0[tid >> 6] = a0; r1[tid >> 6] = a1; }
    __syncthreads();
    if (tid == 0) {
        out[b * 2 + 0] = r0[0] + r0[1] + r0[2] + r0[3] + bc2[0];
        out[b * 2 + 1] = r1[0] + r1[1] + r1[2] + r1[3] + bc2[1];
    }
}

extern "C" void kernel_launch(void* const* d_in, const int* in_sizes, int n_in,
                              void* d_out, int out_size, void* d_ws, size_t ws_size,
                              hipStream_t stream) {
    (void)in_sizes; (void)n_in; (void)out_size; (void)ws_size;

    const float* x_feat = (const float*)d_in[0];
    const int* node_roi = (const int*)d_in[1];
    const int* ei1 = (const int*)d_in[3];
    const float* ew1 = (const float*)d_in[4];
    const float* x2f = (const float*)d_in[5];
    const int* ei2 = (const int*)d_in[8];
    const float* ew2 = (const float*)d_in[9];
    const float* Wg1 = (const float*)d_in[10];
    const float* bg1 = (const float*)d_in[11];
    const float* Wg2 = (const float*)d_in[12];
    const float* bg2 = (const float*)d_in[13];
    const float* Wr1 = (const float*)d_in[14];
    const float* br1 = (const float*)d_in[15];
    const float* Wr2 = (const float*)d_in[16];
    const float* br2 = (const float*)d_in[17];
    const float* in_proj_w = (const float*)d_in[18];
    const float* in_proj_b = (const float*)d_in[19];
    const float* out_proj_w = (const float*)d_in[20];
    const float* out_proj_b = (const float*)d_in[21];
    const float* ln1_g = (const float*)d_in[22];
    const float* ln1_b = (const float*)d_in[23];
    const float* ff_w1 = (const float*)d_in[24];
    const float* ff_b1 = (const float*)d_in[25];
    const float* ff_w2 = (const float*)d_in[26];
    const float* ff_b2 = (const float*)d_in[27];
    const float* ln2_g = (const float*)d_in[28];
    const float* ln2_b = (const float*)d_in[29];
    const float* Wc1 = (const float*)d_in[30];
    const float* bc1 = (const float*)d_in[31];
    const float* bn_g = (const float*)d_in[32];
    const float* bn_b = (const float*)d_in[33];
    const float* Wc2 = (const float*)d_in[34];
    const float* bc2 = (const float*)d_in[35];

    const int* src1 = ei1;
    const int* dst1 = ei1 + E1v;
    const int* src2 = ei2;
    const int* dst2 = ei2 + E2v;

    float* out = (float*)d_out;
    const int PSZ = BRv * 64;
    float* pooled_out = out + 128;
    float* pooledroi_out = out + 128 + PSZ;
    float* tout_out = out + 128 + 2 * PSZ;
    float* attn_out = out + 128 + 3 * PSZ;

    // ===== workspace layout (floats) =====
    float* W = (float*)d_ws;
    size_t o = 0;
    int* bcnt1 = (int*)(W + o);  o += NBK1;
    int* bcnt2 = (int*)(W + o);  o += 128;
    size_t zone_elems = o;
    int* bb1 = (int*)(W + o);  o += NBK1 + 4;
    int* cur1 = (int*)(W + o); o += NBK1;
    int* bb2 = (int*)(W + o);  o += 76;
    int* cur2 = (int*)(W + o); o += 128;
    o = (o + 1) & ~(size_t)1;
    int2* snC1 = (int2*)(W + o); o += (size_t)E1v * 2;
    int2* snC2 = (int2*)(W + o); o += (size_t)E2v * 2;
    float* dinv1 = W + o;        o += N1v;
    float* dinv2 = W + o;        o += N2v;
    int* offs1 = (int*)(W + o);  o += N1v;
    int* offs2 = (int*)(W + o);  o += N2v;
    int* offs_p = (int*)(W + o); o += NSEG;
    int* nodeC = (int*)(W + o);  o += N1v;
    float* zbuf = W + o;         o += BBv * 1024;
    o = (o + 1) & ~(size_t)1;
    size_t h1P_off = o; o += (size_t)N1v * 64;
    size_t h1A_off = o; o += (size_t)N1v * 64;
    ushort_t* h1P = (ushort_t*)(W + h1P_off);
    ushort_t* h1Ab = (ushort_t*)(W + h1A_off);
    u64* rb1 = (u64*)(W + h1P_off);
    u64* rb2 = rb1 + E1v;
    size_t p = h1P_off;
    ushort_t* h2P = (ushort_t*)(W + p);  p += (size_t)N2v * 64;
    ushort_t* h2Ab = (ushort_t*)(W + p); p += (size_t)N2v * 64;
    float* comb = W + p; p += PSZ;
    float* qkvb = W + p; p += (size_t)BRv * 192;
    float* obuf = W + p; p += PSZ;
    float* xbuf = W + p; p += PSZ;
    float* f1 = W + p;   p += PSZ;
    float* WinT = W + p; p += 64 * 192;
    float* WoutT = W + p; p += 64 * 64;
    float* Zp = W + h1A_off;

    dim3 blk(256);

    hipMemsetAsync(W, 0, zone_elems * sizeof(float), stream);

    // ===== atomic-free CSR build (both branches) =====
    k_binA<<<E1v / EPB + E2v / EPB, blk, 0, stream>>>(dst1, bcnt1, dst2, bcnt2);
    k_scanAB<<<1, blk, 0, stream>>>(bcnt1, bb1, cur1, bcnt2, bb2, cur2);
    k_binB<<<E1v / EPB + E2v / EPB, blk, 0, stream>>>(src1, dst1, ew1, cur1, rb1,
                                                      src2, dst2, ew2, cur2, rb2);
    k_csrC<BINS1, CAP1, SH1><<<NBK1, blk, CAP1 * 8, stream>>>(rb1, bb1, dinv1, offs1, snC1);
    k_csrC<BINS2, CAP2, SH2><<<NBK2, blk, CAP2 * 8, stream>>>(rb2, bb2, dinv2, offs2, snC2);
    k_pool_csr<<<BBv, blk, 0, stream>>>(node_roi, offs_p, nodeC);

    // ===== branch 1 layers =====
    k_gemm_mfma<false, false><<<2048, blk, 0, stream>>>(x_feat, Wg1, h1P, N1v);
    k_edge_gather3<<<4096, blk, 0, stream>>>(snC1, offs1, h1P, dinv1, bg1, h1Ab, N1v, E1v);
    k_gemm_mfma<true, true><<<2048, blk, 0, stream>>>(h1Ab, Wg2, h1P, N1v);
    k_edge_gather3<<<4096, blk, 0, stream>>>(snC1, offs1, h1P, dinv1, bg2, h1Ab, N1v, E1v);
    k_pool_gather<<<2048, blk, 0, stream>>>(nodeC, offs_p, h1Ab, pooled_out);

    // ===== branch 2 layers =====
    k_gemm_rowwave<1, false, false, true><<<cdiv(N2v, 4), blk, 148 * 64 * 4, stream>>>(x2f, Wr1, nullptr, h2P, N2v, 148);
    k_edge_gather3<<<cdiv(N2v, 8), blk, 0, stream>>>(snC2, offs2, h2P, dinv2, br1, h2Ab, N2v, E2v);
    k_gemm_mfma<true, true><<<148, blk, 0, stream>>>(h2Ab, Wr2, h2P, N2v);
    k_edge_gather3<<<cdiv(N2v, 8), blk, 0, stream>>>(snC2, offs2, h2P, dinv2, br2, h2Ab, N2v, E2v);
    k_pool_fin2b<<<cdiv(PSZ / 4, 256), blk, 0, stream>>>(h2Ab, pooled_out, pooledroi_out, comb, PSZ / 4);

    // ===== transformer =====
    k_transpose2<<<cdiv(192 * 64 + 64 * 64, 256), blk, 0, stream>>>(in_proj_w, WinT, out_proj_w, WoutT);
    k_gemm_rowwave<3, false, false, false><<<cdiv(N2v, 4), blk, 64 * 192 * 4, stream>>>(comb, WinT, in_proj_b, qkvb, N2v, 64);
    k_attn<<<BBv * 4 * 4, blk, 0, stream>>>(qkvb, attn_out, obuf);
    k_ln_gemm<<<cdiv(N2v, 4), blk, 0, stream>>>(obuf, WoutT, out_proj_b, comb, ln1_g, ln1_b, xbuf, N2v);
    k_gemm_rowwave<1, false, true, false><<<cdiv(N2v, 4), blk, 64 * 64 * 4, stream>>>(xbuf, ff_w1, ff_b1, f1, N2v, 64);
    k_ln_gemm<<<cdiv(N2v, 4), blk, 0, stream>>>(f1, ff_w2, ff_b2, xbuf, ln2_g, ln2_b, tout_out, N2v);

    // ===== classifier =====
    k_cls_part<<<512, blk, 0, stream>>>(tout_out, Wc1, Zp);
    k_cls_reduce<<<BBv * 1024 / 256, blk, 0, stream>>>(Zp, bc1, bn_g, bn_b, zbuf);
    k_cls_final<<<BBv, blk, 0, stream>>>(zbuf, Wc2, bc2, out);
}

// Round 14
// 435.032 us; speedup vs baseline: 1.0592x; 1.0592x over previous
//
#include <hip/hip_runtime.h>
#include <cstdint>
#include <cstddef>

#define N1v 262144
#define E1v 1048576
#define N2v 9472
#define E2v 262144
#define BBv 64
#define RRv 148
#define HIDv 1000
#define BRv (BBv * RRv)
#define NSEG 9472
#define EPB 4096
#define NBK1 256
#define SH1 10
#define BINS1 1024
#define CAP1 4864
#define NBK2 74
#define SH2 7
#define BINS2 128
#define CAP2 4096

__host__ __device__ constexpr int cdiv(int a, int b) { return (a + b - 1) / b; }

typedef __attribute__((ext_vector_type(8))) short bf16x8;
typedef __attribute__((ext_vector_type(4))) float f32x4;
typedef unsigned short ushort_t;
typedef unsigned long long u64;

__device__ inline short f2bf(float f) {
    union { float f; unsigned u; } v; v.f = f;
    unsigned r = v.u + 0x7fff + ((v.u >> 16) & 1);   // RNE
    return (short)(r >> 16);
}
__device__ inline float bf2f(unsigned hs) {
    union { unsigned u; float f; } v; v.u = hs << 16; return v.f;
}
__device__ inline unsigned relu_pk(unsigned u) {
    unsigned r = u;
    if (r & 0x8000u) r &= 0xFFFF0000u;
    if (r & 0x80000000u) r &= 0x0000FFFFu;
    return r;
}

// ---------------- pass A: coarse bucket histogram (both branches) ----------------
__global__ __launch_bounds__(256) void k_binA(const int* __restrict__ dst1, int* __restrict__ bc1,
                                              const int* __restrict__ dst2, int* __restrict__ bc2) {
    int bid = blockIdx.x;
    const int* dst; int* bc; int nbk, sh, e0;
    if (bid < E1v / EPB) { dst = dst1; bc = bc1; nbk = NBK1; sh = SH1; e0 = bid * EPB; }
    else { dst = dst2; bc = bc2; nbk = NBK2; sh = SH2; e0 = (bid - E1v / EPB) * EPB; }
    __shared__ int h[256];
    int tid = threadIdx.x;
    if (tid < nbk) h[tid] = 0;
    __syncthreads();
    for (int t = tid; t < EPB; t += 256) atomicAdd(&h[dst[e0 + t] >> sh], 1);
    __syncthreads();
    if (tid < nbk && h[tid]) atomicAdd(&bc[tid], h[tid]);
}

// ---------------- scan bucket totals -> bases + cursors ----------------
__global__ __launch_bounds__(256) void k_scanAB(const int* __restrict__ bc1, int* __restrict__ bb1, int* __restrict__ cur1,
                                                const int* __restrict__ bc2, int* __restrict__ bb2, int* __restrict__ cur2) {
    __shared__ int tmp[256];
    int t = threadIdx.x;
    int v = bc1[t];
    tmp[t] = v; __syncthreads();
    int val = v;
    for (int off = 1; off < 256; off <<= 1) { int o = (t >= off) ? tmp[t - off] : 0; __syncthreads(); val += o; tmp[t] = val; __syncthreads(); }
    int excl = val - v;
    bb1[t] = excl; cur1[t] = excl;
    if (t == 255) bb1[256] = val;
    __syncthreads();
    int v2 = (t < NBK2) ? bc2[t] : 0;
    tmp[t] = v2; __syncthreads();
    int val2 = v2;
    for (int off = 1; off < 256; off <<= 1) { int o = (t >= off) ? tmp[t - off] : 0; __syncthreads(); val2 += o; tmp[t] = val2; __syncthreads(); }
    if (t < NBK2) { int e2 = val2 - v2; bb2[t] = e2; cur2[t] = e2; }
    if (t == NBK2 - 1) bb2[NBK2] = val2;
}

// ---------------- pass B: bucket-grouped record scatter (ew | src<<sh | dstlow) ----------------
__global__ __launch_bounds__(256) void k_binB(const int* __restrict__ src1, const int* __restrict__ dst1,
                                              const float* __restrict__ ew1, int* __restrict__ cur1, u64* __restrict__ rb1,
                                              const int* __restrict__ src2, const int* __restrict__ dst2,
                                              const float* __restrict__ ew2, int* __restrict__ cur2, u64* __restrict__ rb2) {
    int bid = blockIdx.x;
    const int* src; const int* dst; const float* ew; int* cur; u64* rb; int nbk, sh, e0;
    if (bid < E1v / EPB) { src = src1; dst = dst1; ew = ew1; cur = cur1; rb = rb1; nbk = NBK1; sh = SH1; e0 = bid * EPB; }
    else { src = src2; dst = dst2; ew = ew2; cur = cur2; rb = rb2; nbk = NBK2; sh = SH2; e0 = (bid - E1v / EPB) * EPB; }
    __shared__ int h[256], basg[256];
    int tid = threadIdx.x;
    if (tid < nbk) h[tid] = 0;
    __syncthreads();
    for (int t = tid; t < EPB; t += 256) atomicAdd(&h[dst[e0 + t] >> sh], 1);
    __syncthreads();
    if (tid < nbk) {
        int c = h[tid];
        basg[tid] = c ? atomicAdd(&cur[tid], c) : 0;
        h[tid] = 0;
    }
    __syncthreads();
    unsigned lowmask = (1u << sh) - 1u;
    for (int t = tid; t < EPB; t += 256) {
        int d = dst[e0 + t];
        int b = d >> sh;
        int r = atomicAdd(&h[b], 1);
        unsigned lo = ((unsigned)src[e0 + t] << sh) | ((unsigned)d & lowmask);
        rb[(size_t)basg[b] + r] = ((u64)(unsigned)__float_as_int(ew[e0 + t]) << 32) | lo;
    }
}

// ---------------- pass C: per-bucket CSR build (offs + dinv + (src,ew) records) ----------------
template<int BINS, int CAP, int SH>
__global__ __launch_bounds__(256) void k_csrC(const u64* __restrict__ rb, const int* __restrict__ bb,
                                              float* __restrict__ dinv, int* __restrict__ offs,
                                              int2* __restrict__ snC) {
    int b = blockIdx.x;
    int beg = bb[b], end = bb[b + 1], cnt = end - beg;
    __shared__ int hist[BINS];
    __shared__ float degs[BINS];
    __shared__ int scn[BINS];
    __shared__ int tmp[256];
    extern __shared__ int2 outb[];
    int tid = threadIdx.x;
    for (int i = tid; i < BINS; i += 256) { hist[i] = 0; degs[i] = 0.f; }
    __syncthreads();
    for (int j = beg + tid; j < end; j += 256) {
        u64 rec = rb[j];
        int bin = (int)((unsigned)rec & (BINS - 1));
        float w = __int_as_float((int)(rec >> 32));
        atomicAdd(&hist[bin], 1);
        atomicAdd(&degs[bin], w);
    }
    __syncthreads();
    constexpr int PER = (BINS + 255) / 256;
    int lv[PER];
    int tsum = 0;
    int base_i = tid * PER;
#pragma unroll
    for (int k = 0; k < PER; ++k) { int idx = base_i + k; lv[k] = (idx < BINS) ? hist[idx] : 0; tsum += lv[k]; }
    tmp[tid] = tsum; __syncthreads();
    int val = tsum;
    for (int off = 1; off < 256; off <<= 1) { int o = (tid >= off) ? tmp[tid - off] : 0; __syncthreads(); val += o; tmp[tid] = val; __syncthreads(); }
    int run = val - tsum;
#pragma unroll
    for (int k = 0; k < PER; ++k) { int idx = base_i + k; if (idx < BINS) { scn[idx] = run; run += lv[k]; } }
    __syncthreads();
    for (int i = tid; i < BINS; i += 256) {
        offs[b * BINS + i] = beg + scn[i];
        dinv[b * BINS + i] = rsqrtf(degs[i] + 1.0f);
    }
    __syncthreads();
    bool staged = (cnt <= CAP);
    for (int j = beg + tid; j < end; j += 256) {
        u64 rec = rb[j];
        unsigned lo = (unsigned)rec;
        int bin = (int)(lo & (BINS - 1));
        int s = (int)(lo >> SH);
        int wbits = (int)(rec >> 32);
        int r = atomicAdd(&scn[bin], 1);
        int2 o2 = make_int2(s, wbits);
        if (staged) outb[r] = o2;
        else snC[(size_t)beg + r] = o2;
    }
    __syncthreads();
    if (staged) {
        for (int j = tid; j < cnt; j += 256) snC[(size_t)beg + j] = outb[j];
    }
}

// ---------------- block-local pool CSR ----------------
__global__ __launch_bounds__(256) void k_pool_csr(const int* __restrict__ roi, int* __restrict__ offs_p,
                                                  int* __restrict__ nodeC) {
    int b = blockIdx.x;
    __shared__ int rl[4096];
    __shared__ int hist[RRv];
    __shared__ int curs[RRv];
    int tid = threadIdx.x;
    for (int t = tid; t < RRv; t += 256) hist[t] = 0;
    __syncthreads();
    int base = b * 4096;
    for (int t = tid; t < 4096; t += 256) {
        int r = roi[base + t];
        rl[t] = r;
        atomicAdd(&hist[r], 1);
    }
    __syncthreads();
    if (tid < RRv) {
        int s = 0;
        for (int k = 0; k < tid; ++k) s += hist[k];
        curs[tid] = s;
        offs_p[b * RRv + tid] = base + s;
    }
    __syncthreads();
    for (int t = tid; t < 4096; t += 256) {
        int r = rl[t];
        int j = atomicAdd(&curs[r], 1);
        nodeC[base + j] = base + t;
    }
}

// ---------------- branch-1 pool gather: 2 segs x 4 slots x 8 lanes, uint4 loads ----------------
__global__ __launch_bounds__(256) void k_pool_gather(const int* __restrict__ nodeC, const int* __restrict__ offs,
                                                     const ushort_t* __restrict__ Ab, float* __restrict__ pooled) {
    int tid = threadIdx.x;
    int lane = tid & 63;
    int nh = lane >> 5;
    int slot = (lane >> 3) & 3;
    int f8 = lane & 7;
    int gw = blockIdx.x * 4 + (tid >> 6);
    int tw = gridDim.x * 4;
    for (int ss = gw * 2; ss < NSEG; ss += tw * 2) {
        int s = ss + nh;
        int beg = offs[s];
        int end = (s + 1 < NSEG) ? offs[s + 1] : N1v;
        float a0 = 0.f, a1 = 0.f, a2 = 0.f, a3 = 0.f, a4 = 0.f, a5 = 0.f, a6 = 0.f, a7 = 0.f;
        for (int j = beg + slot; j < end; j += 4) {
            int node = nodeC[j];
            uint4 v = *(const uint4*)(Ab + (size_t)node * 64 + f8 * 8);
            a0 += fmaxf(bf2f(v.x & 0xffffu), 0.f);
            a1 += fmaxf(bf2f(v.x >> 16), 0.f);
            a2 += fmaxf(bf2f(v.y & 0xffffu), 0.f);
            a3 += fmaxf(bf2f(v.y >> 16), 0.f);
            a4 += fmaxf(bf2f(v.z & 0xffffu), 0.f);
            a5 += fmaxf(bf2f(v.z >> 16), 0.f);
            a6 += fmaxf(bf2f(v.w & 0xffffu), 0.f);
            a7 += fmaxf(bf2f(v.w >> 16), 0.f);
        }
        a0 += __shfl_xor(a0, 8);  a1 += __shfl_xor(a1, 8);  a2 += __shfl_xor(a2, 8);  a3 += __shfl_xor(a3, 8);
        a4 += __shfl_xor(a4, 8);  a5 += __shfl_xor(a5, 8);  a6 += __shfl_xor(a6, 8);  a7 += __shfl_xor(a7, 8);
        a0 += __shfl_xor(a0, 16); a1 += __shfl_xor(a1, 16); a2 += __shfl_xor(a2, 16); a3 += __shfl_xor(a3, 16);
        a4 += __shfl_xor(a4, 16); a5 += __shfl_xor(a5, 16); a6 += __shfl_xor(a6, 16); a7 += __shfl_xor(a7, 16);
        if (slot == 0) {
            float inv = 1.f / (float)max(end - beg, 1);
            float4 r0, r1;
            r0.x = a0 * inv; r0.y = a1 * inv; r0.z = a2 * inv; r0.w = a3 * inv;
            r1.x = a4 * inv; r1.y = a5 * inv; r1.z = a6 * inv; r1.w = a7 * inv;
            *(float4*)(pooled + (size_t)s * 64 + f8 * 8) = r0;
            *(float4*)(pooled + (size_t)s * 64 + f8 * 8 + 4) = r1;
        }
    }
}

// ---------------- edge gather v3: 2 nodes x 4 edge-slots x 8 lanes, bf16 P in, bf16 A out ----------------
__global__ __launch_bounds__(256) void k_edge_gather3(const int2* __restrict__ snC,
                                                      const int* __restrict__ offs, const ushort_t* __restrict__ Pb,
                                                      const float* __restrict__ dinv, const float* __restrict__ bias,
                                                      ushort_t* __restrict__ A, int N, int E) {
    int tid = threadIdx.x;
    int lane = tid & 63;
    int nh = lane >> 5;
    int slot = (lane >> 3) & 3;
    int f8 = lane & 7;
    float4 bv0 = *(const float4*)(bias + f8 * 8);
    float4 bv1 = *(const float4*)(bias + f8 * 8 + 4);
    int gw = blockIdx.x * 4 + (tid >> 6);
    int tw = gridDim.x * 4;
    for (int ii = gw * 2; ii < N; ii += tw * 2) {
        int i = ii + nh;
        int beg = offs[i];
        int end = (i + 1 < N) ? offs[i + 1] : E;
        float di = dinv[i];
        float a0 = 0.f, a1 = 0.f, a2 = 0.f, a3 = 0.f, a4 = 0.f, a5 = 0.f, a6 = 0.f, a7 = 0.f;
        for (int j = beg + slot; j < end; j += 4) {
            int2 e = snC[j];
            int s = e.x;
            float nv = dinv[s] * __int_as_float(e.y) * di;
            uint4 w = *(const uint4*)(Pb + (size_t)s * 64 + f8 * 8);
            a0 = fmaf(nv, bf2f(w.x & 0xffffu), a0);
            a1 = fmaf(nv, bf2f(w.x >> 16), a1);
            a2 = fmaf(nv, bf2f(w.y & 0xffffu), a2);
            a3 = fmaf(nv, bf2f(w.y >> 16), a3);
            a4 = fmaf(nv, bf2f(w.z & 0xffffu), a4);
            a5 = fmaf(nv, bf2f(w.z >> 16), a5);
            a6 = fmaf(nv, bf2f(w.w & 0xffffu), a6);
            a7 = fmaf(nv, bf2f(w.w >> 16), a7);
        }
        a0 += __shfl_xor(a0, 8);  a1 += __shfl_xor(a1, 8);  a2 += __shfl_xor(a2, 8);  a3 += __shfl_xor(a3, 8);
        a4 += __shfl_xor(a4, 8);  a5 += __shfl_xor(a5, 8);  a6 += __shfl_xor(a6, 8);  a7 += __shfl_xor(a7, 8);
        a0 += __shfl_xor(a0, 16); a1 += __shfl_xor(a1, 16); a2 += __shfl_xor(a2, 16); a3 += __shfl_xor(a3, 16);
        a4 += __shfl_xor(a4, 16); a5 += __shfl_xor(a5, 16); a6 += __shfl_xor(a6, 16); a7 += __shfl_xor(a7, 16);
        if (slot == 0) {
            uint4 w = *(const uint4*)(Pb + (size_t)i * 64 + f8 * 8);
            float s2 = di * di;
            float r0 = fmaf(s2, bf2f(w.x & 0xffffu), a0) + bv0.x;
            float r1 = fmaf(s2, bf2f(w.x >> 16),    a1) + bv0.y;
            float r2 = fmaf(s2, bf2f(w.y & 0xffffu), a2) + bv0.z;
            float r3 = fmaf(s2, bf2f(w.y >> 16),    a3) + bv0.w;
            float r4 = fmaf(s2, bf2f(w.z & 0xffffu), a4) + bv1.x;
            float r5 = fmaf(s2, bf2f(w.z >> 16),    a5) + bv1.y;
            float r6 = fmaf(s2, bf2f(w.w & 0xffffu), a6) + bv1.z;
            float r7 = fmaf(s2, bf2f(w.w >> 16),    a7) + bv1.w;
            uint4 ov;
            ov.x = (unsigned)(ushort_t)f2bf(r0) | ((unsigned)(ushort_t)f2bf(r1) << 16);
            ov.y = (unsigned)(ushort_t)f2bf(r2) | ((unsigned)(ushort_t)f2bf(r3) << 16);
            ov.z = (unsigned)(ushort_t)f2bf(r4) | ((unsigned)(ushort_t)f2bf(r5) << 16);
            ov.w = (unsigned)(ushort_t)f2bf(r6) | ((unsigned)(ushort_t)f2bf(r7) << 16);
            *(uint4*)(A + (size_t)i * 64 + f8 * 8) = ov;
        }
    }
}

// ---------------- MFMA bf16 GEMM ----------------
template<bool RIN, bool IBF16>
__global__ __launch_bounds__(256) void k_gemm_mfma(const void* __restrict__ Xv, const float* __restrict__ Wmat,
                                                   ushort_t* __restrict__ Y, int N) {
    int tid = threadIdx.x;
    int lane = tid & 63;
    int wv = tid >> 6;
    int l15 = lane & 15;
    int lg = lane >> 4;
    bf16x8 bfrag[2][4];
    for (int kh = 0; kh < 2; ++kh)
        for (int ct = 0; ct < 4; ++ct) {
            bf16x8 b;
#pragma unroll
            for (int i = 0; i < 8; ++i)
                b[i] = f2bf(Wmat[(size_t)(kh * 32 + lg * 8 + i) * 64 + ct * 16 + l15]);
            bfrag[kh][ct] = b;
        }
    int gw = blockIdx.x * 4 + wv;
    int tw = gridDim.x * 4;
    int ntiles = N >> 4;
    for (int t = gw; t < ntiles; t += tw) {
        int row0 = t << 4;
        bf16x8 af0, af1;
        if (IBF16) {
            const ushort_t* xp = (const ushort_t*)Xv + (size_t)(row0 + l15) * 64 + lg * 8;
            uint4 c0 = *(const uint4*)(xp);
            uint4 c1 = *(const uint4*)(xp + 32);
            if (RIN) {
                c0.x = relu_pk(c0.x); c0.y = relu_pk(c0.y); c0.z = relu_pk(c0.z); c0.w = relu_pk(c0.w);
                c1.x = relu_pk(c1.x); c1.y = relu_pk(c1.y); c1.z = relu_pk(c1.z); c1.w = relu_pk(c1.w);
            }
            af0 = *reinterpret_cast<bf16x8*>(&c0);
            af1 = *reinterpret_cast<bf16x8*>(&c1);
        } else {
            const float* xp = (const float*)Xv + (size_t)(row0 + l15) * 64 + lg * 8;
            float4 a0 = *(const float4*)(xp);
            float4 a1 = *(const float4*)(xp + 4);
            float4 a2 = *(const float4*)(xp + 32);
            float4 a3 = *(const float4*)(xp + 36);
            if (RIN) {
                a0.x = fmaxf(a0.x, 0.f); a0.y = fmaxf(a0.y, 0.f); a0.z = fmaxf(a0.z, 0.f); a0.w = fmaxf(a0.w, 0.f);
                a1.x = fmaxf(a1.x, 0.f); a1.y = fmaxf(a1.y, 0.f); a1.z = fmaxf(a1.z, 0.f); a1.w = fmaxf(a1.w, 0.f);
                a2.x = fmaxf(a2.x, 0.f); a2.y = fmaxf(a2.y, 0.f); a2.z = fmaxf(a2.z, 0.f); a2.w = fmaxf(a2.w, 0.f);
                a3.x = fmaxf(a3.x, 0.f); a3.y = fmaxf(a3.y, 0.f); a3.z = fmaxf(a3.z, 0.f); a3.w = fmaxf(a3.w, 0.f);
            }
            af0[0] = f2bf(a0.x); af0[1] = f2bf(a0.y); af0[2] = f2bf(a0.z); af0[3] = f2bf(a0.w);
            af0[4] = f2bf(a1.x); af0[5] = f2bf(a1.y); af0[6] = f2bf(a1.z); af0[7] = f2bf(a1.w);
            af1[0] = f2bf(a2.x); af1[1] = f2bf(a2.y); af1[2] = f2bf(a2.z); af1[3] = f2bf(a2.w);
            af1[4] = f2bf(a3.x); af1[5] = f2bf(a3.y); af1[6] = f2bf(a3.z); af1[7] = f2bf(a3.w);
        }
        f32x4 acc0 = {0.f, 0.f, 0.f, 0.f}, acc1 = acc0, acc2 = acc0, acc3 = acc0;
        acc0 = __builtin_amdgcn_mfma_f32_16x16x32_bf16(af0, bfrag[0][0], acc0, 0, 0, 0);
        acc1 = __builtin_amdgcn_mfma_f32_16x16x32_bf16(af0, bfrag[0][1], acc1, 0, 0, 0);
        acc2 = __builtin_amdgcn_mfma_f32_16x16x32_bf16(af0, bfrag[0][2], acc2, 0, 0, 0);
        acc3 = __builtin_amdgcn_mfma_f32_16x16x32_bf16(af0, bfrag[0][3], acc3, 0, 0, 0);
        acc0 = __builtin_amdgcn_mfma_f32_16x16x32_bf16(af1, bfrag[1][0], acc0, 0, 0, 0);
        acc1 = __builtin_amdgcn_mfma_f32_16x16x32_bf16(af1, bfrag[1][1], acc1, 0, 0, 0);
        acc2 = __builtin_amdgcn_mfma_f32_16x16x32_bf16(af1, bfrag[1][2], acc2, 0, 0, 0);
        acc3 = __builtin_amdgcn_mfma_f32_16x16x32_bf16(af1, bfrag[1][3], acc3, 0, 0, 0);
        ushort_t* yp = Y + (size_t)(row0 + lg * 4) * 64 + l15;
#pragma unroll
        for (int r = 0; r < 4; ++r) {
            yp[(size_t)r * 64 + 0]  = (ushort_t)f2bf(acc0[r]);
            yp[(size_t)r * 64 + 16] = (ushort_t)f2bf(acc1[r]);
            yp[(size_t)r * 64 + 32] = (ushort_t)f2bf(acc2[r]);
            yp[(size_t)r * 64 + 48] = (ushort_t)f2bf(acc3[r]);
        }
    }
}

// ---------------- row-per-wave GEMM ----------------
template<int MB, bool RIN, bool ROUT, bool OBF16>
__global__ __launch_bounds__(256) void k_gemm_rowwave(const float* __restrict__ X, const float* __restrict__ W,
                                                      const float* __restrict__ bias, void* __restrict__ Yv,
                                                      int N, int K) {
    extern __shared__ float Wl[];
    const int M = MB * 64;
    for (int idx = threadIdx.x; idx < K * M; idx += 256) Wl[idx] = W[idx];
    __syncthreads();
    int lane = threadIdx.x & 63;
    int gw = blockIdx.x * 4 + (threadIdx.x >> 6);
    int tw = gridDim.x * 4;
    const int K4 = K >> 2;
    for (int row = gw; row < N; row += tw) {
        float acc[MB];
#pragma unroll
        for (int cb = 0; cb < MB; ++cb) acc[cb] = 0.f;
        const float4* xr = (const float4*)(X + (size_t)row * K);
        for (int k4 = 0; k4 < K4; ++k4) {
            float4 xv = xr[k4];
            if (RIN) {
                xv.x = fmaxf(xv.x, 0.f); xv.y = fmaxf(xv.y, 0.f);
                xv.z = fmaxf(xv.z, 0.f); xv.w = fmaxf(xv.w, 0.f);
            }
            const float* wp = Wl + (k4 * 4) * M + lane;
#pragma unroll
            for (int cb = 0; cb < MB; ++cb) acc[cb] = fmaf(xv.x, wp[cb * 64], acc[cb]);
            wp += M;
#pragma unroll
            for (int cb = 0; cb < MB; ++cb) acc[cb] = fmaf(xv.y, wp[cb * 64], acc[cb]);
            wp += M;
#pragma unroll
            for (int cb = 0; cb < MB; ++cb) acc[cb] = fmaf(xv.z, wp[cb * 64], acc[cb]);
            wp += M;
#pragma unroll
            for (int cb = 0; cb < MB; ++cb) acc[cb] = fmaf(xv.w, wp[cb * 64], acc[cb]);
        }
#pragma unroll
        for (int cb = 0; cb < MB; ++cb) {
            float y = acc[cb];
            int col = cb * 64 + lane;
            if (bias) y += bias[col];
            if (ROUT) y = fmaxf(y, 0.f);
            if (OBF16) ((ushort_t*)Yv)[(size_t)row * M + col] = (ushort_t)f2bf(y);
            else ((float*)Yv)[(size_t)row * M + col] = y;
        }
    }
}

// ---------------- fused double transpose (in_proj 192x64, out_proj 64x64) ----------------
__global__ __launch_bounds__(256) void k_transpose2(const float* __restrict__ Win, float* __restrict__ WinT,
                                                    const float* __restrict__ Wout, float* __restrict__ WoutT) {
    int i = blockIdx.x * 256 + threadIdx.x;
    if (i < 192 * 64) {
        int r = i >> 6, c = i & 63;
        WinT[c * 192 + r] = Win[i];
    } else if (i < 192 * 64 + 64 * 64) {
        int j = i - 192 * 64;
        int r = j >> 6, c = j & 63;
        WoutT[c * 64 + r] = Wout[j];
    }
}

// ---------------- branch-2 pool (identity, bf16 in) + comb ----------------
__global__ __launch_bounds__(256) void k_pool_fin2b(const ushort_t* __restrict__ h2Ab, const float* __restrict__ pooled,
                                                    float* __restrict__ pooledroi, float* __restrict__ comb,
                                                    int n4) {
    int i = blockIdx.x * 256 + threadIdx.x;
    if (i < n4) {
        uint2 v = *(const uint2*)(h2Ab + (size_t)i * 4);
        float4 p = ((const float4*)pooled)[i];
        float4 r;
        r.x = fmaxf(bf2f(v.x & 0xffffu), 0.f);
        r.y = fmaxf(bf2f(v.x >> 16), 0.f);
        r.z = fmaxf(bf2f(v.y & 0xffffu), 0.f);
        r.w = fmaxf(bf2f(v.y >> 16), 0.f);
        ((float4*)pooledroi)[i] = r;
        float4 c;
        c.x = r.x + p.x; c.y = r.y + p.y; c.z = r.z + p.z; c.w = r.w + p.w;
        ((float4*)comb)[i] = c;
    }
}

// ---------------- attention ----------------
__global__ __launch_bounds__(256) void k_attn(const float* __restrict__ qkv, float* __restrict__ aw,
                                              float* __restrict__ o) {
    int qc = blockIdx.x & 3;
    int bh = blockIdx.x >> 2;
    int b = bh >> 2, h = bh & 3;
    __shared__ float qs[37][16];
    __shared__ float kT[16][152];
    __shared__ float vs[148][16];
    __shared__ float ps[4][152];
    int tid = threadIdx.x;
    const float* base = qkv + (size_t)b * 148 * 192 + h * 16;
    for (int idx = tid; idx < 148 * 16; idx += 256) {
        int i = idx >> 4, d = idx & 15;
        const float* p = base + (size_t)i * 192 + d;
        kT[d][i] = p[64];
        vs[i][d] = p[128];
    }
    int q0 = qc * 37;
    for (int idx = tid; idx < 37 * 16; idx += 256) {
        int i = idx >> 4, d = idx & 15;
        qs[i][d] = base[(size_t)(q0 + i) * 192 + d] * 0.25f;
    }
    __syncthreads();
    int wv = tid >> 6, lane = tid & 63;
    float* aw_bh = aw + (size_t)bh * 148 * 148;
    for (int ii = wv; ii < 37; ii += 4) {
        int i = q0 + ii;
        float s0 = 0.f, s1 = 0.f, s2 = 0.f;
#pragma unroll
        for (int d = 0; d < 16; ++d) {
            float q = qs[ii][d];
            s0 = fmaf(q, kT[d][lane], s0);
            s1 = fmaf(q, kT[d][lane + 64], s1);
            if (lane < 20) s2 = fmaf(q, kT[d][lane + 128], s2);
        }
        float m = fmaxf(s0, s1);
        if (lane < 20) m = fmaxf(m, s2);
#pragma unroll
        for (int off = 1; off < 64; off <<= 1) m = fmaxf(m, __shfl_xor(m, off));
        float e0 = __expf(s0 - m), e1 = __expf(s1 - m);
        float e2 = (lane < 20) ? __expf(s2 - m) : 0.f;
        float sum = e0 + e1 + e2;
#pragma unroll
        for (int off = 1; off < 64; off <<= 1) sum += __shfl_xor(sum, off);
        float inv = 1.f / sum;
        float p0 = e0 * inv, p1 = e1 * inv, p2 = e2 * inv;
        float* awr = aw_bh + (size_t)i * 148;
        awr[lane] = p0;
        awr[lane + 64] = p1;
        if (lane < 20) awr[lane + 128] = p2;
        ps[wv][lane] = p0;
        ps[wv][lane + 64] = p1;
        if (lane < 20) ps[wv][lane + 128] = p2;
        int d = lane & 15, jj = lane >> 4;
        float acc = 0.f;
        for (int t = jj; t < 148; t += 4) acc = fmaf(ps[wv][t], vs[t][d], acc);
        acc += __shfl_xor(acc, 16);
        acc += __shfl_xor(acc, 32);
        if (lane < 16) o[((size_t)b * 148 + i) * 64 + h * 16 + d] = acc;
    }
}

// ---------------- fused GEMM + bias + residual + LayerNorm (K=M=64) ----------------
__global__ __launch_bounds__(256) void k_ln_gemm(const float* __restrict__ X, const float* __restrict__ Wt,
                                                 const float* __restrict__ bias, const float* __restrict__ resid,
                                                 const float* __restrict__ g, const float* __restrict__ bb,
                                                 float* __restrict__ Y, int N) {
    __shared__ float Wl[4096];
    for (int idx = threadIdx.x; idx < 4096; idx += 256) Wl[idx] = Wt[idx];
    __syncthreads();
    int lane = threadIdx.x & 63;
    int gw = blockIdx.x * 4 + (threadIdx.x >> 6);
    int tw = gridDim.x * 4;
    for (int row = gw; row < N; row += tw) {
        const float4* xr = (const float4*)(X + (size_t)row * 64);
        float acc = 0.f;
        for (int k4 = 0; k4 < 16; ++k4) {
            float4 xv = xr[k4];
            const float* wp = Wl + (k4 * 4) * 64 + lane;
            acc = fmaf(xv.x, wp[0], acc);
            acc = fmaf(xv.y, wp[64], acc);
            acc = fmaf(xv.z, wp[128], acc);
            acc = fmaf(xv.w, wp[192], acc);
        }
        float y = acc + bias[lane] + resid[(size_t)row * 64 + lane];
        float s = y;
#pragma unroll
        for (int off = 1; off < 64; off <<= 1) s += __shfl_xor(s, off);
        float mu = s * (1.f / 64.f);
        float dcen = y - mu;
        float v = dcen * dcen;
#pragma unroll
        for (int off = 1; off < 64; off <<= 1) v += __shfl_xor(v, off);
        float var = v * (1.f / 64.f);
        Y[(size_t)row * 64 + lane] = dcen * rsqrtf(var + 1e-5f) * g[lane] + bb[lane];
    }
}

// ---------------- classifier stage A ----------------
__global__ __launch_bounds__(256) void k_cls_part(const float* __restrict__ T, const float* __restrict__ Wc1,
                                                  float* __restrict__ Zp) {
    int ks = blockIdx.x >> 2;
    int mt = blockIdx.x & 3;
    int k0 = ks * 74;
    int m0 = mt * 256;
    __shared__ float Tl[64][74];
    int tid = threadIdx.x;
    for (int idx = tid; idx < 64 * 74; idx += 256) {
        int b = idx / 74, kk = idx - b * 74;
        Tl[b][kk] = T[(size_t)b * 9472 + k0 + kk];
    }
    __syncthreads();
    int lane = tid & 63, bq = tid >> 6;
    int mbase = m0 + lane * 4;
    size_t moff = (mbase + 3 < 1000) ? (size_t)mbase : 0;
    float4 acc[16];
#pragma unroll
    for (int j = 0; j < 16; ++j) acc[j] = make_float4(0.f, 0.f, 0.f, 0.f);
#pragma unroll 2
    for (int kk = 0; kk < 74; ++kk) {
        float4 w = *(const float4*)(Wc1 + (size_t)(k0 + kk) * 1000 + moff);
#pragma unroll
        for (int j = 0; j < 16; ++j) {
            float t = Tl[bq * 16 + j][kk];
            acc[j].x = fmaf(t, w.x, acc[j].x);
            acc[j].y = fmaf(t, w.y, acc[j].y);
            acc[j].z = fmaf(t, w.z, acc[j].z);
            acc[j].w = fmaf(t, w.w, acc[j].w);
        }
    }
    float* zp = Zp + (size_t)ks * 64 * 1024;
#pragma unroll
    for (int j = 0; j < 16; ++j) {
        int b = bq * 16 + j;
        *(float4*)(zp + (size_t)b * 1024 + mbase) = acc[j];
    }
}

// ---------------- classifier stage B ----------------
__global__ __launch_bounds__(256) void k_cls_reduce(const float* __restrict__ Zp, const float* __restrict__ bc1,
                                                    const float* __restrict__ bn_g, const float* __restrict__ bn_b,
                                                    float* __restrict__ zb) {
    int flat = blockIdx.x * 256 + threadIdx.x;
    int b = flat >> 10, m = flat & 1023;
    if (m >= 1000) return;
    float s = 0.f;
    for (int ks = 0; ks < 128; ++ks)
        s += Zp[((size_t)ks * 64 + b) * 1024 + m];
    float rs = rsqrtf(1.0f + 1e-5f);
    float z = bn_g[m] * (s + bc1[m]) * rs + bn_b[m];
    zb[flat] = z >= 0.f ? z : 0.01f * z;
}

// ---------------- classifier finish ----------------
__global__ __launch_bounds__(256) void k_cls_final(const float* __restrict__ zb,
                                                   const float* __restrict__ Wc2, const float* __restrict__ bc2,
                                                   float* __restrict__ out) {
    int b = blockIdx.x;
    int tid = threadIdx.x;
    float a0 = 0.f, a1 = 0.f;
    for (int m = tid; m < 1000; m += 256) {
        float z = zb[b * 1024 + m];
        a0 = fmaf(z, Wc2[m * 2], a0);
        a1 = fmaf(z, Wc2[m * 2 + 1], a1);
    }
#pragma unroll
    for (int off = 1; off < 64; off <<= 1) {
        a0 += __shfl_xor(a0, off);
        a1 += __shfl_xor(a1, off);
    }
    __shared__ float r0[4], r1[4];
    if ((tid & 63) == 0) { r0[tid >> 6] = a0; r1[tid >> 6] = a1; }
    __syncthreads();
    if (tid == 0) {
        out[b * 2 + 0] = r0[0] + r0[1] + r0[2] + r0[3] + bc2[0];
        out[b * 2 + 1] = r1[0] + r1[1] + r1[2] + r1[3] + bc2[1];
    }
}

extern "C" void kernel_launch(void* const* d_in, const int* in_sizes, int n_in,
                              void* d_out, int out_size, void* d_ws, size_t ws_size,
                              hipStream_t stream) {
    (void)in_sizes; (void)n_in; (void)out_size; (void)ws_size;

    const float* x_feat = (const float*)d_in[0];
    const int* node_roi = (const int*)d_in[1];
    const int* ei1 = (const int*)d_in[3];
    const float* ew1 = (const float*)d_in[4];
    const float* x2f = (const float*)d_in[5];
    const int* ei2 = (const int*)d_in[8];
    const float* ew2 = (const float*)d_in[9];
    const float* Wg1 = (const float*)d_in[10];
    const float* bg1 = (const float*)d_in[11];
    const float* Wg2 = (const float*)d_in[12];
    const float* bg2 = (const float*)d_in[13];
    const float* Wr1 = (const float*)d_in[14];
    const float* br1 = (const float*)d_in[15];
    const float* Wr2 = (const float*)d_in[16];
    const float* br2 = (const float*)d_in[17];
    const float* in_proj_w = (const float*)d_in[18];
    const float* in_proj_b = (const float*)d_in[19];
    const float* out_proj_w = (const float*)d_in[20];
    const float* out_proj_b = (const float*)d_in[21];
    const float* ln1_g = (const float*)d_in[22];
    const float* ln1_b = (const float*)d_in[23];
    const float* ff_w1 = (const float*)d_in[24];
    const float* ff_b1 = (const float*)d_in[25];
    const float* ff_w2 = (const float*)d_in[26];
    const float* ff_b2 = (const float*)d_in[27];
    const float* ln2_g = (const float*)d_in[28];
    const float* ln2_b = (const float*)d_in[29];
    const float* Wc1 = (const float*)d_in[30];
    const float* bc1 = (const float*)d_in[31];
    const float* bn_g = (const float*)d_in[32];
    const float* bn_b = (const float*)d_in[33];
    const float* Wc2 = (const float*)d_in[34];
    const float* bc2 = (const float*)d_in[35];

    const int* src1 = ei1;
    const int* dst1 = ei1 + E1v;
    const int* src2 = ei2;
    const int* dst2 = ei2 + E2v;

    float* out = (float*)d_out;
    const int PSZ = BRv * 64;
    float* pooled_out = out + 128;
    float* pooledroi_out = out + 128 + PSZ;
    float* tout_out = out + 128 + 2 * PSZ;
    float* attn_out = out + 128 + 3 * PSZ;

    // ===== workspace layout (floats) =====
    float* W = (float*)d_ws;
    size_t o = 0;
    int* bcnt1 = (int*)(W + o);  o += 256;
    int* bcnt2 = (int*)(W + o);  o += 128;
    size_t zone_elems = o;
    int* bb1 = (int*)(W + o);  o += 260;
    int* cur1 = (int*)(W + o); o += 256;
    int* bb2 = (int*)(W + o);  o += 76;
    int* cur2 = (int*)(W + o); o += 128;
    o = (o + 1) & ~(size_t)1;
    int2* snC1 = (int2*)(W + o); o += (size_t)E1v * 2;
    int2* snC2 = (int2*)(W + o); o += (size_t)E2v * 2;
    float* dinv1 = W + o;        o += N1v;
    float* dinv2 = W + o;        o += N2v;
    int* offs1 = (int*)(W + o);  o += N1v;
    int* offs2 = (int*)(W + o);  o += N2v;
    int* offs_p = (int*)(W + o); o += NSEG;
    int* nodeC = (int*)(W + o);  o += N1v;
    float* zbuf = W + o;         o += BBv * 1024;
    o = (o + 1) & ~(size_t)1;
    size_t h1P_off = o; o += (size_t)N1v * 64;
    size_t h1A_off = o; o += (size_t)N1v * 64;
    ushort_t* h1P = (ushort_t*)(W + h1P_off);
    ushort_t* h1Ab = (ushort_t*)(W + h1A_off);
    u64* rb1 = (u64*)(W + h1P_off);
    u64* rb2 = rb1 + E1v;
    size_t p = h1P_off;
    ushort_t* h2P = (ushort_t*)(W + p);  p += (size_t)N2v * 64;
    ushort_t* h2Ab = (ushort_t*)(W + p); p += (size_t)N2v * 64;
    float* comb = W + p; p += PSZ;
    float* qkvb = W + p; p += (size_t)BRv * 192;
    float* obuf = W + p; p += PSZ;
    float* xbuf = W + p; p += PSZ;
    float* f1 = W + p;   p += PSZ;
    float* WinT = W + p; p += 64 * 192;
    float* WoutT = W + p; p += 64 * 64;
    float* Zp = W + h1A_off;

    dim3 blk(256);

    hipMemsetAsync(W, 0, zone_elems * sizeof(float), stream);

    // ===== atomic-free CSR build (both branches) =====
    k_binA<<<E1v / EPB + E2v / EPB, blk, 0, stream>>>(dst1, bcnt1, dst2, bcnt2);
    k_scanAB<<<1, blk, 0, stream>>>(bcnt1, bb1, cur1, bcnt2, bb2, cur2);
    k_binB<<<E1v / EPB + E2v / EPB, blk, 0, stream>>>(src1, dst1, ew1, cur1, rb1,
                                                      src2, dst2, ew2, cur2, rb2);
    k_csrC<BINS1, CAP1, SH1><<<NBK1, blk, CAP1 * 8, stream>>>(rb1, bb1, dinv1, offs1, snC1);
    k_csrC<BINS2, CAP2, SH2><<<NBK2, blk, CAP2 * 8, stream>>>(rb2, bb2, dinv2, offs2, snC2);
    k_pool_csr<<<BBv, blk, 0, stream>>>(node_roi, offs_p, nodeC);

    // ===== branch 1 layers =====
    k_gemm_mfma<false, false><<<2048, blk, 0, stream>>>(x_feat, Wg1, h1P, N1v);
    k_edge_gather3<<<4096, blk, 0, stream>>>(snC1, offs1, h1P, dinv1, bg1, h1Ab, N1v, E1v);
    k_gemm_mfma<true, true><<<2048, blk, 0, stream>>>(h1Ab, Wg2, h1P, N1v);
    k_edge_gather3<<<4096, blk, 0, stream>>>(snC1, offs1, h1P, dinv1, bg2, h1Ab, N1v, E1v);
    k_pool_gather<<<2048, blk, 0, stream>>>(nodeC, offs_p, h1Ab, pooled_out);

    // ===== branch 2 layers =====
    k_gemm_rowwave<1, false, false, true><<<cdiv(N2v, 4), blk, 148 * 64 * 4, stream>>>(x2f, Wr1, nullptr, h2P, N2v, 148);
    k_edge_gather3<<<cdiv(N2v, 8), blk, 0, stream>>>(snC2, offs2, h2P, dinv2, br1, h2Ab, N2v, E2v);
    k_gemm_mfma<true, true><<<148, blk, 0, stream>>>(h2Ab, Wr2, h2P, N2v);
    k_edge_gather3<<<cdiv(N2v, 8), blk, 0, stream>>>(snC2, offs2, h2P, dinv2, br2, h2Ab, N2v, E2v);
    k_pool_fin2b<<<cdiv(PSZ / 4, 256), blk, 0, stream>>>(h2Ab, pooled_out, pooledroi_out, comb, PSZ / 4);

    // ===== transformer =====
    k_transpose2<<<cdiv(192 * 64 + 64 * 64, 256), blk, 0, stream>>>(in_proj_w, WinT, out_proj_w, WoutT);
    k_gemm_rowwave<3, false, false, false><<<cdiv(N2v, 4), blk, 64 * 192 * 4, stream>>>(comb, WinT, in_proj_b, qkvb, N2v, 64);
    k_attn<<<BBv * 4 * 4, blk, 0, stream>>>(qkvb, attn_out, obuf);
    k_ln_gemm<<<cdiv(N2v, 4), blk, 0, stream>>>(obuf, WoutT, out_proj_b, comb, ln1_g, ln1_b, xbuf, N2v);
    k_gemm_rowwave<1, false, true, false><<<cdiv(N2v, 4), blk, 64 * 64 * 4, stream>>>(xbuf, ff_w1, ff_b1, f1, N2v, 64);
    k_ln_gemm<<<cdiv(N2v, 4), blk, 0, stream>>>(f1, ff_w2, ff_b2, xbuf, ln2_g, ln2_b, tout_out, N2v);

    // ===== classifier =====
    k_cls_part<<<512, blk, 0, stream>>>(tout_out, Wc1, Zp);
    k_cls_reduce<<<BBv * 1024 / 256, blk, 0, stream>>>(Zp, bc1, bn_g, bn_b, zbuf);
    k_cls_final<<<BBv, blk, 0, stream>>>(zbuf, Wc2, bc2, out);
}

// Round 16
// 421.637 us; speedup vs baseline: 1.0929x; 1.0318x over previous
//
#include <hip/hip_runtime.h>
#include <cstdint>
#include <cstddef>

#define N1v 262144
#define E1v 1048576
#define N2v 9472
#define E2v 262144
#define BBv 64
#define RRv 148
#define HIDv 1000
#define BRv (BBv * RRv)
#define NSEG 9472
#define EPB 4096
#define NBK1 256
#define SH1 10
#define BINS1 1024
#define CAP1 4864
#define NBK2 74
#define SH2 7
#define BINS2 128
#define CAP2 4096
#define GB1 4096
#define GB2 1184
#define MB1 2048
#define MB2 148

__host__ __device__ constexpr int cdiv(int a, int b) { return (a + b - 1) / b; }

typedef __attribute__((ext_vector_type(8))) short bf16x8;
typedef __attribute__((ext_vector_type(4))) float f32x4;
typedef unsigned short ushort_t;
typedef unsigned long long u64;

__device__ inline short f2bf(float f) {
    union { float f; unsigned u; } v; v.f = f;
    unsigned r = v.u + 0x7fff + ((v.u >> 16) & 1);   // RNE
    return (short)(r >> 16);
}
__device__ inline float bf2f(unsigned hs) {
    union { unsigned u; float f; } v; v.u = hs << 16; return v.f;
}
__device__ inline unsigned relu_pk(unsigned u) {
    unsigned r = u;
    if (r & 0x8000u) r &= 0xFFFF0000u;
    if (r & 0x80000000u) r &= 0x0000FFFFu;
    return r;
}

// ---------------- pass A: coarse bucket histogram (both branches) ----------------
__global__ __launch_bounds__(256) void k_binA(const int* __restrict__ dst1, int* __restrict__ bc1,
                                              const int* __restrict__ dst2, int* __restrict__ bc2) {
    int bid = blockIdx.x;
    const int* dst; int* bc; int nbk, sh, e0;
    if (bid < E1v / EPB) { dst = dst1; bc = bc1; nbk = NBK1; sh = SH1; e0 = bid * EPB; }
    else { dst = dst2; bc = bc2; nbk = NBK2; sh = SH2; e0 = (bid - E1v / EPB) * EPB; }
    __shared__ int h[256];
    int tid = threadIdx.x;
    if (tid < nbk) h[tid] = 0;
    __syncthreads();
    for (int t = tid; t < EPB; t += 256) atomicAdd(&h[dst[e0 + t] >> sh], 1);
    __syncthreads();
    if (tid < nbk && h[tid]) atomicAdd(&bc[tid], h[tid]);
}

// ---------------- scan bucket totals -> bases + cursors ----------------
__global__ __launch_bounds__(256) void k_scanAB(const int* __restrict__ bc1, int* __restrict__ bb1, int* __restrict__ cur1,
                                                const int* __restrict__ bc2, int* __restrict__ bb2, int* __restrict__ cur2) {
    __shared__ int tmp[256];
    int t = threadIdx.x;
    int v = bc1[t];
    tmp[t] = v; __syncthreads();
    int val = v;
    for (int off = 1; off < 256; off <<= 1) { int o = (t >= off) ? tmp[t - off] : 0; __syncthreads(); val += o; tmp[t] = val; __syncthreads(); }
    int excl = val - v;
    bb1[t] = excl; cur1[t] = excl;
    if (t == 255) bb1[256] = val;
    __syncthreads();
    int v2 = (t < NBK2) ? bc2[t] : 0;
    tmp[t] = v2; __syncthreads();
    int val2 = v2;
    for (int off = 1; off < 256; off <<= 1) { int o = (t >= off) ? tmp[t - off] : 0; __syncthreads(); val2 += o; tmp[t] = val2; __syncthreads(); }
    if (t < NBK2) { int e2 = val2 - v2; bb2[t] = e2; cur2[t] = e2; }
    if (t == NBK2 - 1) bb2[NBK2] = val2;
}

// ---------------- pass B: bucket-grouped record scatter (ew | src<<sh | dstlow) ----------------
__global__ __launch_bounds__(256) void k_binB(const int* __restrict__ src1, const int* __restrict__ dst1,
                                              const float* __restrict__ ew1, int* __restrict__ cur1, u64* __restrict__ rb1,
                                              const int* __restrict__ src2, const int* __restrict__ dst2,
                                              const float* __restrict__ ew2, int* __restrict__ cur2, u64* __restrict__ rb2) {
    int bid = blockIdx.x;
    const int* src; const int* dst; const float* ew; int* cur; u64* rb; int nbk, sh, e0;
    if (bid < E1v / EPB) { src = src1; dst = dst1; ew = ew1; cur = cur1; rb = rb1; nbk = NBK1; sh = SH1; e0 = bid * EPB; }
    else { src = src2; dst = dst2; ew = ew2; cur = cur2; rb = rb2; nbk = NBK2; sh = SH2; e0 = (bid - E1v / EPB) * EPB; }
    __shared__ int h[256], basg[256];
    int tid = threadIdx.x;
    if (tid < nbk) h[tid] = 0;
    __syncthreads();
    for (int t = tid; t < EPB; t += 256) atomicAdd(&h[dst[e0 + t] >> sh], 1);
    __syncthreads();
    if (tid < nbk) {
        int c = h[tid];
        basg[tid] = c ? atomicAdd(&cur[tid], c) : 0;
        h[tid] = 0;
    }
    __syncthreads();
    unsigned lowmask = (1u << sh) - 1u;
    for (int t = tid; t < EPB; t += 256) {
        int d = dst[e0 + t];
        int b = d >> sh;
        int r = atomicAdd(&h[b], 1);
        unsigned lo = ((unsigned)src[e0 + t] << sh) | ((unsigned)d & lowmask);
        rb[(size_t)basg[b] + r] = ((u64)(unsigned)__float_as_int(ew[e0 + t]) << 32) | lo;
    }
}

// ---------------- pass C: per-bucket CSR build; snC.y = ew * dinv[d] ----------------
template<int BINS, int CAP, int SH>
__global__ __launch_bounds__(256) void k_csrC(const u64* __restrict__ rb, const int* __restrict__ bb,
                                              float* __restrict__ dinv, int* __restrict__ offs,
                                              int2* __restrict__ snC) {
    int b = blockIdx.x;
    int beg = bb[b], end = bb[b + 1], cnt = end - beg;
    __shared__ int hist[BINS];
    __shared__ float degs[BINS];
    __shared__ int scn[BINS];
    __shared__ int tmp[256];
    extern __shared__ int2 outb[];
    int tid = threadIdx.x;
    for (int i = tid; i < BINS; i += 256) { hist[i] = 0; degs[i] = 0.f; }
    __syncthreads();
    for (int j = beg + tid; j < end; j += 256) {
        u64 rec = rb[j];
        int bin = (int)((unsigned)rec & (BINS - 1));
        float w = __int_as_float((int)(rec >> 32));
        atomicAdd(&hist[bin], 1);
        atomicAdd(&degs[bin], w);
    }
    __syncthreads();
    constexpr int PER = (BINS + 255) / 256;
    int lv[PER];
    int tsum = 0;
    int base_i = tid * PER;
#pragma unroll
    for (int k = 0; k < PER; ++k) { int idx = base_i + k; lv[k] = (idx < BINS) ? hist[idx] : 0; tsum += lv[k]; }
    tmp[tid] = tsum; __syncthreads();
    int val = tsum;
    for (int off = 1; off < 256; off <<= 1) { int o = (tid >= off) ? tmp[tid - off] : 0; __syncthreads(); val += o; tmp[tid] = val; __syncthreads(); }
    int run = val - tsum;
#pragma unroll
    for (int k = 0; k < PER; ++k) { int idx = base_i + k; if (idx < BINS) { scn[idx] = run; run += lv[k]; } }
    __syncthreads();
    for (int i = tid; i < BINS; i += 256) {
        offs[b * BINS + i] = beg + scn[i];
        dinv[b * BINS + i] = rsqrtf(degs[i] + 1.0f);
    }
    __syncthreads();
    bool staged = (cnt <= CAP);
    for (int j = beg + tid; j < end; j += 256) {
        u64 rec = rb[j];
        unsigned lo = (unsigned)rec;
        int bin = (int)(lo & (BINS - 1));
        int s = (int)(lo >> SH);
        float w = __int_as_float((int)(rec >> 32));
        float wd = w * rsqrtf(degs[bin] + 1.0f);   // fold dinv[d]
        int r = atomicAdd(&scn[bin], 1);
        int2 o2 = make_int2(s, __float_as_int(wd));
        if (staged) outb[r] = o2;
        else snC[(size_t)beg + r] = o2;
    }
    __syncthreads();
    if (staged) {
        for (int j = tid; j < cnt; j += 256) snC[(size_t)beg + j] = outb[j];
    }
}

// ---------------- normfix: snC.y *= dinv[src] (both branches, one launch) ----------------
__global__ __launch_bounds__(256) void k_normfix(int2* __restrict__ snC1, const float* __restrict__ dinv1,
                                                 int2* __restrict__ snC2, const float* __restrict__ dinv2) {
    int bid = blockIdx.x;
    int2* snC; const float* dinv; int j;
    if (bid < E1v / 256) { snC = snC1; dinv = dinv1; j = bid * 256 + threadIdx.x; }
    else { snC = snC2; dinv = dinv2; j = (bid - E1v / 256) * 256 + threadIdx.x; }
    int2 e = snC[j];
    e.y = __float_as_int(dinv[e.x] * __int_as_float(e.y));
    snC[j] = e;
}

// ---------------- block-local pool CSR ----------------
__global__ __launch_bounds__(256) void k_pool_csr(const int* __restrict__ roi, int* __restrict__ offs_p,
                                                  int* __restrict__ nodeC) {
    int b = blockIdx.x;
    __shared__ int rl[4096];
    __shared__ int hist[RRv];
    __shared__ int curs[RRv];
    int tid = threadIdx.x;
    for (int t = tid; t < RRv; t += 256) hist[t] = 0;
    __syncthreads();
    int base = b * 4096;
    for (int t = tid; t < 4096; t += 256) {
        int r = roi[base + t];
        rl[t] = r;
        atomicAdd(&hist[r], 1);
    }
    __syncthreads();
    if (tid < RRv) {
        int s = 0;
        for (int k = 0; k < tid; ++k) s += hist[k];
        curs[tid] = s;
        offs_p[b * RRv + tid] = base + s;
    }
    __syncthreads();
    for (int t = tid; t < 4096; t += 256) {
        int r = rl[t];
        int j = atomicAdd(&curs[r], 1);
        nodeC[base + j] = base + t;
    }
}

// ---------------- fused pool: branch-1 mean-pool + branch-2 identity + comb ----------------
__global__ __launch_bounds__(256) void k_pool_all(const int* __restrict__ nodeC, const int* __restrict__ offs,
                                                  const ushort_t* __restrict__ Ab, const ushort_t* __restrict__ h2Ab,
                                                  float* __restrict__ pooled, float* __restrict__ pooledroi,
                                                  float* __restrict__ comb) {
    int tid = threadIdx.x;
    int lane = tid & 63;
    int nh = lane >> 5;
    int slot = (lane >> 3) & 3;
    int f8 = lane & 7;
    int gw = blockIdx.x * 4 + (tid >> 6);
    int tw = gridDim.x * 4;
    for (int ss = gw * 2; ss < NSEG; ss += tw * 2) {
        int s = ss + nh;
        int beg = offs[s];
        int end = (s + 1 < NSEG) ? offs[s + 1] : N1v;
        float a0 = 0.f, a1 = 0.f, a2 = 0.f, a3 = 0.f, a4 = 0.f, a5 = 0.f, a6 = 0.f, a7 = 0.f;
        for (int j = beg + slot; j < end; j += 4) {
            int node = nodeC[j];
            uint4 v = *(const uint4*)(Ab + (size_t)node * 64 + f8 * 8);
            a0 += fmaxf(bf2f(v.x & 0xffffu), 0.f);
            a1 += fmaxf(bf2f(v.x >> 16), 0.f);
            a2 += fmaxf(bf2f(v.y & 0xffffu), 0.f);
            a3 += fmaxf(bf2f(v.y >> 16), 0.f);
            a4 += fmaxf(bf2f(v.z & 0xffffu), 0.f);
            a5 += fmaxf(bf2f(v.z >> 16), 0.f);
            a6 += fmaxf(bf2f(v.w & 0xffffu), 0.f);
            a7 += fmaxf(bf2f(v.w >> 16), 0.f);
        }
        a0 += __shfl_xor(a0, 8);  a1 += __shfl_xor(a1, 8);  a2 += __shfl_xor(a2, 8);  a3 += __shfl_xor(a3, 8);
        a4 += __shfl_xor(a4, 8);  a5 += __shfl_xor(a5, 8);  a6 += __shfl_xor(a6, 8);  a7 += __shfl_xor(a7, 8);
        a0 += __shfl_xor(a0, 16); a1 += __shfl_xor(a1, 16); a2 += __shfl_xor(a2, 16); a3 += __shfl_xor(a3, 16);
        a4 += __shfl_xor(a4, 16); a5 += __shfl_xor(a5, 16); a6 += __shfl_xor(a6, 16); a7 += __shfl_xor(a7, 16);
        if (slot == 0) {
            float inv = 1.f / (float)max(end - beg, 1);
            float p0 = a0 * inv, p1 = a1 * inv, p2 = a2 * inv, p3 = a3 * inv;
            float p4 = a4 * inv, p5 = a5 * inv, p6 = a6 * inv, p7 = a7 * inv;
            uint4 v2 = *(const uint4*)(h2Ab + (size_t)s * 64 + f8 * 8);
            float q0 = fmaxf(bf2f(v2.x & 0xffffu), 0.f);
            float q1 = fmaxf(bf2f(v2.x >> 16), 0.f);
            float q2 = fmaxf(bf2f(v2.y & 0xffffu), 0.f);
            float q3 = fmaxf(bf2f(v2.y >> 16), 0.f);
            float q4 = fmaxf(bf2f(v2.z & 0xffffu), 0.f);
            float q5 = fmaxf(bf2f(v2.z >> 16), 0.f);
            float q6 = fmaxf(bf2f(v2.w & 0xffffu), 0.f);
            float q7 = fmaxf(bf2f(v2.w >> 16), 0.f);
            size_t bo = (size_t)s * 64 + f8 * 8;
            float4 t;
            t.x = p0; t.y = p1; t.z = p2; t.w = p3; *(float4*)(pooled + bo) = t;
            t.x = p4; t.y = p5; t.z = p6; t.w = p7; *(float4*)(pooled + bo + 4) = t;
            t.x = q0; t.y = q1; t.z = q2; t.w = q3; *(float4*)(pooledroi + bo) = t;
            t.x = q4; t.y = q5; t.z = q6; t.w = q7; *(float4*)(pooledroi + bo + 4) = t;
            t.x = p0 + q0; t.y = p1 + q1; t.z = p2 + q2; t.w = p3 + q3; *(float4*)(comb + bo) = t;
            t.x = p4 + q4; t.y = p5 + q5; t.z = p6 + q6; t.w = p7 + q7; *(float4*)(comb + bo + 4) = t;
        }
    }
}

// ---------------- gather body (norm fully precomputed in snC.y) ----------------
__device__ inline void gather_body(const int2* __restrict__ snC, const int* __restrict__ offs,
                                   const ushort_t* __restrict__ Pb, const float* __restrict__ dinv,
                                   const float* __restrict__ bias, ushort_t* __restrict__ A,
                                   int N, int E, int gw, int tw, int lane) {
    int nh = lane >> 5;
    int slot = (lane >> 3) & 3;
    int f8 = lane & 7;
    float4 bv0 = *(const float4*)(bias + f8 * 8);
    float4 bv1 = *(const float4*)(bias + f8 * 8 + 4);
    for (int ii = gw * 2; ii < N; ii += tw * 2) {
        int i = ii + nh;
        int beg = offs[i];
        int end = (i + 1 < N) ? offs[i + 1] : E;
        float a0 = 0.f, a1 = 0.f, a2 = 0.f, a3 = 0.f, a4 = 0.f, a5 = 0.f, a6 = 0.f, a7 = 0.f;
        for (int j = beg + slot; j < end; j += 4) {
            int2 e = snC[j];
            int s = e.x;
            float nv = __int_as_float(e.y);
            uint4 w = *(const uint4*)(Pb + (size_t)s * 64 + f8 * 8);
            a0 = fmaf(nv, bf2f(w.x & 0xffffu), a0);
            a1 = fmaf(nv, bf2f(w.x >> 16), a1);
            a2 = fmaf(nv, bf2f(w.y & 0xffffu), a2);
            a3 = fmaf(nv, bf2f(w.y >> 16), a3);
            a4 = fmaf(nv, bf2f(w.z & 0xffffu), a4);
            a5 = fmaf(nv, bf2f(w.z >> 16), a5);
            a6 = fmaf(nv, bf2f(w.w & 0xffffu), a6);
            a7 = fmaf(nv, bf2f(w.w >> 16), a7);
        }
        a0 += __shfl_xor(a0, 8);  a1 += __shfl_xor(a1, 8);  a2 += __shfl_xor(a2, 8);  a3 += __shfl_xor(a3, 8);
        a4 += __shfl_xor(a4, 8);  a5 += __shfl_xor(a5, 8);  a6 += __shfl_xor(a6, 8);  a7 += __shfl_xor(a7, 8);
        a0 += __shfl_xor(a0, 16); a1 += __shfl_xor(a1, 16); a2 += __shfl_xor(a2, 16); a3 += __shfl_xor(a3, 16);
        a4 += __shfl_xor(a4, 16); a5 += __shfl_xor(a5, 16); a6 += __shfl_xor(a6, 16); a7 += __shfl_xor(a7, 16);
        if (slot == 0) {
            uint4 w = *(const uint4*)(Pb + (size_t)i * 64 + f8 * 8);
            float di = dinv[i];
            float s2 = di * di;
            float r0 = fmaf(s2, bf2f(w.x & 0xffffu), a0) + bv0.x;
            float r1 = fmaf(s2, bf2f(w.x >> 16),    a1) + bv0.y;
            float r2 = fmaf(s2, bf2f(w.y & 0xffffu), a2) + bv0.z;
            float r3 = fmaf(s2, bf2f(w.y >> 16),    a3) + bv0.w;
            float r4 = fmaf(s2, bf2f(w.z & 0xffffu), a4) + bv1.x;
            float r5 = fmaf(s2, bf2f(w.z >> 16),    a5) + bv1.y;
            float r6 = fmaf(s2, bf2f(w.w & 0xffffu), a6) + bv1.z;
            float r7 = fmaf(s2, bf2f(w.w >> 16),    a7) + bv1.w;
            uint4 ov;
            ov.x = (unsigned)(ushort_t)f2bf(r0) | ((unsigned)(ushort_t)f2bf(r1) << 16);
            ov.y = (unsigned)(ushort_t)f2bf(r2) | ((unsigned)(ushort_t)f2bf(r3) << 16);
            ov.z = (unsigned)(ushort_t)f2bf(r4) | ((unsigned)(ushort_t)f2bf(r5) << 16);
            ov.w = (unsigned)(ushort_t)f2bf(r6) | ((unsigned)(ushort_t)f2bf(r7) << 16);
            *(uint4*)(A + (size_t)i * 64 + f8 * 8) = ov;
        }
    }
}

// ---------------- fused gather: branch1 + branch2 in one launch ----------------
__global__ __launch_bounds__(256) void k_gather_both(const int2* __restrict__ snC1, const int* __restrict__ offs1,
                                                     const ushort_t* __restrict__ P1, const float* __restrict__ dinv1,
                                                     const float* __restrict__ b1, ushort_t* __restrict__ A1,
                                                     const int2* __restrict__ snC2, const int* __restrict__ offs2,
                                                     const ushort_t* __restrict__ P2, const float* __restrict__ dinv2,
                                                     const float* __restrict__ b2, ushort_t* __restrict__ A2) {
    int tid = threadIdx.x;
    int lane = tid & 63;
    if (blockIdx.x < GB1)
        gather_body(snC1, offs1, P1, dinv1, b1, A1, N1v, E1v,
                    blockIdx.x * 4 + (tid >> 6), GB1 * 4, lane);
    else
        gather_body(snC2, offs2, P2, dinv2, b2, A2, N2v, E2v,
                    (blockIdx.x - GB1) * 4 + (tid >> 6), GB2 * 4, lane);
}

// ---------------- bf16 GEMM body (RIN=true, bf16 in/out) ----------------
__device__ inline void gemm_bf16_body(const ushort_t* __restrict__ X, const float* __restrict__ Wmat,
                                      ushort_t* __restrict__ Y, int N, int gw, int tw, int tid) {
    int lane = tid & 63;
    int l15 = lane & 15;
    int lg = lane >> 4;
    bf16x8 bfrag[2][4];
    for (int kh = 0; kh < 2; ++kh)
        for (int ct = 0; ct < 4; ++ct) {
            bf16x8 b;
#pragma unroll
            for (int i = 0; i < 8; ++i)
                b[i] = f2bf(Wmat[(size_t)(kh * 32 + lg * 8 + i) * 64 + ct * 16 + l15]);
            bfrag[kh][ct] = b;
        }
    int ntiles = N >> 4;
    for (int t = gw; t < ntiles; t += tw) {
        int row0 = t << 4;
        const ushort_t* xp = X + (size_t)(row0 + l15) * 64 + lg * 8;
        uint4 c0 = *(const uint4*)(xp);
        uint4 c1 = *(const uint4*)(xp + 32);
        c0.x = relu_pk(c0.x); c0.y = relu_pk(c0.y); c0.z = relu_pk(c0.z); c0.w = relu_pk(c0.w);
        c1.x = relu_pk(c1.x); c1.y = relu_pk(c1.y); c1.z = relu_pk(c1.z); c1.w = relu_pk(c1.w);
        bf16x8 af0 = *reinterpret_cast<bf16x8*>(&c0);
        bf16x8 af1 = *reinterpret_cast<bf16x8*>(&c1);
        f32x4 acc0 = {0.f, 0.f, 0.f, 0.f}, acc1 = acc0, acc2 = acc0, acc3 = acc0;
        acc0 = __builtin_amdgcn_mfma_f32_16x16x32_bf16(af0, bfrag[0][0], acc0, 0, 0, 0);
        acc1 = __builtin_amdgcn_mfma_f32_16x16x32_bf16(af0, bfrag[0][1], acc1, 0, 0, 0);
        acc2 = __builtin_amdgcn_mfma_f32_16x16x32_bf16(af0, bfrag[0][2], acc2, 0, 0, 0);
        acc3 = __builtin_amdgcn_mfma_f32_16x16x32_bf16(af0, bfrag[0][3], acc3, 0, 0, 0);
        acc0 = __builtin_amdgcn_mfma_f32_16x16x32_bf16(af1, bfrag[1][0], acc0, 0, 0, 0);
        acc1 = __builtin_amdgcn_mfma_f32_16x16x32_bf16(af1, bfrag[1][1], acc1, 0, 0, 0);
        acc2 = __builtin_amdgcn_mfma_f32_16x16x32_bf16(af1, bfrag[1][2], acc2, 0, 0, 0);
        acc3 = __builtin_amdgcn_mfma_f32_16x16x32_bf16(af1, bfrag[1][3], acc3, 0, 0, 0);
        ushort_t* yp = Y + (size_t)(row0 + lg * 4) * 64 + l15;
#pragma unroll
        for (int r = 0; r < 4; ++r) {
            yp[(size_t)r * 64 + 0]  = (ushort_t)f2bf(acc0[r]);
            yp[(size_t)r * 64 + 16] = (ushort_t)f2bf(acc1[r]);
            yp[(size_t)r * 64 + 32] = (ushort_t)f2bf(acc2[r]);
            yp[(size_t)r * 64 + 48] = (ushort_t)f2bf(acc3[r]);
        }
    }
}

// ---------------- fused layer-2 GEMM: branch1 + branch2 ----------------
__global__ __launch_bounds__(256) void k_gemm_both(const ushort_t* __restrict__ X1, const float* __restrict__ W1,
                                                   ushort_t* __restrict__ Y1,
                                                   const ushort_t* __restrict__ X2, const float* __restrict__ W2,
                                                   ushort_t* __restrict__ Y2) {
    int tid = threadIdx.x;
    if (blockIdx.x < MB1)
        gemm_bf16_body(X1, W1, Y1, N1v, blockIdx.x * 4 + (tid >> 6), MB1 * 4, tid);
    else
        gemm_bf16_body(X2, W2, Y2, N2v, (blockIdx.x - MB1) * 4 + (tid >> 6), MB2 * 4, tid);
}

// ---------------- MFMA bf16 GEMM, fp32 input (branch-1 layer 1) ----------------
__global__ __launch_bounds__(256) void k_gemm_mfma_f32(const float* __restrict__ X, const float* __restrict__ Wmat,
                                                       ushort_t* __restrict__ Y, int N) {
    int tid = threadIdx.x;
    int lane = tid & 63;
    int wv = tid >> 6;
    int l15 = lane & 15;
    int lg = lane >> 4;
    bf16x8 bfrag[2][4];
    for (int kh = 0; kh < 2; ++kh)
        for (int ct = 0; ct < 4; ++ct) {
            bf16x8 b;
#pragma unroll
            for (int i = 0; i < 8; ++i)
                b[i] = f2bf(Wmat[(size_t)(kh * 32 + lg * 8 + i) * 64 + ct * 16 + l15]);
            bfrag[kh][ct] = b;
        }
    int gw = blockIdx.x * 4 + wv;
    int tw = gridDim.x * 4;
    int ntiles = N >> 4;
    for (int t = gw; t < ntiles; t += tw) {
        int row0 = t << 4;
        const float* xp = X + (size_t)(row0 + l15) * 64 + lg * 8;
        float4 a0 = *(const float4*)(xp);
        float4 a1 = *(const float4*)(xp + 4);
        float4 a2 = *(const float4*)(xp + 32);
        float4 a3 = *(const float4*)(xp + 36);
        bf16x8 af0, af1;
        af0[0] = f2bf(a0.x); af0[1] = f2bf(a0.y); af0[2] = f2bf(a0.z); af0[3] = f2bf(a0.w);
        af0[4] = f2bf(a1.x); af0[5] = f2bf(a1.y); af0[6] = f2bf(a1.z); af0[7] = f2bf(a1.w);
        af1[0] = f2bf(a2.x); af1[1] = f2bf(a2.y); af1[2] = f2bf(a2.z); af1[3] = f2bf(a2.w);
        af1[4] = f2bf(a3.x); af1[5] = f2bf(a3.y); af1[6] = f2bf(a3.z); af1[7] = f2bf(a3.w);
        f32x4 acc0 = {0.f, 0.f, 0.f, 0.f}, acc1 = acc0, acc2 = acc0, acc3 = acc0;
        acc0 = __builtin_amdgcn_mfma_f32_16x16x32_bf16(af0, bfrag[0][0], acc0, 0, 0, 0);
        acc1 = __builtin_amdgcn_mfma_f32_16x16x32_bf16(af0, bfrag[0][1], acc1, 0, 0, 0);
        acc2 = __builtin_amdgcn_mfma_f32_16x16x32_bf16(af0, bfrag[0][2], acc2, 0, 0, 0);
        acc3 = __builtin_amdgcn_mfma_f32_16x16x32_bf16(af0, bfrag[0][3], acc3, 0, 0, 0);
        acc0 = __builtin_amdgcn_mfma_f32_16x16x32_bf16(af1, bfrag[1][0], acc0, 0, 0, 0);
        acc1 = __builtin_amdgcn_mfma_f32_16x16x32_bf16(af1, bfrag[1][1], acc1, 0, 0, 0);
        acc2 = __builtin_amdgcn_mfma_f32_16x16x32_bf16(af1, bfrag[1][2], acc2, 0, 0, 0);
        acc3 = __builtin_amdgcn_mfma_f32_16x16x32_bf16(af1, bfrag[1][3], acc3, 0, 0, 0);
        ushort_t* yp = Y + (size_t)(row0 + lg * 4) * 64 + l15;
#pragma unroll
        for (int r = 0; r < 4; ++r) {
            yp[(size_t)r * 64 + 0]  = (ushort_t)f2bf(acc0[r]);
            yp[(size_t)r * 64 + 16] = (ushort_t)f2bf(acc1[r]);
            yp[(size_t)r * 64 + 32] = (ushort_t)f2bf(acc2[r]);
            yp[(size_t)r * 64 + 48] = (ushort_t)f2bf(acc3[r]);
        }
    }
}

// ---------------- row-per-wave GEMM ----------------
template<int MB, bool RIN, bool ROUT, bool OBF16>
__global__ __launch_bounds__(256) void k_gemm_rowwave(const float* __restrict__ X, const float* __restrict__ W,
                                                      const float* __restrict__ bias, void* __restrict__ Yv,
                                                      int N, int K) {
    extern __shared__ float Wl[];
    const int M = MB * 64;
    for (int idx = threadIdx.x; idx < K * M; idx += 256) Wl[idx] = W[idx];
    __syncthreads();
    int lane = threadIdx.x & 63;
    int gw = blockIdx.x * 4 + (threadIdx.x >> 6);
    int tw = gridDim.x * 4;
    const int K4 = K >> 2;
    for (int row = gw; row < N; row += tw) {
        float acc[MB];
#pragma unroll
        for (int cb = 0; cb < MB; ++cb) acc[cb] = 0.f;
        const float4* xr = (const float4*)(X + (size_t)row * K);
        for (int k4 = 0; k4 < K4; ++k4) {
            float4 xv = xr[k4];
            if (RIN) {
                xv.x = fmaxf(xv.x, 0.f); xv.y = fmaxf(xv.y, 0.f);
                xv.z = fmaxf(xv.z, 0.f); xv.w = fmaxf(xv.w, 0.f);
            }
            const float* wp = Wl + (k4 * 4) * M + lane;
#pragma unroll
            for (int cb = 0; cb < MB; ++cb) acc[cb] = fmaf(xv.x, wp[cb * 64], acc[cb]);
            wp += M;
#pragma unroll
            for (int cb = 0; cb < MB; ++cb) acc[cb] = fmaf(xv.y, wp[cb * 64], acc[cb]);
            wp += M;
#pragma unroll
            for (int cb = 0; cb < MB; ++cb) acc[cb] = fmaf(xv.z, wp[cb * 64], acc[cb]);
            wp += M;
#pragma unroll
            for (int cb = 0; cb < MB; ++cb) acc[cb] = fmaf(xv.w, wp[cb * 64], acc[cb]);
        }
#pragma unroll
        for (int cb = 0; cb < MB; ++cb) {
            float y = acc[cb];
            int col = cb * 64 + lane;
            if (bias) y += bias[col];
            if (ROUT) y = fmaxf(y, 0.f);
            if (OBF16) ((ushort_t*)Yv)[(size_t)row * M + col] = (ushort_t)f2bf(y);
            else ((float*)Yv)[(size_t)row * M + col] = y;
        }
    }
}

// ---------------- fused double transpose ----------------
__global__ __launch_bounds__(256) void k_transpose2(const float* __restrict__ Win, float* __restrict__ WinT,
                                                    const float* __restrict__ Wout, float* __restrict__ WoutT) {
    int i = blockIdx.x * 256 + threadIdx.x;
    if (i < 192 * 64) {
        int r = i >> 6, c = i & 63;
        WinT[c * 192 + r] = Win[i];
    } else if (i < 192 * 64 + 64 * 64) {
        int j = i - 192 * 64;
        int r = j >> 6, c = j & 63;
        WoutT[c * 64 + r] = Wout[j];
    }
}

// ---------------- attention ----------------
__global__ __launch_bounds__(256) void k_attn(const float* __restrict__ qkv, float* __restrict__ aw,
                                              float* __restrict__ o) {
    int qc = blockIdx.x & 3;
    int bh = blockIdx.x >> 2;
    int b = bh >> 2, h = bh & 3;
    __shared__ float qs[37][16];
    __shared__ float kT[16][152];
    __shared__ float vs[148][16];
    __shared__ float ps[4][152];
    int tid = threadIdx.x;
    const float* base = qkv + (size_t)b * 148 * 192 + h * 16;
    for (int idx = tid; idx < 148 * 16; idx += 256) {
        int i = idx >> 4, d = idx & 15;
        const float* p = base + (size_t)i * 192 + d;
        kT[d][i] = p[64];
        vs[i][d] = p[128];
    }
    int q0 = qc * 37;
    for (int idx = tid; idx < 37 * 16; idx += 256) {
        int i = idx >> 4, d = idx & 15;
        qs[i][d] = base[(size_t)(q0 + i) * 192 + d] * 0.25f;
    }
    __syncthreads();
    int wv = tid >> 6, lane = tid & 63;
    float* aw_bh = aw + (size_t)bh * 148 * 148;
    for (int ii = wv; ii < 37; ii += 4) {
        int i = q0 + ii;
        float s0 = 0.f, s1 = 0.f, s2 = 0.f;
#pragma unroll
        for (int d = 0; d < 16; ++d) {
            float q = qs[ii][d];
            s0 = fmaf(q, kT[d][lane], s0);
            s1 = fmaf(q, kT[d][lane + 64], s1);
            if (lane < 20) s2 = fmaf(q, kT[d][lane + 128], s2);
        }
        float m = fmaxf(s0, s1);
        if (lane < 20) m = fmaxf(m, s2);
#pragma unroll
        for (int off = 1; off < 64; off <<= 1) m = fmaxf(m, __shfl_xor(m, off));
        float e0 = __expf(s0 - m), e1 = __expf(s1 - m);
        float e2 = (lane < 20) ? __expf(s2 - m) : 0.f;
        float sum = e0 + e1 + e2;
#pragma unroll
        for (int off = 1; off < 64; off <<= 1) sum += __shfl_xor(sum, off);
        float inv = 1.f / sum;
        float p0 = e0 * inv, p1 = e1 * inv, p2 = e2 * inv;
        float* awr = aw_bh + (size_t)i * 148;
        awr[lane] = p0;
        awr[lane + 64] = p1;
        if (lane < 20) awr[lane + 128] = p2;
        ps[wv][lane] = p0;
        ps[wv][lane + 64] = p1;
        if (lane < 20) ps[wv][lane + 128] = p2;
        int d = lane & 15, jj = lane >> 4;
        float acc = 0.f;
        for (int t = jj; t < 148; t += 4) acc = fmaf(ps[wv][t], vs[t][d], acc);
        acc += __shfl_xor(acc, 16);
        acc += __shfl_xor(acc, 32);
        if (lane < 16) o[((size_t)b * 148 + i) * 64 + h * 16 + d] = acc;
    }
}

// ---------------- fused GEMM + bias + residual + LayerNorm (K=M=64) ----------------
__global__ __launch_bounds__(256) void k_ln_gemm(const float* __restrict__ X, const float* __restrict__ Wt,
                                                 const float* __restrict__ bias, const float* __restrict__ resid,
                                                 const float* __restrict__ g, const float* __restrict__ bb,
                                                 float* __restrict__ Y, int N) {
    __shared__ float Wl[4096];
    for (int idx = threadIdx.x; idx < 4096; idx += 256) Wl[idx] = Wt[idx];
    __syncthreads();
    int lane = threadIdx.x & 63;
    int gw = blockIdx.x * 4 + (threadIdx.x >> 6);
    int tw = gridDim.x * 4;
    for (int row = gw; row < N; row += tw) {
        const float4* xr = (const float4*)(X + (size_t)row * 64);
        float acc = 0.f;
        for (int k4 = 0; k4 < 16; ++k4) {
            float4 xv = xr[k4];
            const float* wp = Wl + (k4 * 4) * 64 + lane;
            acc = fmaf(xv.x, wp[0], acc);
            acc = fmaf(xv.y, wp[64], acc);
            acc = fmaf(xv.z, wp[128], acc);
            acc = fmaf(xv.w, wp[192], acc);
        }
        float y = acc + bias[lane] + resid[(size_t)row * 64 + lane];
        float s = y;
#pragma unroll
        for (int off = 1; off < 64; off <<= 1) s += __shfl_xor(s, off);
        float mu = s * (1.f / 64.f);
        float dcen = y - mu;
        float v = dcen * dcen;
#pragma unroll
        for (int off = 1; off < 64; off <<= 1) v += __shfl_xor(v, off);
        float var = v * (1.f / 64.f);
        Y[(size_t)row * 64 + lane] = dcen * rsqrtf(var + 1e-5f) * g[lane] + bb[lane];
    }
}

// ---------------- classifier stage A ----------------
__global__ __launch_bounds__(256) void k_cls_part(const float* __restrict__ T, const float* __restrict__ Wc1,
                                                  float* __restrict__ Zp) {
    int ks = blockIdx.x >> 2;
    int mt = blockIdx.x & 3;
    int k0 = ks * 74;
    int m0 = mt * 256;
    __shared__ float Tl[64][74];
    int tid = threadIdx.x;
    for (int idx = tid; idx < 64 * 74; idx += 256) {
        int b = idx / 74, kk = idx - b * 74;
        Tl[b][kk] = T[(size_t)b * 9472 + k0 + kk];
    }
    __syncthreads();
    int lane = tid & 63, bq = tid >> 6;
    int mbase = m0 + lane * 4;
    size_t moff = (mbase + 3 < 1000) ? (size_t)mbase : 0;
    float4 acc[16];
#pragma unroll
    for (int j = 0; j < 16; ++j) acc[j] = make_float4(0.f, 0.f, 0.f, 0.f);
#pragma unroll 2
    for (int kk = 0; kk < 74; ++kk) {
        float4 w = *(const float4*)(Wc1 + (size_t)(k0 + kk) * 1000 + moff);
#pragma unroll
        for (int j = 0; j < 16; ++j) {
            float t = Tl[bq * 16 + j][kk];
            acc[j].x = fmaf(t, w.x, acc[j].x);
            acc[j].y = fmaf(t, w.y, acc[j].y);
            acc[j].z = fmaf(t, w.z, acc[j].z);
            acc[j].w = fmaf(t, w.w, acc[j].w);
        }
    }
    float* zp = Zp + (size_t)ks * 64 * 1024;
#pragma unroll
    for (int j = 0; j < 16; ++j) {
        int b = bq * 16 + j;
        *(float4*)(zp + (size_t)b * 1024 + mbase) = acc[j];
    }
}

// ---------------- classifier stage B ----------------
__global__ __launch_bounds__(256) void k_cls_reduce(const float* __restrict__ Zp, const float* __restrict__ bc1,
                                                    const float* __restrict__ bn_g, const float* __restrict__ bn_b,
                                                    float* __restrict__ zb) {
    int flat = blockIdx.x * 256 + threadIdx.x;
    int b = flat >> 10, m = flat & 1023;
    if (m >= 1000) return;
    float s = 0.f;
    for (int ks = 0; ks < 128; ++ks)
        s += Zp[((size_t)ks * 64 + b) * 1024 + m];
    float rs = rsqrtf(1.0f + 1e-5f);
    float z = bn_g[m] * (s + bc1[m]) * rs + bn_b[m];
    zb[flat] = z >= 0.f ? z : 0.01f * z;
}

// ---------------- classifier finish ----------------
__global__ __launch_bounds__(256) void k_cls_final(const float* __restrict__ zb,
                                                   const float* __restrict__ Wc2, const float* __restrict__ bc2,
                                                   float* __restrict__ out) {
    int b = blockIdx.x;
    int tid = threadIdx.x;
    float a0 = 0.f, a1 = 0.f;
    for (int m = tid; m < 1000; m += 256) {
        float z = zb[b * 1024 + m];
        a0 = fmaf(z, Wc2[m * 2], a0);
        a1 = fmaf(z, Wc2[m * 2 + 1], a1);
    }
#pragma unroll
    for (int off = 1; off < 64; off <<= 1) {
        a0 += __shfl_xor(a0, off);
        a1 += __shfl_xor(a1, off);
    }
    __shared__ float r0[4], r1[4];
    if ((tid & 63) == 0) { r0[tid >> 6] = a0; r1[tid >> 6] = a1; }
    __syncthreads();
    if (tid == 0) {
        out[b * 2 + 0] = r0[0] + r0[1] + r0[2] + r0[3] + bc2[0];
        out[b * 2 + 1] = r1[0] + r1[1] + r1[2] + r1[3] + bc2[1];
    }
}

extern "C" void kernel_launch(void* const* d_in, const int* in_sizes, int n_in,
                              void* d_out, int out_size, void* d_ws, size_t ws_size,
                              hipStream_t stream) {
    (void)in_sizes; (void)n_in; (void)out_size; (void)ws_size;

    const float* x_feat = (const float*)d_in[0];
    const int* node_roi = (const int*)d_in[1];
    const int* ei1 = (const int*)d_in[3];
    const float* ew1 = (const float*)d_in[4];
    const float* x2f = (const float*)d_in[5];
    const int* ei2 = (const int*)d_in[8];
    const float* ew2 = (const float*)d_in[9];
    const float* Wg1 = (const float*)d_in[10];
    const float* bg1 = (const float*)d_in[11];
    const float* Wg2 = (const float*)d_in[12];
    const float* bg2 = (const float*)d_in[13];
    const float* Wr1 = (const float*)d_in[14];
    const float* br1 = (const float*)d_in[15];
    const float* Wr2 = (const float*)d_in[16];
    const float* br2 = (const float*)d_in[17];
    const float* in_proj_w = (const float*)d_in[18];
    const float* in_proj_b = (const float*)d_in[19];
    const float* out_proj_w = (const float*)d_in[20];
    const float* out_proj_b = (const float*)d_in[21];
    const float* ln1_g = (const float*)d_in[22];
    const float* ln1_b = (const float*)d_in[23];
    const float* ff_w1 = (const float*)d_in[24];
    const float* ff_b1 = (const float*)d_in[25];
    const float* ff_w2 = (const float*)d_in[26];
    const float* ff_b2 = (const float*)d_in[27];
    const float* ln2_g = (const float*)d_in[28];
    const float* ln2_b = (const float*)d_in[29];
    const float* Wc1 = (const float*)d_in[30];
    const float* bc1 = (const float*)d_in[31];
    const float* bn_g = (const float*)d_in[32];
    const float* bn_b = (const float*)d_in[33];
    const float* Wc2 = (const float*)d_in[34];
    const float* bc2 = (const float*)d_in[35];

    const int* src1 = ei1;
    const int* dst1 = ei1 + E1v;
    const int* src2 = ei2;
    const int* dst2 = ei2 + E2v;

    float* out = (float*)d_out;
    const int PSZ = BRv * 64;
    float* pooled_out = out + 128;
    float* pooledroi_out = out + 128 + PSZ;
    float* tout_out = out + 128 + 2 * PSZ;
    float* attn_out = out + 128 + 3 * PSZ;

    // ===== workspace layout (floats) =====
    float* W = (float*)d_ws;
    size_t o = 0;
    int* bcnt1 = (int*)(W + o);  o += 256;
    int* bcnt2 = (int*)(W + o);  o += 128;
    size_t zone_elems = o;
    int* bb1 = (int*)(W + o);  o += 260;
    int* cur1 = (int*)(W + o); o += 256;
    int* bb2 = (int*)(W + o);  o += 76;
    int* cur2 = (int*)(W + o); o += 128;
    o = (o + 1) & ~(size_t)1;
    int2* snC1 = (int2*)(W + o); o += (size_t)E1v * 2;
    int2* snC2 = (int2*)(W + o); o += (size_t)E2v * 2;
    float* dinv1 = W + o;        o += N1v;
    float* dinv2 = W + o;        o += N2v;
    int* offs1 = (int*)(W + o);  o += N1v;
    int* offs2 = (int*)(W + o);  o += N2v;
    int* offs_p = (int*)(W + o); o += NSEG;
    int* nodeC = (int*)(W + o);  o += N1v;
    float* zbuf = W + o;         o += BBv * 1024;
    o = (o + 1) & ~(size_t)1;
    // DEDICATED branch-2 buffers (must NOT alias h1P: branches run fused)
    ushort_t* h2P = (ushort_t*)(W + o);  o += (size_t)N2v * 32;   // N2v*64 ushorts
    ushort_t* h2Ab = (ushort_t*)(W + o); o += (size_t)N2v * 32;
    o = (o + 1) & ~(size_t)1;
    size_t h1P_off = o; o += (size_t)N1v * 64;
    size_t h1A_off = o; o += (size_t)N1v * 64;
    ushort_t* h1P = (ushort_t*)(W + h1P_off);
    ushort_t* h1Ab = (ushort_t*)(W + h1A_off);
    u64* rb1 = (u64*)(W + h1P_off);       // dead before first GEMM writes h1P
    u64* rb2 = rb1 + E1v;
    size_t p = h1P_off;                    // transformer scratch aliases h1P (used after GCN phase)
    float* comb = W + p; p += PSZ;
    float* qkvb = W + p; p += (size_t)BRv * 192;
    float* obuf = W + p; p += PSZ;
    float* xbuf = W + p; p += PSZ;
    float* f1 = W + p;   p += PSZ;
    float* WinT = W + p; p += 64 * 192;
    float* WoutT = W + p; p += 64 * 64;
    float* Zp = W + h1A_off;   // classifier partials alias h1A (dead after pool_all)

    dim3 blk(256);

    hipMemsetAsync(W, 0, zone_elems * sizeof(float), stream);

    // ===== atomic-free CSR build (both branches) =====
    k_binA<<<E1v / EPB + E2v / EPB, blk, 0, stream>>>(dst1, bcnt1, dst2, bcnt2);
    k_scanAB<<<1, blk, 0, stream>>>(bcnt1, bb1, cur1, bcnt2, bb2, cur2);
    k_binB<<<E1v / EPB + E2v / EPB, blk, 0, stream>>>(src1, dst1, ew1, cur1, rb1,
                                                      src2, dst2, ew2, cur2, rb2);
    k_csrC<BINS1, CAP1, SH1><<<NBK1, blk, CAP1 * 8, stream>>>(rb1, bb1, dinv1, offs1, snC1);
    k_csrC<BINS2, CAP2, SH2><<<NBK2, blk, CAP2 * 8, stream>>>(rb2, bb2, dinv2, offs2, snC2);
    k_normfix<<<E1v / 256 + E2v / 256, blk, 0, stream>>>(snC1, dinv1, snC2, dinv2);
    k_pool_csr<<<BBv, blk, 0, stream>>>(node_roi, offs_p, nodeC);

    // ===== GCN layers (fused across branches) =====
    k_gemm_mfma_f32<<<MB1, blk, 0, stream>>>(x_feat, Wg1, h1P, N1v);
    k_gemm_rowwave<1, false, false, true><<<cdiv(N2v, 4), blk, 148 * 64 * 4, stream>>>(x2f, Wr1, nullptr, h2P, N2v, 148);
    k_gather_both<<<GB1 + GB2, blk, 0, stream>>>(snC1, offs1, h1P, dinv1, bg1, h1Ab,
                                                 snC2, offs2, h2P, dinv2, br1, h2Ab);
    k_gemm_both<<<MB1 + MB2, blk, 0, stream>>>(h1Ab, Wg2, h1P, h2Ab, Wr2, h2P);
    k_gather_both<<<GB1 + GB2, blk, 0, stream>>>(snC1, offs1, h1P, dinv1, bg2, h1Ab,
                                                 snC2, offs2, h2P, dinv2, br2, h2Ab);
    k_pool_all<<<2048, blk, 0, stream>>>(nodeC, offs_p, h1Ab, h2Ab, pooled_out, pooledroi_out, comb);

    // ===== transformer =====
    k_transpose2<<<cdiv(192 * 64 + 64 * 64, 256), blk, 0, stream>>>(in_proj_w, WinT, out_proj_w, WoutT);
    k_gemm_rowwave<3, false, false, false><<<cdiv(N2v, 4), blk, 64 * 192 * 4, stream>>>(comb, WinT, in_proj_b, qkvb, N2v, 64);
    k_attn<<<BBv * 4 * 4, blk, 0, stream>>>(qkvb, attn_out, obuf);
    k_ln_gemm<<<cdiv(N2v, 4), blk, 0, stream>>>(obuf, WoutT, out_proj_b, comb, ln1_g, ln1_b, xbuf, N2v);
    k_gemm_rowwave<1, false, true, false><<<cdiv(N2v, 4), blk, 64 * 64 * 4, stream>>>(xbuf, ff_w1, ff_b1, f1, N2v, 64);
    k_ln_gemm<<<cdiv(N2v, 4), blk, 0, stream>>>(f1, ff_w2, ff_b2, xbuf, ln2_g, ln2_b, tout_out, N2v);

    // ===== classifier =====
    k_cls_part<<<512, blk, 0, stream>>>(tout_out, Wc1, Zp);
    k_cls_reduce<<<BBv * 1024 / 256, blk, 0, stream>>>(Zp, bc1, bn_g, bn_b, zbuf);
    k_cls_final<<<BBv, blk, 0, stream>>>(zbuf, Wc2, bc2, out);
}

// Round 17
// 393.130 us; speedup vs baseline: 1.1721x; 1.0725x over previous
//
#include <hip/hip_runtime.h>
#include <cstdint>
#include <cstddef>

#define N1v 262144
#define E1v 1048576
#define N2v 9472
#define E2v 262144
#define BBv 64
#define RRv 148
#define HIDv 1000
#define BRv (BBv * RRv)
#define NSEG 9472
#define EPB 4096
#define NBK1 256
#define SH1 10
#define BINS1 1024
#define CAP1 4864
#define STR1 4608
#define NBK2 74
#define SH2 7
#define BINS2 128
#define CAP2 4096
#define STR2 4096
#define GB1 4096
#define GB2 1184
#define MB1 2048
#define MB2 148

__host__ __device__ constexpr int cdiv(int a, int b) { return (a + b - 1) / b; }

typedef __attribute__((ext_vector_type(8))) short bf16x8;
typedef __attribute__((ext_vector_type(4))) float f32x4;
typedef unsigned short ushort_t;
typedef unsigned long long u64;

__device__ inline short f2bf(float f) {
    union { float f; unsigned u; } v; v.f = f;
    unsigned r = v.u + 0x7fff + ((v.u >> 16) & 1);   // RNE
    return (short)(r >> 16);
}
__device__ inline float bf2f(unsigned hs) {
    union { unsigned u; float f; } v; v.u = hs << 16; return v.f;
}
__device__ inline unsigned relu_pk(unsigned u) {
    unsigned r = u;
    if (r & 0x8000u) r &= 0xFFFF0000u;
    if (r & 0x80000000u) r &= 0x0000FFFFu;
    return r;
}

// ---------------- pass B (direct): bucket-grouped record scatter into fixed-stride slabs ----------------
__global__ __launch_bounds__(256) void k_binB2(const int* __restrict__ src1, const int* __restrict__ dst1,
                                               const float* __restrict__ ew1, int* __restrict__ cur1, u64* __restrict__ rb1,
                                               const int* __restrict__ src2, const int* __restrict__ dst2,
                                               const float* __restrict__ ew2, int* __restrict__ cur2, u64* __restrict__ rb2) {
    int bid = blockIdx.x;
    const int* src; const int* dst; const float* ew; int* cur; u64* rb; int nbk, sh, e0; size_t stride;
    if (bid < E1v / EPB) { src = src1; dst = dst1; ew = ew1; cur = cur1; rb = rb1; nbk = NBK1; sh = SH1; e0 = bid * EPB; stride = STR1; }
    else { src = src2; dst = dst2; ew = ew2; cur = cur2; rb = rb2; nbk = NBK2; sh = SH2; e0 = (bid - E1v / EPB) * EPB; stride = STR2; }
    __shared__ int h[256], basg[256];
    int tid = threadIdx.x;
    if (tid < nbk) h[tid] = 0;
    __syncthreads();
    for (int t = tid; t < EPB; t += 256) atomicAdd(&h[dst[e0 + t] >> sh], 1);
    __syncthreads();
    if (tid < nbk) {
        int c = h[tid];
        basg[tid] = c ? atomicAdd(&cur[tid], c) : 0;
        h[tid] = 0;
    }
    __syncthreads();
    unsigned lowmask = (1u << sh) - 1u;
    for (int t = tid; t < EPB; t += 256) {
        int d = dst[e0 + t];
        int b = d >> sh;
        int r = atomicAdd(&h[b], 1);
        unsigned lo = ((unsigned)src[e0 + t] << sh) | ((unsigned)d & lowmask);
        rb[(size_t)b * stride + basg[b] + r] = ((u64)(unsigned)__float_as_int(ew[e0 + t]) << 32) | lo;
    }
}

// ---------------- scan bucket fill counts -> compact bases ----------------
__global__ __launch_bounds__(256) void k_scanC(const int* __restrict__ cur1, int* __restrict__ cb1,
                                               const int* __restrict__ cur2, int* __restrict__ cb2) {
    __shared__ int tmp[256];
    int t = threadIdx.x;
    int v = cur1[t];
    tmp[t] = v; __syncthreads();
    int val = v;
    for (int off = 1; off < 256; off <<= 1) { int o = (t >= off) ? tmp[t - off] : 0; __syncthreads(); val += o; tmp[t] = val; __syncthreads(); }
    cb1[t] = val - v;
    if (t == 255) cb1[256] = val;
    __syncthreads();
    int v2 = (t < NBK2) ? cur2[t] : 0;
    tmp[t] = v2; __syncthreads();
    int val2 = v2;
    for (int off = 1; off < 256; off <<= 1) { int o = (t >= off) ? tmp[t - off] : 0; __syncthreads(); val2 += o; tmp[t] = val2; __syncthreads(); }
    if (t < NBK2) cb2[t] = val2 - v2;
    if (t == NBK2 - 1) cb2[NBK2] = val2;
}

// ---------------- pass C: per-bucket CSR build from strided slab; snC.y = ew * dinv[d] ----------------
template<int BINS, int CAP, int SH, int STRIDE>
__global__ __launch_bounds__(256) void k_csrC(const u64* __restrict__ rb, const int* __restrict__ cnts,
                                              const int* __restrict__ cbase,
                                              float* __restrict__ dinv, int* __restrict__ offs,
                                              int2* __restrict__ snC) {
    int b = blockIdx.x;
    const u64* rbb = rb + (size_t)b * STRIDE;
    int cnt = cnts[b];
    int cb = cbase[b];
    __shared__ int hist[BINS];
    __shared__ float degs[BINS];
    __shared__ int scn[BINS];
    __shared__ int tmp[256];
    extern __shared__ int2 outb[];
    int tid = threadIdx.x;
    for (int i = tid; i < BINS; i += 256) { hist[i] = 0; degs[i] = 0.f; }
    __syncthreads();
    for (int j = tid; j < cnt; j += 256) {
        u64 rec = rbb[j];
        int bin = (int)((unsigned)rec & (BINS - 1));
        float w = __int_as_float((int)(rec >> 32));
        atomicAdd(&hist[bin], 1);
        atomicAdd(&degs[bin], w);
    }
    __syncthreads();
    constexpr int PER = (BINS + 255) / 256;
    int lv[PER];
    int tsum = 0;
    int base_i = tid * PER;
#pragma unroll
    for (int k = 0; k < PER; ++k) { int idx = base_i + k; lv[k] = (idx < BINS) ? hist[idx] : 0; tsum += lv[k]; }
    tmp[tid] = tsum; __syncthreads();
    int val = tsum;
    for (int off = 1; off < 256; off <<= 1) { int o = (tid >= off) ? tmp[tid - off] : 0; __syncthreads(); val += o; tmp[tid] = val; __syncthreads(); }
    int run = val - tsum;
#pragma unroll
    for (int k = 0; k < PER; ++k) { int idx = base_i + k; if (idx < BINS) { scn[idx] = run; run += lv[k]; } }
    __syncthreads();
    for (int i = tid; i < BINS; i += 256) {
        offs[b * BINS + i] = cb + scn[i];
        dinv[b * BINS + i] = rsqrtf(degs[i] + 1.0f);
    }
    __syncthreads();
    bool staged = (cnt <= CAP);
    for (int j = tid; j < cnt; j += 256) {
        u64 rec = rbb[j];
        unsigned lo = (unsigned)rec;
        int bin = (int)(lo & (BINS - 1));
        int s = (int)(lo >> SH);
        float w = __int_as_float((int)(rec >> 32));
        float wd = w * rsqrtf(degs[bin] + 1.0f);   // fold dinv[d]
        int r = atomicAdd(&scn[bin], 1);
        int2 o2 = make_int2(s, __float_as_int(wd));
        if (staged) outb[r] = o2;
        else snC[(size_t)cb + r] = o2;
    }
    __syncthreads();
    if (staged) {
        for (int j = tid; j < cnt; j += 256) snC[(size_t)cb + j] = outb[j];
    }
}

// ---------------- normfix: snC.y *= dinv[src] (both branches, one launch) ----------------
__global__ __launch_bounds__(256) void k_normfix(int2* __restrict__ snC1, const float* __restrict__ dinv1,
                                                 int2* __restrict__ snC2, const float* __restrict__ dinv2) {
    int bid = blockIdx.x;
    int2* snC; const float* dinv; int j;
    if (bid < E1v / 256) { snC = snC1; dinv = dinv1; j = bid * 256 + threadIdx.x; }
    else { snC = snC2; dinv = dinv2; j = (bid - E1v / 256) * 256 + threadIdx.x; }
    int2 e = snC[j];
    e.y = __float_as_int(dinv[e.x] * __int_as_float(e.y));
    snC[j] = e;
}

// ---------------- block-local pool CSR ----------------
__global__ __launch_bounds__(256) void k_pool_csr(const int* __restrict__ roi, int* __restrict__ offs_p,
                                                  int* __restrict__ nodeC) {
    int b = blockIdx.x;
    __shared__ int rl[4096];
    __shared__ int hist[RRv];
    __shared__ int curs[RRv];
    int tid = threadIdx.x;
    for (int t = tid; t < RRv; t += 256) hist[t] = 0;
    __syncthreads();
    int base = b * 4096;
    for (int t = tid; t < 4096; t += 256) {
        int r = roi[base + t];
        rl[t] = r;
        atomicAdd(&hist[r], 1);
    }
    __syncthreads();
    if (tid < RRv) {
        int s = 0;
        for (int k = 0; k < tid; ++k) s += hist[k];
        curs[tid] = s;
        offs_p[b * RRv + tid] = base + s;
    }
    __syncthreads();
    for (int t = tid; t < 4096; t += 256) {
        int r = rl[t];
        int j = atomicAdd(&curs[r], 1);
        nodeC[base + j] = base + t;
    }
}

// ---------------- fused pool: branch-1 mean-pool + branch-2 identity + comb ----------------
__global__ __launch_bounds__(256) void k_pool_all(const int* __restrict__ nodeC, const int* __restrict__ offs,
                                                  const ushort_t* __restrict__ Ab, const ushort_t* __restrict__ h2Ab,
                                                  float* __restrict__ pooled, float* __restrict__ pooledroi,
                                                  float* __restrict__ comb) {
    int tid = threadIdx.x;
    int lane = tid & 63;
    int nh = lane >> 5;
    int slot = (lane >> 3) & 3;
    int f8 = lane & 7;
    int gw = blockIdx.x * 4 + (tid >> 6);
    int tw = gridDim.x * 4;
    for (int ss = gw * 2; ss < NSEG; ss += tw * 2) {
        int s = ss + nh;
        int beg = offs[s];
        int end = (s + 1 < NSEG) ? offs[s + 1] : N1v;
        float a0 = 0.f, a1 = 0.f, a2 = 0.f, a3 = 0.f, a4 = 0.f, a5 = 0.f, a6 = 0.f, a7 = 0.f;
        for (int j = beg + slot; j < end; j += 4) {
            int node = nodeC[j];
            uint4 v = *(const uint4*)(Ab + (size_t)node * 64 + f8 * 8);
            a0 += fmaxf(bf2f(v.x & 0xffffu), 0.f);
            a1 += fmaxf(bf2f(v.x >> 16), 0.f);
            a2 += fmaxf(bf2f(v.y & 0xffffu), 0.f);
            a3 += fmaxf(bf2f(v.y >> 16), 0.f);
            a4 += fmaxf(bf2f(v.z & 0xffffu), 0.f);
            a5 += fmaxf(bf2f(v.z >> 16), 0.f);
            a6 += fmaxf(bf2f(v.w & 0xffffu), 0.f);
            a7 += fmaxf(bf2f(v.w >> 16), 0.f);
        }
        a0 += __shfl_xor(a0, 8);  a1 += __shfl_xor(a1, 8);  a2 += __shfl_xor(a2, 8);  a3 += __shfl_xor(a3, 8);
        a4 += __shfl_xor(a4, 8);  a5 += __shfl_xor(a5, 8);  a6 += __shfl_xor(a6, 8);  a7 += __shfl_xor(a7, 8);
        a0 += __shfl_xor(a0, 16); a1 += __shfl_xor(a1, 16); a2 += __shfl_xor(a2, 16); a3 += __shfl_xor(a3, 16);
        a4 += __shfl_xor(a4, 16); a5 += __shfl_xor(a5, 16); a6 += __shfl_xor(a6, 16); a7 += __shfl_xor(a7, 16);
        if (slot == 0) {
            float inv = 1.f / (float)max(end - beg, 1);
            float p0 = a0 * inv, p1 = a1 * inv, p2 = a2 * inv, p3 = a3 * inv;
            float p4 = a4 * inv, p5 = a5 * inv, p6 = a6 * inv, p7 = a7 * inv;
            uint4 v2 = *(const uint4*)(h2Ab + (size_t)s * 64 + f8 * 8);
            float q0 = fmaxf(bf2f(v2.x & 0xffffu), 0.f);
            float q1 = fmaxf(bf2f(v2.x >> 16), 0.f);
            float q2 = fmaxf(bf2f(v2.y & 0xffffu), 0.f);
            float q3 = fmaxf(bf2f(v2.y >> 16), 0.f);
            float q4 = fmaxf(bf2f(v2.z & 0xffffu), 0.f);
            float q5 = fmaxf(bf2f(v2.z >> 16), 0.f);
            float q6 = fmaxf(bf2f(v2.w & 0xffffu), 0.f);
            float q7 = fmaxf(bf2f(v2.w >> 16), 0.f);
            size_t bo = (size_t)s * 64 + f8 * 8;
            float4 t;
            t.x = p0; t.y = p1; t.z = p2; t.w = p3; *(float4*)(pooled + bo) = t;
            t.x = p4; t.y = p5; t.z = p6; t.w = p7; *(float4*)(pooled + bo + 4) = t;
            t.x = q0; t.y = q1; t.z = q2; t.w = q3; *(float4*)(pooledroi + bo) = t;
            t.x = q4; t.y = q5; t.z = q6; t.w = q7; *(float4*)(pooledroi + bo + 4) = t;
            t.x = p0 + q0; t.y = p1 + q1; t.z = p2 + q2; t.w = p3 + q3; *(float4*)(comb + bo) = t;
            t.x = p4 + q4; t.y = p5 + q5; t.z = p6 + q6; t.w = p7 + q7; *(float4*)(comb + bo + 4) = t;
        }
    }
}

// ---------------- gather body (norm fully precomputed in snC.y) ----------------
__device__ inline void gather_body(const int2* __restrict__ snC, const int* __restrict__ offs,
                                   const ushort_t* __restrict__ Pb, const float* __restrict__ dinv,
                                   const float* __restrict__ bias, ushort_t* __restrict__ A,
                                   int N, int E, int gw, int tw, int lane) {
    int nh = lane >> 5;
    int slot = (lane >> 3) & 3;
    int f8 = lane & 7;
    float4 bv0 = *(const float4*)(bias + f8 * 8);
    float4 bv1 = *(const float4*)(bias + f8 * 8 + 4);
    for (int ii = gw * 2; ii < N; ii += tw * 2) {
        int i = ii + nh;
        int beg = offs[i];
        int end = (i + 1 < N) ? offs[i + 1] : E;
        float a0 = 0.f, a1 = 0.f, a2 = 0.f, a3 = 0.f, a4 = 0.f, a5 = 0.f, a6 = 0.f, a7 = 0.f;
        for (int j = beg + slot; j < end; j += 4) {
            int2 e = snC[j];
            int s = e.x;
            float nv = __int_as_float(e.y);
            uint4 w = *(const uint4*)(Pb + (size_t)s * 64 + f8 * 8);
            a0 = fmaf(nv, bf2f(w.x & 0xffffu), a0);
            a1 = fmaf(nv, bf2f(w.x >> 16), a1);
            a2 = fmaf(nv, bf2f(w.y & 0xffffu), a2);
            a3 = fmaf(nv, bf2f(w.y >> 16), a3);
            a4 = fmaf(nv, bf2f(w.z & 0xffffu), a4);
            a5 = fmaf(nv, bf2f(w.z >> 16), a5);
            a6 = fmaf(nv, bf2f(w.w & 0xffffu), a6);
            a7 = fmaf(nv, bf2f(w.w >> 16), a7);
        }
        a0 += __shfl_xor(a0, 8);  a1 += __shfl_xor(a1, 8);  a2 += __shfl_xor(a2, 8);  a3 += __shfl_xor(a3, 8);
        a4 += __shfl_xor(a4, 8);  a5 += __shfl_xor(a5, 8);  a6 += __shfl_xor(a6, 8);  a7 += __shfl_xor(a7, 8);
        a0 += __shfl_xor(a0, 16); a1 += __shfl_xor(a1, 16); a2 += __shfl_xor(a2, 16); a3 += __shfl_xor(a3, 16);
        a4 += __shfl_xor(a4, 16); a5 += __shfl_xor(a5, 16); a6 += __shfl_xor(a6, 16); a7 += __shfl_xor(a7, 16);
        if (slot == 0) {
            uint4 w = *(const uint4*)(Pb + (size_t)i * 64 + f8 * 8);
            float di = dinv[i];
            float s2 = di * di;
            float r0 = fmaf(s2, bf2f(w.x & 0xffffu), a0) + bv0.x;
            float r1 = fmaf(s2, bf2f(w.x >> 16),    a1) + bv0.y;
            float r2 = fmaf(s2, bf2f(w.y & 0xffffu), a2) + bv0.z;
            float r3 = fmaf(s2, bf2f(w.y >> 16),    a3) + bv0.w;
            float r4 = fmaf(s2, bf2f(w.z & 0xffffu), a4) + bv1.x;
            float r5 = fmaf(s2, bf2f(w.z >> 16),    a5) + bv1.y;
            float r6 = fmaf(s2, bf2f(w.w & 0xffffu), a6) + bv1.z;
            float r7 = fmaf(s2, bf2f(w.w >> 16),    a7) + bv1.w;
            uint4 ov;
            ov.x = (unsigned)(ushort_t)f2bf(r0) | ((unsigned)(ushort_t)f2bf(r1) << 16);
            ov.y = (unsigned)(ushort_t)f2bf(r2) | ((unsigned)(ushort_t)f2bf(r3) << 16);
            ov.z = (unsigned)(ushort_t)f2bf(r4) | ((unsigned)(ushort_t)f2bf(r5) << 16);
            ov.w = (unsigned)(ushort_t)f2bf(r6) | ((unsigned)(ushort_t)f2bf(r7) << 16);
            *(uint4*)(A + (size_t)i * 64 + f8 * 8) = ov;
        }
    }
}

// ---------------- fused gather: branch1 + branch2 in one launch ----------------
__global__ __launch_bounds__(256) void k_gather_both(const int2* __restrict__ snC1, const int* __restrict__ offs1,
                                                     const ushort_t* __restrict__ P1, const float* __restrict__ dinv1,
                                                     const float* __restrict__ b1, ushort_t* __restrict__ A1,
                                                     const int2* __restrict__ snC2, const int* __restrict__ offs2,
                                                     const ushort_t* __restrict__ P2, const float* __restrict__ dinv2,
                                                     const float* __restrict__ b2, ushort_t* __restrict__ A2) {
    int tid = threadIdx.x;
    int lane = tid & 63;
    if (blockIdx.x < GB1)
        gather_body(snC1, offs1, P1, dinv1, b1, A1, N1v, E1v,
                    blockIdx.x * 4 + (tid >> 6), GB1 * 4, lane);
    else
        gather_body(snC2, offs2, P2, dinv2, b2, A2, N2v, E2v,
                    (blockIdx.x - GB1) * 4 + (tid >> 6), GB2 * 4, lane);
}

// ---------------- bf16 GEMM body (RIN=true, bf16 in/out) ----------------
__device__ inline void gemm_bf16_body(const ushort_t* __restrict__ X, const float* __restrict__ Wmat,
                                      ushort_t* __restrict__ Y, int N, int gw, int tw, int tid) {
    int lane = tid & 63;
    int l15 = lane & 15;
    int lg = lane >> 4;
    bf16x8 bfrag[2][4];
    for (int kh = 0; kh < 2; ++kh)
        for (int ct = 0; ct < 4; ++ct) {
            bf16x8 b;
#pragma unroll
            for (int i = 0; i < 8; ++i)
                b[i] = f2bf(Wmat[(size_t)(kh * 32 + lg * 8 + i) * 64 + ct * 16 + l15]);
            bfrag[kh][ct] = b;
        }
    int ntiles = N >> 4;
    for (int t = gw; t < ntiles; t += tw) {
        int row0 = t << 4;
        const ushort_t* xp = X + (size_t)(row0 + l15) * 64 + lg * 8;
        uint4 c0 = *(const uint4*)(xp);
        uint4 c1 = *(const uint4*)(xp + 32);
        c0.x = relu_pk(c0.x); c0.y = relu_pk(c0.y); c0.z = relu_pk(c0.z); c0.w = relu_pk(c0.w);
        c1.x = relu_pk(c1.x); c1.y = relu_pk(c1.y); c1.z = relu_pk(c1.z); c1.w = relu_pk(c1.w);
        bf16x8 af0 = *reinterpret_cast<bf16x8*>(&c0);
        bf16x8 af1 = *reinterpret_cast<bf16x8*>(&c1);
        f32x4 acc0 = {0.f, 0.f, 0.f, 0.f}, acc1 = acc0, acc2 = acc0, acc3 = acc0;
        acc0 = __builtin_amdgcn_mfma_f32_16x16x32_bf16(af0, bfrag[0][0], acc0, 0, 0, 0);
        acc1 = __builtin_amdgcn_mfma_f32_16x16x32_bf16(af0, bfrag[0][1], acc1, 0, 0, 0);
        acc2 = __builtin_amdgcn_mfma_f32_16x16x32_bf16(af0, bfrag[0][2], acc2, 0, 0, 0);
        acc3 = __builtin_amdgcn_mfma_f32_16x16x32_bf16(af0, bfrag[0][3], acc3, 0, 0, 0);
        acc0 = __builtin_amdgcn_mfma_f32_16x16x32_bf16(af1, bfrag[1][0], acc0, 0, 0, 0);
        acc1 = __builtin_amdgcn_mfma_f32_16x16x32_bf16(af1, bfrag[1][1], acc1, 0, 0, 0);
        acc2 = __builtin_amdgcn_mfma_f32_16x16x32_bf16(af1, bfrag[1][2], acc2, 0, 0, 0);
        acc3 = __builtin_amdgcn_mfma_f32_16x16x32_bf16(af1, bfrag[1][3], acc3, 0, 0, 0);
        ushort_t* yp = Y + (size_t)(row0 + lg * 4) * 64 + l15;
#pragma unroll
        for (int r = 0; r < 4; ++r) {
            yp[(size_t)r * 64 + 0]  = (ushort_t)f2bf(acc0[r]);
            yp[(size_t)r * 64 + 16] = (ushort_t)f2bf(acc1[r]);
            yp[(size_t)r * 64 + 32] = (ushort_t)f2bf(acc2[r]);
            yp[(size_t)r * 64 + 48] = (ushort_t)f2bf(acc3[r]);
        }
    }
}

// ---------------- fused layer-2 GEMM: branch1 + branch2 ----------------
__global__ __launch_bounds__(256) void k_gemm_both(const ushort_t* __restrict__ X1, const float* __restrict__ W1,
                                                   ushort_t* __restrict__ Y1,
                                                   const ushort_t* __restrict__ X2, const float* __restrict__ W2,
                                                   ushort_t* __restrict__ Y2) {
    int tid = threadIdx.x;
    if (blockIdx.x < MB1)
        gemm_bf16_body(X1, W1, Y1, N1v, blockIdx.x * 4 + (tid >> 6), MB1 * 4, tid);
    else
        gemm_bf16_body(X2, W2, Y2, N2v, (blockIdx.x - MB1) * 4 + (tid >> 6), MB2 * 4, tid);
}

// ---------------- MFMA bf16 GEMM, fp32 input (branch-1 layer 1) ----------------
__global__ __launch_bounds__(256) void k_gemm_mfma_f32(const float* __restrict__ X, const float* __restrict__ Wmat,
                                                       ushort_t* __restrict__ Y, int N) {
    int tid = threadIdx.x;
    int lane = tid & 63;
    int wv = tid >> 6;
    int l15 = lane & 15;
    int lg = lane >> 4;
    bf16x8 bfrag[2][4];
    for (int kh = 0; kh < 2; ++kh)
        for (int ct = 0; ct < 4; ++ct) {
            bf16x8 b;
#pragma unroll
            for (int i = 0; i < 8; ++i)
                b[i] = f2bf(Wmat[(size_t)(kh * 32 + lg * 8 + i) * 64 + ct * 16 + l15]);
            bfrag[kh][ct] = b;
        }
    int gw = blockIdx.x * 4 + wv;
    int tw = gridDim.x * 4;
    int ntiles = N >> 4;
    for (int t = gw; t < ntiles; t += tw) {
        int row0 = t << 4;
        const float* xp = X + (size_t)(row0 + l15) * 64 + lg * 8;
        float4 a0 = *(const float4*)(xp);
        float4 a1 = *(const float4*)(xp + 4);
        float4 a2 = *(const float4*)(xp + 32);
        float4 a3 = *(const float4*)(xp + 36);
        bf16x8 af0, af1;
        af0[0] = f2bf(a0.x); af0[1] = f2bf(a0.y); af0[2] = f2bf(a0.z); af0[3] = f2bf(a0.w);
        af0[4] = f2bf(a1.x); af0[5] = f2bf(a1.y); af0[6] = f2bf(a1.z); af0[7] = f2bf(a1.w);
        af1[0] = f2bf(a2.x); af1[1] = f2bf(a2.y); af1[2] = f2bf(a2.z); af1[3] = f2bf(a2.w);
        af1[4] = f2bf(a3.x); af1[5] = f2bf(a3.y); af1[6] = f2bf(a3.z); af1[7] = f2bf(a3.w);
        f32x4 acc0 = {0.f, 0.f, 0.f, 0.f}, acc1 = acc0, acc2 = acc0, acc3 = acc0;
        acc0 = __builtin_amdgcn_mfma_f32_16x16x32_bf16(af0, bfrag[0][0], acc0, 0, 0, 0);
        acc1 = __builtin_amdgcn_mfma_f32_16x16x32_bf16(af0, bfrag[0][1], acc1, 0, 0, 0);
        acc2 = __builtin_amdgcn_mfma_f32_16x16x32_bf16(af0, bfrag[0][2], acc2, 0, 0, 0);
        acc3 = __builtin_amdgcn_mfma_f32_16x16x32_bf16(af0, bfrag[0][3], acc3, 0, 0, 0);
        acc0 = __builtin_amdgcn_mfma_f32_16x16x32_bf16(af1, bfrag[1][0], acc0, 0, 0, 0);
        acc1 = __builtin_amdgcn_mfma_f32_16x16x32_bf16(af1, bfrag[1][1], acc1, 0, 0, 0);
        acc2 = __builtin_amdgcn_mfma_f32_16x16x32_bf16(af1, bfrag[1][2], acc2, 0, 0, 0);
        acc3 = __builtin_amdgcn_mfma_f32_16x16x32_bf16(af1, bfrag[1][3], acc3, 0, 0, 0);
        ushort_t* yp = Y + (size_t)(row0 + lg * 4) * 64 + l15;
#pragma unroll
        for (int r = 0; r < 4; ++r) {
            yp[(size_t)r * 64 + 0]  = (ushort_t)f2bf(acc0[r]);
            yp[(size_t)r * 64 + 16] = (ushort_t)f2bf(acc1[r]);
            yp[(size_t)r * 64 + 32] = (ushort_t)f2bf(acc2[r]);
            yp[(size_t)r * 64 + 48] = (ushort_t)f2bf(acc3[r]);
        }
    }
}

// ---------------- row-per-wave GEMM ----------------
template<int MB, bool RIN, bool ROUT, bool OBF16>
__global__ __launch_bounds__(256) void k_gemm_rowwave(const float* __restrict__ X, const float* __restrict__ W,
                                                      const float* __restrict__ bias, void* __restrict__ Yv,
                                                      int N, int K) {
    extern __shared__ float Wl[];
    const int M = MB * 64;
    for (int idx = threadIdx.x; idx < K * M; idx += 256) Wl[idx] = W[idx];
    __syncthreads();
    int lane = threadIdx.x & 63;
    int gw = blockIdx.x * 4 + (threadIdx.x >> 6);
    int tw = gridDim.x * 4;
    const int K4 = K >> 2;
    for (int row = gw; row < N; row += tw) {
        float acc[MB];
#pragma unroll
        for (int cb = 0; cb < MB; ++cb) acc[cb] = 0.f;
        const float4* xr = (const float4*)(X + (size_t)row * K);
        for (int k4 = 0; k4 < K4; ++k4) {
            float4 xv = xr[k4];
            if (RIN) {
                xv.x = fmaxf(xv.x, 0.f); xv.y = fmaxf(xv.y, 0.f);
                xv.z = fmaxf(xv.z, 0.f); xv.w = fmaxf(xv.w, 0.f);
            }
            const float* wp = Wl + (k4 * 4) * M + lane;
#pragma unroll
            for (int cb = 0; cb < MB; ++cb) acc[cb] = fmaf(xv.x, wp[cb * 64], acc[cb]);
            wp += M;
#pragma unroll
            for (int cb = 0; cb < MB; ++cb) acc[cb] = fmaf(xv.y, wp[cb * 64], acc[cb]);
            wp += M;
#pragma unroll
            for (int cb = 0; cb < MB; ++cb) acc[cb] = fmaf(xv.z, wp[cb * 64], acc[cb]);
            wp += M;
#pragma unroll
            for (int cb = 0; cb < MB; ++cb) acc[cb] = fmaf(xv.w, wp[cb * 64], acc[cb]);
        }
#pragma unroll
        for (int cb = 0; cb < MB; ++cb) {
            float y = acc[cb];
            int col = cb * 64 + lane;
            if (bias) y += bias[col];
            if (ROUT) y = fmaxf(y, 0.f);
            if (OBF16) ((ushort_t*)Yv)[(size_t)row * M + col] = (ushort_t)f2bf(y);
            else ((float*)Yv)[(size_t)row * M + col] = y;
        }
    }
}

// ---------------- fused double transpose ----------------
__global__ __launch_bounds__(256) void k_transpose2(const float* __restrict__ Win, float* __restrict__ WinT,
                                                    const float* __restrict__ Wout, float* __restrict__ WoutT) {
    int i = blockIdx.x * 256 + threadIdx.x;
    if (i < 192 * 64) {
        int r = i >> 6, c = i & 63;
        WinT[c * 192 + r] = Win[i];
    } else if (i < 192 * 64 + 64 * 64) {
        int j = i - 192 * 64;
        int r = j >> 6, c = j & 63;
        WoutT[c * 64 + r] = Wout[j];
    }
}

// ---------------- attention ----------------
__global__ __launch_bounds__(256) void k_attn(const float* __restrict__ qkv, float* __restrict__ aw,
                                              float* __restrict__ o) {
    int qc = blockIdx.x & 3;
    int bh = blockIdx.x >> 2;
    int b = bh >> 2, h = bh & 3;
    __shared__ float qs[37][16];
    __shared__ float kT[16][152];
    __shared__ float vs[148][16];
    __shared__ float ps[4][152];
    int tid = threadIdx.x;
    const float* base = qkv + (size_t)b * 148 * 192 + h * 16;
    for (int idx = tid; idx < 148 * 16; idx += 256) {
        int i = idx >> 4, d = idx & 15;
        const float* p = base + (size_t)i * 192 + d;
        kT[d][i] = p[64];
        vs[i][d] = p[128];
    }
    int q0 = qc * 37;
    for (int idx = tid; idx < 37 * 16; idx += 256) {
        int i = idx >> 4, d = idx & 15;
        qs[i][d] = base[(size_t)(q0 + i) * 192 + d] * 0.25f;
    }
    __syncthreads();
    int wv = tid >> 6, lane = tid & 63;
    float* aw_bh = aw + (size_t)bh * 148 * 148;
    for (int ii = wv; ii < 37; ii += 4) {
        int i = q0 + ii;
        float s0 = 0.f, s1 = 0.f, s2 = 0.f;
#pragma unroll
        for (int d = 0; d < 16; ++d) {
            float q = qs[ii][d];
            s0 = fmaf(q, kT[d][lane], s0);
            s1 = fmaf(q, kT[d][lane + 64], s1);
            if (lane < 20) s2 = fmaf(q, kT[d][lane + 128], s2);
        }
        float m = fmaxf(s0, s1);
        if (lane < 20) m = fmaxf(m, s2);
#pragma unroll
        for (int off = 1; off < 64; off <<= 1) m = fmaxf(m, __shfl_xor(m, off));
        float e0 = __expf(s0 - m), e1 = __expf(s1 - m);
        float e2 = (lane < 20) ? __expf(s2 - m) : 0.f;
        float sum = e0 + e1 + e2;
#pragma unroll
        for (int off = 1; off < 64; off <<= 1) sum += __shfl_xor(sum, off);
        float inv = 1.f / sum;
        float p0 = e0 * inv, p1 = e1 * inv, p2 = e2 * inv;
        float* awr = aw_bh + (size_t)i * 148;
        awr[lane] = p0;
        awr[lane + 64] = p1;
        if (lane < 20) awr[lane + 128] = p2;
        ps[wv][lane] = p0;
        ps[wv][lane + 64] = p1;
        if (lane < 20) ps[wv][lane + 128] = p2;
        int d = lane & 15, jj = lane >> 4;
        float acc = 0.f;
        for (int t = jj; t < 148; t += 4) acc = fmaf(ps[wv][t], vs[t][d], acc);
        acc += __shfl_xor(acc, 16);
        acc += __shfl_xor(acc, 32);
        if (lane < 16) o[((size_t)b * 148 + i) * 64 + h * 16 + d] = acc;
    }
}

// ---------------- fused GEMM + bias + residual + LayerNorm (K=M=64) ----------------
__global__ __launch_bounds__(256) void k_ln_gemm(const float* __restrict__ X, const float* __restrict__ Wt,
                                                 const float* __restrict__ bias, const float* __restrict__ resid,
                                                 const float* __restrict__ g, const float* __restrict__ bb,
                                                 float* __restrict__ Y, int N) {
    __shared__ float Wl[4096];
    for (int idx = threadIdx.x; idx < 4096; idx += 256) Wl[idx] = Wt[idx];
    __syncthreads();
    int lane = threadIdx.x & 63;
    int gw = blockIdx.x * 4 + (threadIdx.x >> 6);
    int tw = gridDim.x * 4;
    for (int row = gw; row < N; row += tw) {
        const float4* xr = (const float4*)(X + (size_t)row * 64);
        float acc = 0.f;
        for (int k4 = 0; k4 < 16; ++k4) {
            float4 xv = xr[k4];
            const float* wp = Wl + (k4 * 4) * 64 + lane;
            acc = fmaf(xv.x, wp[0], acc);
            acc = fmaf(xv.y, wp[64], acc);
            acc = fmaf(xv.z, wp[128], acc);
            acc = fmaf(xv.w, wp[192], acc);
        }
        float y = acc + bias[lane] + resid[(size_t)row * 64 + lane];
        float s = y;
#pragma unroll
        for (int off = 1; off < 64; off <<= 1) s += __shfl_xor(s, off);
        float mu = s * (1.f / 64.f);
        float dcen = y - mu;
        float v = dcen * dcen;
#pragma unroll
        for (int off = 1; off < 64; off <<= 1) v += __shfl_xor(v, off);
        float var = v * (1.f / 64.f);
        Y[(size_t)row * 64 + lane] = dcen * rsqrtf(var + 1e-5f) * g[lane] + bb[lane];
    }
}

// ---------------- classifier stage A ----------------
__global__ __launch_bounds__(256) void k_cls_part(const float* __restrict__ T, const float* __restrict__ Wc1,
                                                  float* __restrict__ Zp) {
    int ks = blockIdx.x >> 2;
    int mt = blockIdx.x & 3;
    int k0 = ks * 74;
    int m0 = mt * 256;
    __shared__ float Tl[64][74];
    int tid = threadIdx.x;
    for (int idx = tid; idx < 64 * 74; idx += 256) {
        int b = idx / 74, kk = idx - b * 74;
        Tl[b][kk] = T[(size_t)b * 9472 + k0 + kk];
    }
    __syncthreads();
    int lane = tid & 63, bq = tid >> 6;
    int mbase = m0 + lane * 4;
    size_t moff = (mbase + 3 < 1000) ? (size_t)mbase : 0;
    float4 acc[16];
#pragma unroll
    for (int j = 0; j < 16; ++j) acc[j] = make_float4(0.f, 0.f, 0.f, 0.f);
#pragma unroll 2
    for (int kk = 0; kk < 74; ++kk) {
        float4 w = *(const float4*)(Wc1 + (size_t)(k0 + kk) * 1000 + moff);
#pragma unroll
        for (int j = 0; j < 16; ++j) {
            float t = Tl[bq * 16 + j][kk];
            acc[j].x = fmaf(t, w.x, acc[j].x);
            acc[j].y = fmaf(t, w.y, acc[j].y);
            acc[j].z = fmaf(t, w.z, acc[j].z);
            acc[j].w = fmaf(t, w.w, acc[j].w);
        }
    }
    float* zp = Zp + (size_t)ks * 64 * 1024;
#pragma unroll
    for (int j = 0; j < 16; ++j) {
        int b = bq * 16 + j;
        *(float4*)(zp + (size_t)b * 1024 + mbase) = acc[j];
    }
}

// ---------------- classifier stage B ----------------
__global__ __launch_bounds__(256) void k_cls_reduce(const float* __restrict__ Zp, const float* __restrict__ bc1,
                                                    const float* __restrict__ bn_g, const float* __restrict__ bn_b,
                                                    float* __restrict__ zb) {
    int flat = blockIdx.x * 256 + threadIdx.x;
    int b = flat >> 10, m = flat & 1023;
    if (m >= 1000) return;
    float s = 0.f;
    for (int ks = 0; ks < 128; ++ks)
        s += Zp[((size_t)ks * 64 + b) * 1024 + m];
    float rs = rsqrtf(1.0f + 1e-5f);
    float z = bn_g[m] * (s + bc1[m]) * rs + bn_b[m];
    zb[flat] = z >= 0.f ? z : 0.01f * z;
}

// ---------------- classifier finish ----------------
__global__ __launch_bounds__(256) void k_cls_final(const float* __restrict__ zb,
                                                   const float* __restrict__ Wc2, const float* __restrict__ bc2,
                                                   float* __restrict__ out) {
    int b = blockIdx.x;
    int tid = threadIdx.x;
    float a0 = 0.f, a1 = 0.f;
    for (int m = tid; m < 1000; m += 256) {
        float z = zb[b * 1024 + m];
        a0 = fmaf(z, Wc2[m * 2], a0);
        a1 = fmaf(z, Wc2[m * 2 + 1], a1);
    }
#pragma unroll
    for (int off = 1; off < 64; off <<= 1) {
        a0 += __shfl_xor(a0, off);
        a1 += __shfl_xor(a1, off);
    }
    __shared__ float r0[4], r1[4];
    if ((tid & 63) == 0) { r0[tid >> 6] = a0; r1[tid >> 6] = a1; }
    __syncthreads();
    if (tid == 0) {
        out[b * 2 + 0] = r0[0] + r0[1] + r0[2] + r0[3] + bc2[0];
        out[b * 2 + 1] = r1[0] + r1[1] + r1[2] + r1[3] + bc2[1];
    }
}

extern "C" void kernel_launch(void* const* d_in, const int* in_sizes, int n_in,
                              void* d_out, int out_size, void* d_ws, size_t ws_size,
                              hipStream_t stream) {
    (void)in_sizes; (void)n_in; (void)out_size; (void)ws_size;

    const float* x_feat = (const float*)d_in[0];
    const int* node_roi = (const int*)d_in[1];
    const int* ei1 = (const int*)d_in[3];
    const float* ew1 = (const float*)d_in[4];
    const float* x2f = (const float*)d_in[5];
    const int* ei2 = (const int*)d_in[8];
    const float* ew2 = (const float*)d_in[9];
    const float* Wg1 = (const float*)d_in[10];
    const float* bg1 = (const float*)d_in[11];
    const float* Wg2 = (const float*)d_in[12];
    const float* bg2 = (const float*)d_in[13];
    const float* Wr1 = (const float*)d_in[14];
    const float* br1 = (const float*)d_in[15];
    const float* Wr2 = (const float*)d_in[16];
    const float* br2 = (const float*)d_in[17];
    const float* in_proj_w = (const float*)d_in[18];
    const float* in_proj_b = (const float*)d_in[19];
    const float* out_proj_w = (const float*)d_in[20];
    const float* out_proj_b = (const float*)d_in[21];
    const float* ln1_g = (const float*)d_in[22];
    const float* ln1_b = (const float*)d_in[23];
    const float* ff_w1 = (const float*)d_in[24];
    const float* ff_b1 = (const float*)d_in[25];
    const float* ff_w2 = (const float*)d_in[26];
    const float* ff_b2 = (const float*)d_in[27];
    const float* ln2_g = (const float*)d_in[28];
    const float* ln2_b = (const float*)d_in[29];
    const float* Wc1 = (const float*)d_in[30];
    const float* bc1 = (const float*)d_in[31];
    const float* bn_g = (const float*)d_in[32];
    const float* bn_b = (const float*)d_in[33];
    const float* Wc2 = (const float*)d_in[34];
    const float* bc2 = (const float*)d_in[35];

    const int* src1 = ei1;
    const int* dst1 = ei1 + E1v;
    const int* src2 = ei2;
    const int* dst2 = ei2 + E2v;

    float* out = (float*)d_out;
    const int PSZ = BRv * 64;
    float* pooled_out = out + 128;
    float* pooledroi_out = out + 128 + PSZ;
    float* tout_out = out + 128 + 2 * PSZ;
    float* attn_out = out + 128 + 3 * PSZ;

    // ===== workspace layout (floats) =====
    float* W = (float*)d_ws;
    size_t o = 0;
    // zero zone: bucket cursors only
    int* cur1 = (int*)(W + o); o += 256;
    int* cur2 = (int*)(W + o); o += 128;
    size_t zone_elems = o;
    int* cb1 = (int*)(W + o);  o += 260;
    int* cb2 = (int*)(W + o);  o += 76;
    o = (o + 1) & ~(size_t)1;
    int2* snC1 = (int2*)(W + o); o += (size_t)E1v * 2;
    int2* snC2 = (int2*)(W + o); o += (size_t)E2v * 2;
    float* dinv1 = W + o;        o += N1v;
    float* dinv2 = W + o;        o += N2v;
    int* offs1 = (int*)(W + o);  o += N1v;
    int* offs2 = (int*)(W + o);  o += N2v;
    int* offs_p = (int*)(W + o); o += NSEG;
    int* nodeC = (int*)(W + o);  o += N1v;
    float* zbuf = W + o;         o += BBv * 1024;
    o = (o + 1) & ~(size_t)1;
    // dedicated branch-2 activation buffers (branches run fused)
    ushort_t* h2P = (ushort_t*)(W + o);  o += (size_t)N2v * 32;
    ushort_t* h2Ab = (ushort_t*)(W + o); o += (size_t)N2v * 32;
    o = (o + 1) & ~(size_t)1;
    size_t h1P_off = o; o += (size_t)N1v * 64;
    size_t h1A_off = o; o += (size_t)N1v * 64;
    ushort_t* h1P = (ushort_t*)(W + h1P_off);
    ushort_t* h1Ab = (ushort_t*)(W + h1A_off);
    u64* rb1 = (u64*)(W + h1P_off);       // strided slabs; dead before first GEMM writes h1P
    u64* rb2 = rb1 + (size_t)NBK1 * STR1;
    size_t p = h1P_off;                    // transformer scratch aliases h1P
    float* comb = W + p; p += PSZ;
    float* qkvb = W + p; p += (size_t)BRv * 192;
    float* obuf = W + p; p += PSZ;
    float* xbuf = W + p; p += PSZ;
    float* f1 = W + p;   p += PSZ;
    float* WinT = W + p; p += 64 * 192;
    float* WoutT = W + p; p += 64 * 64;
    float* Zp = W + h1A_off;   // classifier partials alias h1A

    dim3 blk(256);

    hipMemsetAsync(W, 0, zone_elems * sizeof(float), stream);

    // ===== atomic-light CSR build (both branches), binA eliminated =====
    k_binB2<<<E1v / EPB + E2v / EPB, blk, 0, stream>>>(src1, dst1, ew1, cur1, rb1,
                                                       src2, dst2, ew2, cur2, rb2);
    k_scanC<<<1, blk, 0, stream>>>(cur1, cb1, cur2, cb2);
    k_csrC<BINS1, CAP1, SH1, STR1><<<NBK1, blk, CAP1 * 8, stream>>>(rb1, cur1, cb1, dinv1, offs1, snC1);
    k_csrC<BINS2, CAP2, SH2, STR2><<<NBK2, blk, CAP2 * 8, stream>>>(rb2, cur2, cb2, dinv2, offs2, snC2);
    k_normfix<<<E1v / 256 + E2v / 256, blk, 0, stream>>>(snC1, dinv1, snC2, dinv2);
    k_pool_csr<<<BBv, blk, 0, stream>>>(node_roi, offs_p, nodeC);

    // ===== GCN layers (fused across branches) =====
    k_gemm_mfma_f32<<<MB1, blk, 0, stream>>>(x_feat, Wg1, h1P, N1v);
    k_gemm_rowwave<1, false, false, true><<<cdiv(N2v, 4), blk, 148 * 64 * 4, stream>>>(x2f, Wr1, nullptr, h2P, N2v, 148);
    k_gather_both<<<GB1 + GB2, blk, 0, stream>>>(snC1, offs1, h1P, dinv1, bg1, h1Ab,
                                                 snC2, offs2, h2P, dinv2, br1, h2Ab);
    k_gemm_both<<<MB1 + MB2, blk, 0, stream>>>(h1Ab, Wg2, h1P, h2Ab, Wr2, h2P);
    k_gather_both<<<GB1 + GB2, blk, 0, stream>>>(snC1, offs1, h1P, dinv1, bg2, h1Ab,
                                                 snC2, offs2, h2P, dinv2, br2, h2Ab);
    k_pool_all<<<2048, blk, 0, stream>>>(nodeC, offs_p, h1Ab, h2Ab, pooled_out, pooledroi_out, comb);

    // ===== transformer =====
    k_transpose2<<<cdiv(192 * 64 + 64 * 64, 256), blk, 0, stream>>>(in_proj_w, WinT, out_proj_w, WoutT);
    k_gemm_rowwave<3, false, false, false><<<cdiv(N2v, 4), blk, 64 * 192 * 4, stream>>>(comb, WinT, in_proj_b, qkvb, N2v, 64);
    k_attn<<<BBv * 4 * 4, blk, 0, stream>>>(qkvb, attn_out, obuf);
    k_ln_gemm<<<cdiv(N2v, 4), blk, 0, stream>>>(obuf, WoutT, out_proj_b, comb, ln1_g, ln1_b, xbuf, N2v);
    k_gemm_rowwave<1, false, true, false><<<cdiv(N2v, 4), blk, 64 * 64 * 4, stream>>>(xbuf, ff_w1, ff_b1, f1, N2v, 64);
    k_ln_gemm<<<cdiv(N2v, 4), blk, 0, stream>>>(f1, ff_w2, ff_b2, xbuf, ln2_g, ln2_b, tout_out, N2v);

    // ===== classifier =====
    k_cls_part<<<512, blk, 0, stream>>>(tout_out, Wc1, Zp);
    k_cls_reduce<<<BBv * 1024 / 256, blk, 0, stream>>>(Zp, bc1, bn_g, bn_b, zbuf);
    k_cls_final<<<BBv, blk, 0, stream>>>(zbuf, Wc2, bc2, out);
}

// Round 18
// 390.529 us; speedup vs baseline: 1.1799x; 1.0067x over previous
//
#include <hip/hip_runtime.h>
#include <cstdint>
#include <cstddef>

#define N1v 262144
#define E1v 1048576
#define N2v 9472
#define E2v 262144
#define BBv 64
#define RRv 148
#define HIDv 1000
#define BRv (BBv * RRv)
#define NSEG 9472
#define EPB 4096
#define NBK1 256
#define SH1 10
#define BINS1 1024
#define CAP1 4864
#define STR1 4608
#define NBK2 74
#define SH2 7
#define BINS2 128
#define CAP2 4096
#define STR2 4096
#define GB1 4096
#define GB2 1184
#define MB1 2048
#define MB2 148
#define PH_B2 (E1v / EPB + E2v / EPB)   // 320
#define PH_G1 MB1                        // 2048
#define PH_PC BBv                        // 64
#define PH_TR 64

__host__ __device__ constexpr int cdiv(int a, int b) { return (a + b - 1) / b; }

typedef __attribute__((ext_vector_type(8))) short bf16x8;
typedef __attribute__((ext_vector_type(4))) float f32x4;
typedef unsigned short ushort_t;
typedef unsigned long long u64;

__device__ inline short f2bf(float f) {
    union { float f; unsigned u; } v; v.f = f;
    unsigned r = v.u + 0x7fff + ((v.u >> 16) & 1);   // RNE
    return (short)(r >> 16);
}
__device__ inline float bf2f(unsigned hs) {
    union { unsigned u; float f; } v; v.u = hs << 16; return v.f;
}
__device__ inline unsigned relu_pk(unsigned u) {
    unsigned r = u;
    if (r & 0x8000u) r &= 0xFFFF0000u;
    if (r & 0x80000000u) r &= 0x0000FFFFu;
    return r;
}

// ---------------- binB body: bucket-grouped record scatter into fixed-stride slabs ----------------
__device__ inline void binB2_body(const int* __restrict__ src, const int* __restrict__ dst,
                                  const float* __restrict__ ew, int* __restrict__ cur, u64* __restrict__ rb,
                                  int nbk, int sh, int e0, size_t stride,
                                  int* __restrict__ h, int* __restrict__ basg) {
    int tid = threadIdx.x;
    if (tid < nbk) h[tid] = 0;
    __syncthreads();
    for (int t = tid; t < EPB; t += 256) atomicAdd(&h[dst[e0 + t] >> sh], 1);
    __syncthreads();
    if (tid < nbk) {
        int c = h[tid];
        basg[tid] = c ? atomicAdd(&cur[tid], c) : 0;
        h[tid] = 0;
    }
    __syncthreads();
    unsigned lowmask = (1u << sh) - 1u;
    for (int t = tid; t < EPB; t += 256) {
        int d = dst[e0 + t];
        int b = d >> sh;
        int r = atomicAdd(&h[b], 1);
        unsigned lo = ((unsigned)src[e0 + t] << sh) | ((unsigned)d & lowmask);
        rb[(size_t)b * stride + basg[b] + r] = ((u64)(unsigned)__float_as_int(ew[e0 + t]) << 32) | lo;
    }
}

// ---------------- gemm f32-input body ----------------
__device__ inline void gemm_f32_body(const float* __restrict__ X, const float* __restrict__ Wmat,
                                     ushort_t* __restrict__ Y, int N, int gw, int tw, int tid) {
    int lane = tid & 63;
    int l15 = lane & 15;
    int lg = lane >> 4;
    bf16x8 bfrag[2][4];
    for (int kh = 0; kh < 2; ++kh)
        for (int ct = 0; ct < 4; ++ct) {
            bf16x8 b;
#pragma unroll
            for (int i = 0; i < 8; ++i)
                b[i] = f2bf(Wmat[(size_t)(kh * 32 + lg * 8 + i) * 64 + ct * 16 + l15]);
            bfrag[kh][ct] = b;
        }
    int ntiles = N >> 4;
    for (int t = gw; t < ntiles; t += tw) {
        int row0 = t << 4;
        const float* xp = X + (size_t)(row0 + l15) * 64 + lg * 8;
        float4 a0 = *(const float4*)(xp);
        float4 a1 = *(const float4*)(xp + 4);
        float4 a2 = *(const float4*)(xp + 32);
        float4 a3 = *(const float4*)(xp + 36);
        bf16x8 af0, af1;
        af0[0] = f2bf(a0.x); af0[1] = f2bf(a0.y); af0[2] = f2bf(a0.z); af0[3] = f2bf(a0.w);
        af0[4] = f2bf(a1.x); af0[5] = f2bf(a1.y); af0[6] = f2bf(a1.z); af0[7] = f2bf(a1.w);
        af1[0] = f2bf(a2.x); af1[1] = f2bf(a2.y); af1[2] = f2bf(a2.z); af1[3] = f2bf(a2.w);
        af1[4] = f2bf(a3.x); af1[5] = f2bf(a3.y); af1[6] = f2bf(a3.z); af1[7] = f2bf(a3.w);
        f32x4 acc0 = {0.f, 0.f, 0.f, 0.f}, acc1 = acc0, acc2 = acc0, acc3 = acc0;
        acc0 = __builtin_amdgcn_mfma_f32_16x16x32_bf16(af0, bfrag[0][0], acc0, 0, 0, 0);
        acc1 = __builtin_amdgcn_mfma_f32_16x16x32_bf16(af0, bfrag[0][1], acc1, 0, 0, 0);
        acc2 = __builtin_amdgcn_mfma_f32_16x16x32_bf16(af0, bfrag[0][2], acc2, 0, 0, 0);
        acc3 = __builtin_amdgcn_mfma_f32_16x16x32_bf16(af0, bfrag[0][3], acc3, 0, 0, 0);
        acc0 = __builtin_amdgcn_mfma_f32_16x16x32_bf16(af1, bfrag[1][0], acc0, 0, 0, 0);
        acc1 = __builtin_amdgcn_mfma_f32_16x16x32_bf16(af1, bfrag[1][1], acc1, 0, 0, 0);
        acc2 = __builtin_amdgcn_mfma_f32_16x16x32_bf16(af1, bfrag[1][2], acc2, 0, 0, 0);
        acc3 = __builtin_amdgcn_mfma_f32_16x16x32_bf16(af1, bfrag[1][3], acc3, 0, 0, 0);
        ushort_t* yp = Y + (size_t)(row0 + lg * 4) * 64 + l15;
#pragma unroll
        for (int r = 0; r < 4; ++r) {
            yp[(size_t)r * 64 + 0]  = (ushort_t)f2bf(acc0[r]);
            yp[(size_t)r * 64 + 16] = (ushort_t)f2bf(acc1[r]);
            yp[(size_t)r * 64 + 32] = (ushort_t)f2bf(acc2[r]);
            yp[(size_t)r * 64 + 48] = (ushort_t)f2bf(acc3[r]);
        }
    }
}

// ---------------- pool CSR body ----------------
__device__ inline void pool_csr_body(const int* __restrict__ roi, int* __restrict__ offs_p,
                                     int* __restrict__ nodeC, int b, int* __restrict__ smem) {
    int* rl = smem;                // 4096
    int* hist = smem + 4096;       // 148
    int* curs = smem + 4096 + RRv; // 148
    int tid = threadIdx.x;
    for (int t = tid; t < RRv; t += 256) hist[t] = 0;
    __syncthreads();
    int base = b * 4096;
    for (int t = tid; t < 4096; t += 256) {
        int r = roi[base + t];
        rl[t] = r;
        atomicAdd(&hist[r], 1);
    }
    __syncthreads();
    if (tid < RRv) {
        int s = 0;
        for (int k = 0; k < tid; ++k) s += hist[k];
        curs[tid] = s;
        offs_p[b * RRv + tid] = base + s;
    }
    __syncthreads();
    for (int t = tid; t < 4096; t += 256) {
        int r = rl[t];
        int j = atomicAdd(&curs[r], 1);
        nodeC[base + j] = base + t;
    }
}

// ---------------- phase 1: binB2 + gemm_f32 + pool_csr + transposes, fused ----------------
__global__ __launch_bounds__(256) void k_phase1(
    const int* __restrict__ src1, const int* __restrict__ dst1, const float* __restrict__ ew1,
    int* __restrict__ cur1, u64* __restrict__ rb1,
    const int* __restrict__ src2, const int* __restrict__ dst2, const float* __restrict__ ew2,
    int* __restrict__ cur2, u64* __restrict__ rb2,
    const float* __restrict__ x_feat, const float* __restrict__ Wg1, ushort_t* __restrict__ h1P,
    const int* __restrict__ roi, int* __restrict__ offs_p, int* __restrict__ nodeC,
    const float* __restrict__ Win, float* __restrict__ WinT,
    const float* __restrict__ Wout, float* __restrict__ WoutT) {
    __shared__ int smem[4096 + 2 * RRv];
    int bid = blockIdx.x;
    int tid = threadIdx.x;
    if (bid < PH_B2) {
        if (bid < E1v / EPB)
            binB2_body(src1, dst1, ew1, cur1, rb1, NBK1, SH1, bid * EPB, STR1, smem, smem + 256);
        else
            binB2_body(src2, dst2, ew2, cur2, rb2, NBK2, SH2, (bid - E1v / EPB) * EPB, STR2, smem, smem + 256);
    } else if (bid < PH_B2 + PH_G1) {
        gemm_f32_body(x_feat, Wg1, h1P, N1v, (bid - PH_B2) * 4 + (tid >> 6), PH_G1 * 4, tid);
    } else if (bid < PH_B2 + PH_G1 + PH_PC) {
        pool_csr_body(roi, offs_p, nodeC, bid - PH_B2 - PH_G1, smem);
    } else {
        int i = (bid - PH_B2 - PH_G1 - PH_PC) * 256 + tid;
        if (i < 192 * 64) {
            WinT[(i & 63) * 192 + (i >> 6)] = Win[i];
        } else if (i < 192 * 64 + 64 * 64) {
            int j = i - 192 * 64;
            WoutT[(j & 63) * 64 + (j >> 6)] = Wout[j];
        }
    }
}

// ---------------- scan bucket fill counts -> compact bases ----------------
__global__ __launch_bounds__(256) void k_scanC(const int* __restrict__ cur1, int* __restrict__ cb1,
                                               const int* __restrict__ cur2, int* __restrict__ cb2) {
    __shared__ int tmp[256];
    int t = threadIdx.x;
    int v = cur1[t];
    tmp[t] = v; __syncthreads();
    int val = v;
    for (int off = 1; off < 256; off <<= 1) { int o = (t >= off) ? tmp[t - off] : 0; __syncthreads(); val += o; tmp[t] = val; __syncthreads(); }
    cb1[t] = val - v;
    if (t == 255) cb1[256] = val;
    __syncthreads();
    int v2 = (t < NBK2) ? cur2[t] : 0;
    tmp[t] = v2; __syncthreads();
    int val2 = v2;
    for (int off = 1; off < 256; off <<= 1) { int o = (t >= off) ? tmp[t - off] : 0; __syncthreads(); val2 += o; tmp[t] = val2; __syncthreads(); }
    if (t < NBK2) cb2[t] = val2 - v2;
    if (t == NBK2 - 1) cb2[NBK2] = val2;
}

// ---------------- pass C: per-bucket CSR build from strided slab; snC.y = ew * dinv[d] ----------------
template<int BINS, int CAP, int SH, int STRIDE>
__global__ __launch_bounds__(256) void k_csrC(const u64* __restrict__ rb, const int* __restrict__ cnts,
                                              const int* __restrict__ cbase,
                                              float* __restrict__ dinv, int* __restrict__ offs,
                                              int2* __restrict__ snC) {
    int b = blockIdx.x;
    const u64* rbb = rb + (size_t)b * STRIDE;
    int cnt = cnts[b];
    int cb = cbase[b];
    __shared__ int hist[BINS];
    __shared__ float degs[BINS];
    __shared__ int scn[BINS];
    __shared__ int tmp[256];
    extern __shared__ int2 outb[];
    int tid = threadIdx.x;
    for (int i = tid; i < BINS; i += 256) { hist[i] = 0; degs[i] = 0.f; }
    __syncthreads();
    for (int j = tid; j < cnt; j += 256) {
        u64 rec = rbb[j];
        int bin = (int)((unsigned)rec & (BINS - 1));
        float w = __int_as_float((int)(rec >> 32));
        atomicAdd(&hist[bin], 1);
        atomicAdd(&degs[bin], w);
    }
    __syncthreads();
    constexpr int PER = (BINS + 255) / 256;
    int lv[PER];
    int tsum = 0;
    int base_i = tid * PER;
#pragma unroll
    for (int k = 0; k < PER; ++k) { int idx = base_i + k; lv[k] = (idx < BINS) ? hist[idx] : 0; tsum += lv[k]; }
    tmp[tid] = tsum; __syncthreads();
    int val = tsum;
    for (int off = 1; off < 256; off <<= 1) { int o = (tid >= off) ? tmp[tid - off] : 0; __syncthreads(); val += o; tmp[tid] = val; __syncthreads(); }
    int run = val - tsum;
#pragma unroll
    for (int k = 0; k < PER; ++k) { int idx = base_i + k; if (idx < BINS) { scn[idx] = run; run += lv[k]; } }
    __syncthreads();
    for (int i = tid; i < BINS; i += 256) {
        offs[b * BINS + i] = cb + scn[i];
        dinv[b * BINS + i] = rsqrtf(degs[i] + 1.0f);
    }
    __syncthreads();
    bool staged = (cnt <= CAP);
    for (int j = tid; j < cnt; j += 256) {
        u64 rec = rbb[j];
        unsigned lo = (unsigned)rec;
        int bin = (int)(lo & (BINS - 1));
        int s = (int)(lo >> SH);
        float w = __int_as_float((int)(rec >> 32));
        float wd = w * rsqrtf(degs[bin] + 1.0f);   // fold dinv[d]
        int r = atomicAdd(&scn[bin], 1);
        int2 o2 = make_int2(s, __float_as_int(wd));
        if (staged) outb[r] = o2;
        else snC[(size_t)cb + r] = o2;
    }
    __syncthreads();
    if (staged) {
        for (int j = tid; j < cnt; j += 256) snC[(size_t)cb + j] = outb[j];
    }
}

// ---------------- normfix: snC.y *= dinv[src] (both branches, one launch) ----------------
__global__ __launch_bounds__(256) void k_normfix(int2* __restrict__ snC1, const float* __restrict__ dinv1,
                                                 int2* __restrict__ snC2, const float* __restrict__ dinv2) {
    int bid = blockIdx.x;
    int2* snC; const float* dinv; int j;
    if (bid < E1v / 256) { snC = snC1; dinv = dinv1; j = bid * 256 + threadIdx.x; }
    else { snC = snC2; dinv = dinv2; j = (bid - E1v / 256) * 256 + threadIdx.x; }
    int2 e = snC[j];
    e.y = __float_as_int(dinv[e.x] * __int_as_float(e.y));
    snC[j] = e;
}

// ---------------- fused pool: branch-1 mean-pool + branch-2 identity + comb ----------------
__global__ __launch_bounds__(256) void k_pool_all(const int* __restrict__ nodeC, const int* __restrict__ offs,
                                                  const ushort_t* __restrict__ Ab, const ushort_t* __restrict__ h2Ab,
                                                  float* __restrict__ pooled, float* __restrict__ pooledroi,
                                                  float* __restrict__ comb) {
    int tid = threadIdx.x;
    int lane = tid & 63;
    int nh = lane >> 5;
    int slot = (lane >> 3) & 3;
    int f8 = lane & 7;
    int gw = blockIdx.x * 4 + (tid >> 6);
    int tw = gridDim.x * 4;
    for (int ss = gw * 2; ss < NSEG; ss += tw * 2) {
        int s = ss + nh;
        int beg = offs[s];
        int end = (s + 1 < NSEG) ? offs[s + 1] : N1v;
        float a0 = 0.f, a1 = 0.f, a2 = 0.f, a3 = 0.f, a4 = 0.f, a5 = 0.f, a6 = 0.f, a7 = 0.f;
        for (int j = beg + slot; j < end; j += 4) {
            int node = nodeC[j];
            uint4 v = *(const uint4*)(Ab + (size_t)node * 64 + f8 * 8);
            a0 += fmaxf(bf2f(v.x & 0xffffu), 0.f);
            a1 += fmaxf(bf2f(v.x >> 16), 0.f);
            a2 += fmaxf(bf2f(v.y & 0xffffu), 0.f);
            a3 += fmaxf(bf2f(v.y >> 16), 0.f);
            a4 += fmaxf(bf2f(v.z & 0xffffu), 0.f);
            a5 += fmaxf(bf2f(v.z >> 16), 0.f);
            a6 += fmaxf(bf2f(v.w & 0xffffu), 0.f);
            a7 += fmaxf(bf2f(v.w >> 16), 0.f);
        }
        a0 += __shfl_xor(a0, 8);  a1 += __shfl_xor(a1, 8);  a2 += __shfl_xor(a2, 8);  a3 += __shfl_xor(a3, 8);
        a4 += __shfl_xor(a4, 8);  a5 += __shfl_xor(a5, 8);  a6 += __shfl_xor(a6, 8);  a7 += __shfl_xor(a7, 8);
        a0 += __shfl_xor(a0, 16); a1 += __shfl_xor(a1, 16); a2 += __shfl_xor(a2, 16); a3 += __shfl_xor(a3, 16);
        a4 += __shfl_xor(a4, 16); a5 += __shfl_xor(a5, 16); a6 += __shfl_xor(a6, 16); a7 += __shfl_xor(a7, 16);
        if (slot == 0) {
            float inv = 1.f / (float)max(end - beg, 1);
            float p0 = a0 * inv, p1 = a1 * inv, p2 = a2 * inv, p3 = a3 * inv;
            float p4 = a4 * inv, p5 = a5 * inv, p6 = a6 * inv, p7 = a7 * inv;
            uint4 v2 = *(const uint4*)(h2Ab + (size_t)s * 64 + f8 * 8);
            float q0 = fmaxf(bf2f(v2.x & 0xffffu), 0.f);
            float q1 = fmaxf(bf2f(v2.x >> 16), 0.f);
            float q2 = fmaxf(bf2f(v2.y & 0xffffu), 0.f);
            float q3 = fmaxf(bf2f(v2.y >> 16), 0.f);
            float q4 = fmaxf(bf2f(v2.z & 0xffffu), 0.f);
            float q5 = fmaxf(bf2f(v2.z >> 16), 0.f);
            float q6 = fmaxf(bf2f(v2.w & 0xffffu), 0.f);
            float q7 = fmaxf(bf2f(v2.w >> 16), 0.f);
            size_t bo = (size_t)s * 64 + f8 * 8;
            float4 t;
            t.x = p0; t.y = p1; t.z = p2; t.w = p3; *(float4*)(pooled + bo) = t;
            t.x = p4; t.y = p5; t.z = p6; t.w = p7; *(float4*)(pooled + bo + 4) = t;
            t.x = q0; t.y = q1; t.z = q2; t.w = q3; *(float4*)(pooledroi + bo) = t;
            t.x = q4; t.y = q5; t.z = q6; t.w = q7; *(float4*)(pooledroi + bo + 4) = t;
            t.x = p0 + q0; t.y = p1 + q1; t.z = p2 + q2; t.w = p3 + q3; *(float4*)(comb + bo) = t;
            t.x = p4 + q4; t.y = p5 + q5; t.z = p6 + q6; t.w = p7 + q7; *(float4*)(comb + bo + 4) = t;
        }
    }
}

// ---------------- gather body (norm fully precomputed in snC.y) ----------------
__device__ inline void gather_body(const int2* __restrict__ snC, const int* __restrict__ offs,
                                   const ushort_t* __restrict__ Pb, const float* __restrict__ dinv,
                                   const float* __restrict__ bias, ushort_t* __restrict__ A,
                                   int N, int E, int gw, int tw, int lane) {
    int nh = lane >> 5;
    int slot = (lane >> 3) & 3;
    int f8 = lane & 7;
    float4 bv0 = *(const float4*)(bias + f8 * 8);
    float4 bv1 = *(const float4*)(bias + f8 * 8 + 4);
    for (int ii = gw * 2; ii < N; ii += tw * 2) {
        int i = ii + nh;
        int beg = offs[i];
        int end = (i + 1 < N) ? offs[i + 1] : E;
        float a0 = 0.f, a1 = 0.f, a2 = 0.f, a3 = 0.f, a4 = 0.f, a5 = 0.f, a6 = 0.f, a7 = 0.f;
        for (int j = beg + slot; j < end; j += 4) {
            int2 e = snC[j];
            int s = e.x;
            float nv = __int_as_float(e.y);
            uint4 w = *(const uint4*)(Pb + (size_t)s * 64 + f8 * 8);
            a0 = fmaf(nv, bf2f(w.x & 0xffffu), a0);
            a1 = fmaf(nv, bf2f(w.x >> 16), a1);
            a2 = fmaf(nv, bf2f(w.y & 0xffffu), a2);
            a3 = fmaf(nv, bf2f(w.y >> 16), a3);
            a4 = fmaf(nv, bf2f(w.z & 0xffffu), a4);
            a5 = fmaf(nv, bf2f(w.z >> 16), a5);
            a6 = fmaf(nv, bf2f(w.w & 0xffffu), a6);
            a7 = fmaf(nv, bf2f(w.w >> 16), a7);
        }
        a0 += __shfl_xor(a0, 8);  a1 += __shfl_xor(a1, 8);  a2 += __shfl_xor(a2, 8);  a3 += __shfl_xor(a3, 8);
        a4 += __shfl_xor(a4, 8);  a5 += __shfl_xor(a5, 8);  a6 += __shfl_xor(a6, 8);  a7 += __shfl_xor(a7, 8);
        a0 += __shfl_xor(a0, 16); a1 += __shfl_xor(a1, 16); a2 += __shfl_xor(a2, 16); a3 += __shfl_xor(a3, 16);
        a4 += __shfl_xor(a4, 16); a5 += __shfl_xor(a5, 16); a6 += __shfl_xor(a6, 16); a7 += __shfl_xor(a7, 16);
        if (slot == 0) {
            uint4 w = *(const uint4*)(Pb + (size_t)i * 64 + f8 * 8);
            float di = dinv[i];
            float s2 = di * di;
            float r0 = fmaf(s2, bf2f(w.x & 0xffffu), a0) + bv0.x;
            float r1 = fmaf(s2, bf2f(w.x >> 16),    a1) + bv0.y;
            float r2 = fmaf(s2, bf2f(w.y & 0xffffu), a2) + bv0.z;
            float r3 = fmaf(s2, bf2f(w.y >> 16),    a3) + bv0.w;
            float r4 = fmaf(s2, bf2f(w.z & 0xffffu), a4) + bv1.x;
            float r5 = fmaf(s2, bf2f(w.z >> 16),    a5) + bv1.y;
            float r6 = fmaf(s2, bf2f(w.w & 0xffffu), a6) + bv1.z;
            float r7 = fmaf(s2, bf2f(w.w >> 16),    a7) + bv1.w;
            uint4 ov;
            ov.x = (unsigned)(ushort_t)f2bf(r0) | ((unsigned)(ushort_t)f2bf(r1) << 16);
            ov.y = (unsigned)(ushort_t)f2bf(r2) | ((unsigned)(ushort_t)f2bf(r3) << 16);
            ov.z = (unsigned)(ushort_t)f2bf(r4) | ((unsigned)(ushort_t)f2bf(r5) << 16);
            ov.w = (unsigned)(ushort_t)f2bf(r6) | ((unsigned)(ushort_t)f2bf(r7) << 16);
            *(uint4*)(A + (size_t)i * 64 + f8 * 8) = ov;
        }
    }
}

// ---------------- fused gather: branch1 + branch2 in one launch ----------------
__global__ __launch_bounds__(256) void k_gather_both(const int2* __restrict__ snC1, const int* __restrict__ offs1,
                                                     const ushort_t* __restrict__ P1, const float* __restrict__ dinv1,
                                                     const float* __restrict__ b1, ushort_t* __restrict__ A1,
                                                     const int2* __restrict__ snC2, const int* __restrict__ offs2,
                                                     const ushort_t* __restrict__ P2, const float* __restrict__ dinv2,
                                                     const float* __restrict__ b2, ushort_t* __restrict__ A2) {
    int tid = threadIdx.x;
    int lane = tid & 63;
    if (blockIdx.x < GB1)
        gather_body(snC1, offs1, P1, dinv1, b1, A1, N1v, E1v,
                    blockIdx.x * 4 + (tid >> 6), GB1 * 4, lane);
    else
        gather_body(snC2, offs2, P2, dinv2, b2, A2, N2v, E2v,
                    (blockIdx.x - GB1) * 4 + (tid >> 6), GB2 * 4, lane);
}

// ---------------- bf16 GEMM body (RIN=true, bf16 in/out) ----------------
__device__ inline void gemm_bf16_body(const ushort_t* __restrict__ X, const float* __restrict__ Wmat,
                                      ushort_t* __restrict__ Y, int N, int gw, int tw, int tid) {
    int lane = tid & 63;
    int l15 = lane & 15;
    int lg = lane >> 4;
    bf16x8 bfrag[2][4];
    for (int kh = 0; kh < 2; ++kh)
        for (int ct = 0; ct < 4; ++ct) {
            bf16x8 b;
#pragma unroll
            for (int i = 0; i < 8; ++i)
                b[i] = f2bf(Wmat[(size_t)(kh * 32 + lg * 8 + i) * 64 + ct * 16 + l15]);
            bfrag[kh][ct] = b;
        }
    int ntiles = N >> 4;
    for (int t = gw; t < ntiles; t += tw) {
        int row0 = t << 4;
        const ushort_t* xp = X + (size_t)(row0 + l15) * 64 + lg * 8;
        uint4 c0 = *(const uint4*)(xp);
        uint4 c1 = *(const uint4*)(xp + 32);
        c0.x = relu_pk(c0.x); c0.y = relu_pk(c0.y); c0.z = relu_pk(c0.z); c0.w = relu_pk(c0.w);
        c1.x = relu_pk(c1.x); c1.y = relu_pk(c1.y); c1.z = relu_pk(c1.z); c1.w = relu_pk(c1.w);
        bf16x8 af0 = *reinterpret_cast<bf16x8*>(&c0);
        bf16x8 af1 = *reinterpret_cast<bf16x8*>(&c1);
        f32x4 acc0 = {0.f, 0.f, 0.f, 0.f}, acc1 = acc0, acc2 = acc0, acc3 = acc0;
        acc0 = __builtin_amdgcn_mfma_f32_16x16x32_bf16(af0, bfrag[0][0], acc0, 0, 0, 0);
        acc1 = __builtin_amdgcn_mfma_f32_16x16x32_bf16(af0, bfrag[0][1], acc1, 0, 0, 0);
        acc2 = __builtin_amdgcn_mfma_f32_16x16x32_bf16(af0, bfrag[0][2], acc2, 0, 0, 0);
        acc3 = __builtin_amdgcn_mfma_f32_16x16x32_bf16(af0, bfrag[0][3], acc3, 0, 0, 0);
        acc0 = __builtin_amdgcn_mfma_f32_16x16x32_bf16(af1, bfrag[1][0], acc0, 0, 0, 0);
        acc1 = __builtin_amdgcn_mfma_f32_16x16x32_bf16(af1, bfrag[1][1], acc1, 0, 0, 0);
        acc2 = __builtin_amdgcn_mfma_f32_16x16x32_bf16(af1, bfrag[1][2], acc2, 0, 0, 0);
        acc3 = __builtin_amdgcn_mfma_f32_16x16x32_bf16(af1, bfrag[1][3], acc3, 0, 0, 0);
        ushort_t* yp = Y + (size_t)(row0 + lg * 4) * 64 + l15;
#pragma unroll
        for (int r = 0; r < 4; ++r) {
            yp[(size_t)r * 64 + 0]  = (ushort_t)f2bf(acc0[r]);
            yp[(size_t)r * 64 + 16] = (ushort_t)f2bf(acc1[r]);
            yp[(size_t)r * 64 + 32] = (ushort_t)f2bf(acc2[r]);
            yp[(size_t)r * 64 + 48] = (ushort_t)f2bf(acc3[r]);
        }
    }
}

// ---------------- fused layer-2 GEMM: branch1 + branch2 ----------------
__global__ __launch_bounds__(256) void k_gemm_both(const ushort_t* __restrict__ X1, const float* __restrict__ W1,
                                                   ushort_t* __restrict__ Y1,
                                                   const ushort_t* __restrict__ X2, const float* __restrict__ W2,
                                                   ushort_t* __restrict__ Y2) {
    int tid = threadIdx.x;
    if (blockIdx.x < MB1)
        gemm_bf16_body(X1, W1, Y1, N1v, blockIdx.x * 4 + (tid >> 6), MB1 * 4, tid);
    else
        gemm_bf16_body(X2, W2, Y2, N2v, (blockIdx.x - MB1) * 4 + (tid >> 6), MB2 * 4, tid);
}

// ---------------- row-per-wave GEMM ----------------
template<int MB, bool RIN, bool ROUT, bool OBF16>
__global__ __launch_bounds__(256) void k_gemm_rowwave(const float* __restrict__ X, const float* __restrict__ W,
                                                      const float* __restrict__ bias, void* __restrict__ Yv,
                                                      int N, int K) {
    extern __shared__ float Wl[];
    const int M = MB * 64;
    for (int idx = threadIdx.x; idx < K * M; idx += 256) Wl[idx] = W[idx];
    __syncthreads();
    int lane = threadIdx.x & 63;
    int gw = blockIdx.x * 4 + (threadIdx.x >> 6);
    int tw = gridDim.x * 4;
    const int K4 = K >> 2;
    for (int row = gw; row < N; row += tw) {
        float acc[MB];
#pragma unroll
        for (int cb = 0; cb < MB; ++cb) acc[cb] = 0.f;
        const float4* xr = (const float4*)(X + (size_t)row * K);
        for (int k4 = 0; k4 < K4; ++k4) {
            float4 xv = xr[k4];
            if (RIN) {
                xv.x = fmaxf(xv.x, 0.f); xv.y = fmaxf(xv.y, 0.f);
                xv.z = fmaxf(xv.z, 0.f); xv.w = fmaxf(xv.w, 0.f);
            }
            const float* wp = Wl + (k4 * 4) * M + lane;
#pragma unroll
            for (int cb = 0; cb < MB; ++cb) acc[cb] = fmaf(xv.x, wp[cb * 64], acc[cb]);
            wp += M;
#pragma unroll
            for (int cb = 0; cb < MB; ++cb) acc[cb] = fmaf(xv.y, wp[cb * 64], acc[cb]);
            wp += M;
#pragma unroll
            for (int cb = 0; cb < MB; ++cb) acc[cb] = fmaf(xv.z, wp[cb * 64], acc[cb]);
            wp += M;
#pragma unroll
            for (int cb = 0; cb < MB; ++cb) acc[cb] = fmaf(xv.w, wp[cb * 64], acc[cb]);
        }
#pragma unroll
        for (int cb = 0; cb < MB; ++cb) {
            float y = acc[cb];
            int col = cb * 64 + lane;
            if (bias) y += bias[col];
            if (ROUT) y = fmaxf(y, 0.f);
            if (OBF16) ((ushort_t*)Yv)[(size_t)row * M + col] = (ushort_t)f2bf(y);
            else ((float*)Yv)[(size_t)row * M + col] = y;
        }
    }
}

// ---------------- attention ----------------
__global__ __launch_bounds__(256) void k_attn(const float* __restrict__ qkv, float* __restrict__ aw,
                                              float* __restrict__ o) {
    int qc = blockIdx.x & 3;
    int bh = blockIdx.x >> 2;
    int b = bh >> 2, h = bh & 3;
    __shared__ float qs[37][16];
    __shared__ float kT[16][152];
    __shared__ float vs[148][16];
    __shared__ float ps[4][152];
    int tid = threadIdx.x;
    const float* base = qkv + (size_t)b * 148 * 192 + h * 16;
    for (int idx = tid; idx < 148 * 16; idx += 256) {
        int i = idx >> 4, d = idx & 15;
        const float* p = base + (size_t)i * 192 + d;
        kT[d][i] = p[64];
        vs[i][d] = p[128];
    }
    int q0 = qc * 37;
    for (int idx = tid; idx < 37 * 16; idx += 256) {
        int i = idx >> 4, d = idx & 15;
        qs[i][d] = base[(size_t)(q0 + i) * 192 + d] * 0.25f;
    }
    __syncthreads();
    int wv = tid >> 6, lane = tid & 63;
    float* aw_bh = aw + (size_t)bh * 148 * 148;
    for (int ii = wv; ii < 37; ii += 4) {
        int i = q0 + ii;
        float s0 = 0.f, s1 = 0.f, s2 = 0.f;
#pragma unroll
        for (int d = 0; d < 16; ++d) {
            float q = qs[ii][d];
            s0 = fmaf(q, kT[d][lane], s0);
            s1 = fmaf(q, kT[d][lane + 64], s1);
            if (lane < 20) s2 = fmaf(q, kT[d][lane + 128], s2);
        }
        float m = fmaxf(s0, s1);
        if (lane < 20) m = fmaxf(m, s2);
#pragma unroll
        for (int off = 1; off < 64; off <<= 1) m = fmaxf(m, __shfl_xor(m, off));
        float e0 = __expf(s0 - m), e1 = __expf(s1 - m);
        float e2 = (lane < 20) ? __expf(s2 - m) : 0.f;
        float sum = e0 + e1 + e2;
#pragma unroll
        for (int off = 1; off < 64; off <<= 1) sum += __shfl_xor(sum, off);
        float inv = 1.f / sum;
        float p0 = e0 * inv, p1 = e1 * inv, p2 = e2 * inv;
        float* awr = aw_bh + (size_t)i * 148;
        awr[lane] = p0;
        awr[lane + 64] = p1;
        if (lane < 20) awr[lane + 128] = p2;
        ps[wv][lane] = p0;
        ps[wv][lane + 64] = p1;
        if (lane < 20) ps[wv][lane + 128] = p2;
        int d = lane & 15, jj = lane >> 4;
        float acc = 0.f;
        for (int t = jj; t < 148; t += 4) acc = fmaf(ps[wv][t], vs[t][d], acc);
        acc += __shfl_xor(acc, 16);
        acc += __shfl_xor(acc, 32);
        if (lane < 16) o[((size_t)b * 148 + i) * 64 + h * 16 + d] = acc;
    }
}

// ---------------- fused GEMM + bias + residual + LayerNorm (K=M=64) ----------------
__global__ __launch_bounds__(256) void k_ln_gemm(const float* __restrict__ X, const float* __restrict__ Wt,
                                                 const float* __restrict__ bias, const float* __restrict__ resid,
                                                 const float* __restrict__ g, const float* __restrict__ bb,
                                                 float* __restrict__ Y, int N) {
    __shared__ float Wl[4096];
    for (int idx = threadIdx.x; idx < 4096; idx += 256) Wl[idx] = Wt[idx];
    __syncthreads();
    int lane = threadIdx.x & 63;
    int gw = blockIdx.x * 4 + (threadIdx.x >> 6);
    int tw = gridDim.x * 4;
    for (int row = gw; row < N; row += tw) {
        const float4* xr = (const float4*)(X + (size_t)row * 64);
        float acc = 0.f;
        for (int k4 = 0; k4 < 16; ++k4) {
            float4 xv = xr[k4];
            const float* wp = Wl + (k4 * 4) * 64 + lane;
            acc = fmaf(xv.x, wp[0], acc);
            acc = fmaf(xv.y, wp[64], acc);
            acc = fmaf(xv.z, wp[128], acc);
            acc = fmaf(xv.w, wp[192], acc);
        }
        float y = acc + bias[lane] + resid[(size_t)row * 64 + lane];
        float s = y;
#pragma unroll
        for (int off = 1; off < 64; off <<= 1) s += __shfl_xor(s, off);
        float mu = s * (1.f / 64.f);
        float dcen = y - mu;
        float v = dcen * dcen;
#pragma unroll
        for (int off = 1; off < 64; off <<= 1) v += __shfl_xor(v, off);
        float var = v * (1.f / 64.f);
        Y[(size_t)row * 64 + lane] = dcen * rsqrtf(var + 1e-5f) * g[lane] + bb[lane];
    }
}

// ---------------- classifier stage A ----------------
__global__ __launch_bounds__(256) void k_cls_part(const float* __restrict__ T, const float* __restrict__ Wc1,
                                                  float* __restrict__ Zp) {
    int ks = blockIdx.x >> 2;
    int mt = blockIdx.x & 3;
    int k0 = ks * 74;
    int m0 = mt * 256;
    __shared__ float Tl[64][74];
    int tid = threadIdx.x;
    for (int idx = tid; idx < 64 * 74; idx += 256) {
        int b = idx / 74, kk = idx - b * 74;
        Tl[b][kk] = T[(size_t)b * 9472 + k0 + kk];
    }
    __syncthreads();
    int lane = tid & 63, bq = tid >> 6;
    int mbase = m0 + lane * 4;
    size_t moff = (mbase + 3 < 1000) ? (size_t)mbase : 0;
    float4 acc[16];
#pragma unroll
    for (int j = 0; j < 16; ++j) acc[j] = make_float4(0.f, 0.f, 0.f, 0.f);
#pragma unroll 2
    for (int kk = 0; kk < 74; ++kk) {
        float4 w = *(const float4*)(Wc1 + (size_t)(k0 + kk) * 1000 + moff);
#pragma unroll
        for (int j = 0; j < 16; ++j) {
            float t = Tl[bq * 16 + j][kk];
            acc[j].x = fmaf(t, w.x, acc[j].x);
            acc[j].y = fmaf(t, w.y, acc[j].y);
            acc[j].z = fmaf(t, w.z, acc[j].z);
            acc[j].w = fmaf(t, w.w, acc[j].w);
        }
    }
    float* zp = Zp + (size_t)ks * 64 * 1024;
#pragma unroll
    for (int j = 0; j < 16; ++j) {
        int b = bq * 16 + j;
        *(float4*)(zp + (size_t)b * 1024 + mbase) = acc[j];
    }
}

// ---------------- classifier stage B ----------------
__global__ __launch_bounds__(256) void k_cls_reduce(const float* __restrict__ Zp, const float* __restrict__ bc1,
                                                    const float* __restrict__ bn_g, const float* __restrict__ bn_b,
                                                    float* __restrict__ zb) {
    int flat = blockIdx.x * 256 + threadIdx.x;
    int b = flat >> 10, m = flat & 1023;
    if (m >= 1000) return;
    float s = 0.f;
    for (int ks = 0; ks < 128; ++ks)
        s += Zp[((size_t)ks * 64 + b) * 1024 + m];
    float rs = rsqrtf(1.0f + 1e-5f);
    float z = bn_g[m] * (s + bc1[m]) * rs + bn_b[m];
    zb[flat] = z >= 0.f ? z : 0.01f * z;
}

// ---------------- classifier finish ----------------
__global__ __launch_bounds__(256) void k_cls_final(const float* __restrict__ zb,
                                                   const float* __restrict__ Wc2, const float* __restrict__ bc2,
                                                   float* __restrict__ out) {
    int b = blockIdx.x;
    int tid = threadIdx.x;
    float a0 = 0.f, a1 = 0.f;
    for (int m = tid; m < 1000; m += 256) {
        float z = zb[b * 1024 + m];
        a0 = fmaf(z, Wc2[m * 2], a0);
        a1 = fmaf(z, Wc2[m * 2 + 1], a1);
    }
#pragma unroll
    for (int off = 1; off < 64; off <<= 1) {
        a0 += __shfl_xor(a0, off);
        a1 += __shfl_xor(a1, off);
    }
    __shared__ float r0[4], r1[4];
    if ((tid & 63) == 0) { r0[tid >> 6] = a0; r1[tid >> 6] = a1; }
    __syncthreads();
    if (tid == 0) {
        out[b * 2 + 0] = r0[0] + r0[1] + r0[2] + r0[3] + bc2[0];
        out[b * 2 + 1] = r1[0] + r1[1] + r1[2] + r1[3] + bc2[1];
    }
}

extern "C" void kernel_launch(void* const* d_in, const int* in_sizes, int n_in,
                              void* d_out, int out_size, void* d_ws, size_t ws_size,
                              hipStream_t stream) {
    (void)in_sizes; (void)n_in; (void)out_size; (void)ws_size;

    const float* x_feat = (const float*)d_in[0];
    const int* node_roi = (const int*)d_in[1];
    const int* ei1 = (const int*)d_in[3];
    const float* ew1 = (const float*)d_in[4];
    const float* x2f = (const float*)d_in[5];
    const int* ei2 = (const int*)d_in[8];
    const float* ew2 = (const float*)d_in[9];
    const float* Wg1 = (const float*)d_in[10];
    const float* bg1 = (const float*)d_in[11];
    const float* Wg2 = (const float*)d_in[12];
    const float* bg2 = (const float*)d_in[13];
    const float* Wr1 = (const float*)d_in[14];
    const float* br1 = (const float*)d_in[15];
    const float* Wr2 = (const float*)d_in[16];
    const float* br2 = (const float*)d_in[17];
    const float* in_proj_w = (const float*)d_in[18];
    const float* in_proj_b = (const float*)d_in[19];
    const float* out_proj_w = (const float*)d_in[20];
    const float* out_proj_b = (const float*)d_in[21];
    const float* ln1_g = (const float*)d_in[22];
    const float* ln1_b = (const float*)d_in[23];
    const float* ff_w1 = (const float*)d_in[24];
    const float* ff_b1 = (const float*)d_in[25];
    const float* ff_w2 = (const float*)d_in[26];
    const float* ff_b2 = (const float*)d_in[27];
    const float* ln2_g = (const float*)d_in[28];
    const float* ln2_b = (const float*)d_in[29];
    const float* Wc1 = (const float*)d_in[30];
    const float* bc1 = (const float*)d_in[31];
    const float* bn_g = (const float*)d_in[32];
    const float* bn_b = (const float*)d_in[33];
    const float* Wc2 = (const float*)d_in[34];
    const float* bc2 = (const float*)d_in[35];

    const int* src1 = ei1;
    const int* dst1 = ei1 + E1v;
    const int* src2 = ei2;
    const int* dst2 = ei2 + E2v;

    float* out = (float*)d_out;
    const int PSZ = BRv * 64;
    float* pooled_out = out + 128;
    float* pooledroi_out = out + 128 + PSZ;
    float* tout_out = out + 128 + 2 * PSZ;
    float* attn_out = out + 128 + 3 * PSZ;

    // ===== workspace layout (floats) =====
    float* W = (float*)d_ws;
    size_t o = 0;
    // zero zone: bucket cursors only
    int* cur1 = (int*)(W + o); o += 256;
    int* cur2 = (int*)(W + o); o += 128;
    size_t zone_elems = o;
    int* cb1 = (int*)(W + o);  o += 260;
    int* cb2 = (int*)(W + o);  o += 76;
    o = (o + 1) & ~(size_t)1;
    // dedicated record slabs (must NOT alias h1P: phase1 runs binB2 || gemm_f32)
    u64* rb1 = (u64*)(W + o);  o += (size_t)NBK1 * STR1 * 2;
    u64* rb2 = (u64*)(W + o);  o += (size_t)NBK2 * STR2 * 2;
    int2* snC1 = (int2*)(W + o); o += (size_t)E1v * 2;
    int2* snC2 = (int2*)(W + o); o += (size_t)E2v * 2;
    float* dinv1 = W + o;        o += N1v;
    float* dinv2 = W + o;        o += N2v;
    int* offs1 = (int*)(W + o);  o += N1v;
    int* offs2 = (int*)(W + o);  o += N2v;
    int* offs_p = (int*)(W + o); o += NSEG;
    int* nodeC = (int*)(W + o);  o += N1v;
    float* zbuf = W + o;         o += BBv * 1024;
    // dedicated transposed weights (phase1 writes them while h1P is live)
    float* WinT = W + o;  o += 192 * 64;
    float* WoutT = W + o; o += 64 * 64;
    o = (o + 1) & ~(size_t)1;
    // dedicated branch-2 activation buffers
    ushort_t* h2P = (ushort_t*)(W + o);  o += (size_t)N2v * 32;
    ushort_t* h2Ab = (ushort_t*)(W + o); o += (size_t)N2v * 32;
    o = (o + 1) & ~(size_t)1;
    size_t h1P_off = o; o += (size_t)N1v * 64;
    size_t h1A_off = o; o += (size_t)N1v * 64;
    ushort_t* h1P = (ushort_t*)(W + h1P_off);
    ushort_t* h1Ab = (ushort_t*)(W + h1A_off);
    size_t p = h1P_off;                    // transformer scratch aliases h1P (used after GCN phase)
    float* comb = W + p; p += PSZ;
    float* qkvb = W + p; p += (size_t)BRv * 192;
    float* obuf = W + p; p += PSZ;
    float* xbuf = W + p; p += PSZ;
    float* f1 = W + p;   p += PSZ;
    float* Zp = W + h1A_off;   // classifier partials alias h1A (dead after pool_all)

    dim3 blk(256);

    hipMemsetAsync(W, 0, zone_elems * sizeof(float), stream);

    // ===== phase 1: binB2 || gemm_f32(layer1 b1) || pool_csr || transposes =====
    k_phase1<<<PH_B2 + PH_G1 + PH_PC + PH_TR, blk, 0, stream>>>(
        src1, dst1, ew1, cur1, rb1, src2, dst2, ew2, cur2, rb2,
        x_feat, Wg1, h1P, node_roi, offs_p, nodeC,
        in_proj_w, WinT, out_proj_w, WoutT);
    k_gemm_rowwave<1, false, false, true><<<cdiv(N2v, 4), blk, 148 * 64 * 4, stream>>>(x2f, Wr1, nullptr, h2P, N2v, 148);
    k_scanC<<<1, blk, 0, stream>>>(cur1, cb1, cur2, cb2);
    k_csrC<BINS1, CAP1, SH1, STR1><<<NBK1, blk, CAP1 * 8, stream>>>(rb1, cur1, cb1, dinv1, offs1, snC1);
    k_csrC<BINS2, CAP2, SH2, STR2><<<NBK2, blk, CAP2 * 8, stream>>>(rb2, cur2, cb2, dinv2, offs2, snC2);
    k_normfix<<<E1v / 256 + E2v / 256, blk, 0, stream>>>(snC1, dinv1, snC2, dinv2);

    // ===== GCN layers (fused across branches) =====
    k_gather_both<<<GB1 + GB2, blk, 0, stream>>>(snC1, offs1, h1P, dinv1, bg1, h1Ab,
                                                 snC2, offs2, h2P, dinv2, br1, h2Ab);
    k_gemm_both<<<MB1 + MB2, blk, 0, stream>>>(h1Ab, Wg2, h1P, h2Ab, Wr2, h2P);
    k_gather_both<<<GB1 + GB2, blk, 0, stream>>>(snC1, offs1, h1P, dinv1, bg2, h1Ab,
                                                 snC2, offs2, h2P, dinv2, br2, h2Ab);
    k_pool_all<<<2048, blk, 0, stream>>>(nodeC, offs_p, h1Ab, h2Ab, pooled_out, pooledroi_out, comb);

    // ===== transformer =====
    k_gemm_rowwave<3, false, false, false><<<cdiv(N2v, 4), blk, 64 * 192 * 4, stream>>>(comb, WinT, in_proj_b, qkvb, N2v, 64);
    k_attn<<<BBv * 4 * 4, blk, 0, stream>>>(qkvb, attn_out, obuf);
    k_ln_gemm<<<cdiv(N2v, 4), blk, 0, stream>>>(obuf, WoutT, out_proj_b, comb, ln1_g, ln1_b, xbuf, N2v);
    k_gemm_rowwave<1, false, true, false><<<cdiv(N2v, 4), blk, 64 * 64 * 4, stream>>>(xbuf, ff_w1, ff_b1, f1, N2v, 64);
    k_ln_gemm<<<cdiv(N2v, 4), blk, 0, stream>>>(f1, ff_w2, ff_b2, xbuf, ln2_g, ln2_b, tout_out, N2v);

    // ===== classifier =====
    k_cls_part<<<512, blk, 0, stream>>>(tout_out, Wc1, Zp);
    k_cls_reduce<<<BBv * 1024 / 256, blk, 0, stream>>>(Zp, bc1, bn_g, bn_b, zbuf);
    k_cls_final<<<BBv, blk, 0, stream>>>(zbuf, Wc2, bc2, out);
}